// Round 5
// baseline (2232.389 us; speedup 1.0000x reference)
//
#include <hip/hip_runtime.h>
#include <cstdint>
#include <cstddef>

// ---------------------------------------------------------------------------
// TransformerEncoderLayer on MI355X (gfx950). Correctness-first round:
//  - entire pre-gate path (QKV, scores, softmax, PV, out_proj, LN1, gate) in
//    pure fp32 (tiled VALU SGEMM, deterministic, no precision tricks) so the
//    gumbel-argmax expert choice matches the JAX reference.
//  - categorical(key(42)) with jax_threefry_partitionable=True semantics
//    (jax/_src/prng.py::_threefry_random_bits_partitionable):
//      (b1,b2) = threefry2x32(key, counts_hi=0, counts_lo=i)
//      bit_width 32 -> bits = b1 ^ b2          [THIS round: XOR of both words]
//  - MoE FFN dense all-expert in f16 MFMA + one-hot select (error ~1e-3,
//    far under threshold; no bucketing/atomics -> fully deterministic).
// ---------------------------------------------------------------------------

typedef _Float16 h16;
typedef h16 h16x8 __attribute__((ext_vector_type(8)));
typedef h16 h16x4 __attribute__((ext_vector_type(4)));
typedef float f32x4 __attribute__((ext_vector_type(4)));
typedef uint32_t u32;

#define DM 1024
#define NH 16
#define HD 64
#define SEQ 1024
#define BB 8
#define BS (BB*SEQ)      /* 8192 tokens */
#define NBH (BB*NH)      /* 128 (b,h) pairs */
#define NE 4
#define DFE 1024
#define QB 64            /* query rows per attention chunk */
#define NCHUNK (SEQ/QB)  /* 16 */
#define LDK 40           /* padded LDS row (h16) for f16 core */

// ---- workspace layout (bytes) ----
static constexpr size_t SZF     = (size_t)BS*DM*4;          // 33,554,432
static constexpr size_t OFF_QK  = 0;                        // qk = src+pos (fp32)
static constexpr size_t OFF_S   = 0;                        // scores chunk (qk dead)
static constexpr size_t OFF_ATT = 0;                        // attn fp32 (S dead)
static constexpr size_t OFF_YSEL= 0;                        // moe out (attn dead)
static constexpr size_t OFF_Q   = SZF;                      // Q fp32 [bh][s][d]
static constexpr size_t OFF_XH  = SZF;                      // x*16 f16 (Q dead)
static constexpr size_t OFF_K   = 2*SZF;                    // K fp32
static constexpr size_t OFF_W1H = 2*SZF;                    // w1*64 f16 (K dead)
static constexpr size_t OFF_W2H = 2*SZF + (size_t)NE*DFE*DM*2;
static constexpr size_t OFF_V   = 3*SZF;                    // V^T fp32 [bh][d][s]
static constexpr size_t OFF_HH  = 3*SZF;                    // h f16 [8192][4096] (V,P dead)
static constexpr size_t OFF_P   = 4*SZF;                    // P chunk fp32
static constexpr size_t OFF_O   = 5*SZF;                    // attn heads out fp32
static constexpr size_t OFF_X   = 5*SZF;                    // LN1 out fp32 (O dead)
static constexpr size_t OFF_PART= 6*SZF;                    // PV k-split partials
static constexpr size_t PART_B  = (size_t)4*NBH*QB*HD*4;    // 8,388,608
static constexpr size_t OFF_CHOSEN = OFF_PART + PART_B;
static constexpr size_t WS_NEEDED  = OFF_CHOSEN + (size_t)BS*4;

// ---------------------------------------------------------------------------
__device__ __forceinline__ float wave_sum(float v) {
  #pragma unroll
  for (int o = 32; o; o >>= 1) v += __shfl_xor(v, o);
  return v;
}
__device__ __forceinline__ float wave_max(float v) {
  #pragma unroll
  for (int o = 32; o; o >>= 1) v = fmaxf(v, __shfl_xor(v, o));
  return v;
}

// ---------------------------------------------------------------------------
// fp32 NT SGEMM core: C(64x64) = A(M,K;lda) * B(N,K;ldb)^T at tile (m0,n0).
// 256 threads, each computes a 4x4 micro-tile; K staged 16 at a time with
// LDS transpose so inner loop reads are contiguous float4.
// ---------------------------------------------------------------------------
__device__ __forceinline__ void sgemm_core(
    const float* __restrict__ A, const float* __restrict__ B,
    int K, int lda, int ldb, int m0, int n0,
    float (&acc)[4][4], float* sAT, float* sBT)   // each [16][68]
{
  const int tid = threadIdx.x;
  const int lr = tid >> 2;            // 0..63
  const int lk = (tid & 3) << 2;      // 0,4,8,12
  const int ty = tid >> 4, tx = tid & 15;
  const long abase = (long)(m0 + lr) * lda + lk;
  const long bbase = (long)(n0 + lr) * ldb + lk;
  for (int k0 = 0; k0 < K; k0 += 16) {
    __syncthreads();
    float4 va = *(const float4*)(A + abase + k0);
    float4 vb = *(const float4*)(B + bbase + k0);
    sAT[(lk+0)*68 + lr] = va.x; sAT[(lk+1)*68 + lr] = va.y;
    sAT[(lk+2)*68 + lr] = va.z; sAT[(lk+3)*68 + lr] = va.w;
    sBT[(lk+0)*68 + lr] = vb.x; sBT[(lk+1)*68 + lr] = vb.y;
    sBT[(lk+2)*68 + lr] = vb.z; sBT[(lk+3)*68 + lr] = vb.w;
    __syncthreads();
    #pragma unroll
    for (int kk = 0; kk < 16; ++kk) {
      float4 a = *(const float4*)(sAT + kk*68 + ty*4);
      float4 b = *(const float4*)(sBT + kk*68 + tx*4);
      float av[4] = {a.x, a.y, a.z, a.w};
      float bv[4] = {b.x, b.y, b.z, b.w};
      #pragma unroll
      for (int i = 0; i < 4; ++i)
        #pragma unroll
        for (int j = 0; j < 4; ++j)
          acc[i][j] = fmaf(av[i], bv[j], acc[i][j]);
    }
  }
}

#define SG_SHARED __shared__ float sAT[16*68], sBT[16*68]
#define SG_EPI const int ty = threadIdx.x >> 4, tx = threadIdx.x & 15

// ---------------------------------------------------------------------------
// f16 MFMA core (dense NT): C(64x64) = A(M,K;lda)*B(N,K;ldb)^T, 4 waves 2x2,
// each wave 32x32 of 2x2 mfma_f32_16x16x32_f16 fragments.
// A/B frag: idx16 = lane&15, k = (lane>>4)*8 + j. D: col=lane&15, row=(lane>>4)*4+r.
// ---------------------------------------------------------------------------
__device__ __forceinline__ void hgemm_core(
    const h16* __restrict__ A, const h16* __restrict__ B,
    int K, int lda, int ldb, int m0, int n0,
    f32x4 (&acc)[2][2], h16* lds)
{
  const int tid = threadIdx.x, lane = tid & 63, wave = tid >> 6;
  const int wm = (wave >> 1) * 32, wn = (wave & 1) * 32;
  h16* sA = lds; h16* sB = lds + 64*LDK;
  const int srow = tid >> 2, skc = (tid & 3) << 3;
  const long arow = (long)(m0 + srow) * lda + skc;
  const long brow = (long)(n0 + srow) * ldb + skc;
  const int fr = lane & 15, kg = (lane >> 4) << 3;
  for (int k0 = 0; k0 < K; k0 += 32) {
    __syncthreads();
    *(uint4*)(sA + srow*LDK + skc) = *(const uint4*)(A + arow + k0);
    *(uint4*)(sB + srow*LDK + skc) = *(const uint4*)(B + brow + k0);
    __syncthreads();
    #pragma unroll
    for (int i = 0; i < 2; ++i) {
      h16x8 ah = *(const h16x8*)(sA + (wm + i*16 + fr)*LDK + kg);
      #pragma unroll
      for (int j = 0; j < 2; ++j) {
        h16x8 bh = *(const h16x8*)(sB + (wn + j*16 + fr)*LDK + kg);
        acc[i][j] = __builtin_amdgcn_mfma_f32_16x16x32_f16(ah, bh, acc[i][j], 0, 0, 0);
      }
    }
  }
}

#define HG_EPI \
  const int lane = threadIdx.x & 63, wave = threadIdx.x >> 6; \
  const int wm = (wave>>1)*32, wn = (wave&1)*32; \
  const int fr = lane & 15, rb = (lane>>4)*4;

// ---------------------------------------------------------------------------
__global__ void k_add(const float* __restrict__ a, const float* __restrict__ b,
                      float* __restrict__ o) {
  long i = (long)blockIdx.x*256 + threadIdx.x;
  float4 va = ((const float4*)a)[i], vb = ((const float4*)b)[i];
  float4 r = {va.x+vb.x, va.y+vb.y, va.z+vb.z, va.w+vb.w};
  ((float4*)o)[i] = r;
}

__global__ void k_tof16(const float* __restrict__ a, h16* __restrict__ H, float scale, int n4) {
  int i = blockIdx.x*256 + threadIdx.x;
  if (i >= n4) return;
  float4 v = ((const float4*)a)[i];
  h16x4 hv;
  hv[0] = (h16)(v.x*scale); hv[1] = (h16)(v.y*scale);
  hv[2] = (h16)(v.z*scale); hv[3] = (h16)(v.w*scale);
  ((h16x4*)H)[i] = hv;
}

// QKV projection fp32: rows over tokens, cols over [q|k|v] x 1024.
__global__ __launch_bounds__(256) void k_qkv32(
    const float* __restrict__ qk, const float* __restrict__ src,
    const float* __restrict__ W, const float* __restrict__ bias,
    float* __restrict__ Q, float* __restrict__ K, float* __restrict__ V)
{
  SG_SHARED;
  const int n0 = blockIdx.x*64, m0 = blockIdx.y*64;
  const float* Ap = (n0 >= 2048) ? src : qk;
  float acc[4][4] = {};
  sgemm_core(Ap, W, 1024, 1024, 1024, m0, n0, acc, sAT, sBT);
  SG_EPI;
  #pragma unroll
  for (int i = 0; i < 4; ++i)
    #pragma unroll
    for (int j = 0; j < 4; ++j) {
      int row = m0 + ty*4 + i;
      int col = n0 + tx*4 + j;
      float c = acc[i][j] + bias[col];
      int b = row >> 10, s = row & 1023;
      int cc = col & 1023, h = cc >> 6, d = cc & 63;
      long bh = (long)b*NH + h;
      if (col < 1024)      Q[(bh*SEQ + s)*HD + d] = c;
      else if (col < 2048) K[(bh*SEQ + s)*HD + d] = c;
      else                 V[(bh*HD + d)*SEQ + s] = c;
    }
}

// scores chunk fp32: S[bh][m][n] = (Q[bh][q0+m,:] . K[bh][n,:]) / 8
__global__ __launch_bounds__(256) void k_scores32(
    const float* __restrict__ Q, const float* __restrict__ K,
    float* __restrict__ S, int q0)
{
  SG_SHARED;
  const int n0 = blockIdx.x*64;
  const int bh = blockIdx.z;
  const long base = (long)bh*SEQ*HD;
  float acc[4][4] = {};
  sgemm_core(Q + base, K + base, HD, HD, HD, q0, n0, acc, sAT, sBT);
  SG_EPI;
  #pragma unroll
  for (int i = 0; i < 4; ++i)
    #pragma unroll
    for (int j = 0; j < 4; ++j)
      S[((long)bh*QB + ty*4 + i)*SEQ + n0 + tx*4 + j] = acc[i][j] * 0.125f;
}

// row softmax over 1024 (fp32 in/out)
__global__ __launch_bounds__(256) void k_softmax32(const float* __restrict__ S,
                                                   float* __restrict__ P) {
  int wave = threadIdx.x >> 6, lane = threadIdx.x & 63;
  long row = (long)blockIdx.x*4 + wave;
  const float* sr = S + row*SEQ;
  float v[16]; float mx = -3.0e38f;
  #pragma unroll
  for (int p = 0; p < 4; ++p) {
    int d = p*256 + lane*4;
    float4 a = *(const float4*)(sr + d);
    v[4*p+0]=a.x; v[4*p+1]=a.y; v[4*p+2]=a.z; v[4*p+3]=a.w;
    mx = fmaxf(mx, fmaxf(fmaxf(a.x,a.y), fmaxf(a.z,a.w)));
  }
  mx = wave_max(mx);
  float s = 0.0f;
  #pragma unroll
  for (int i = 0; i < 16; ++i) { float e = expf(v[i]-mx); v[i]=e; s += e; }
  s = wave_sum(s);
  float inv = 1.0f / s;
  #pragma unroll
  for (int p = 0; p < 4; ++p) {
    int d = p*256 + lane*4;
    float4 o = {v[4*p+0]*inv, v[4*p+1]*inv, v[4*p+2]*inv, v[4*p+3]*inv};
    *(float4*)(P + row*SEQ + d) = o;
  }
}

// PV fp32, K split in 4 segments of 256 (deterministic partials)
__global__ __launch_bounds__(256) void k_pv32(
    const float* __restrict__ P, const float* __restrict__ V, float* __restrict__ part)
{
  SG_SHARED;
  int z = blockIdx.z; int bh = z >> 2, ks = z & 3;
  const float* Ap = P + (long)bh*QB*SEQ + ks*256;
  const float* Bp = V + (long)bh*HD*SEQ + ks*256;
  float acc[4][4] = {};
  sgemm_core(Ap, Bp, 256, SEQ, SEQ, 0, 0, acc, sAT, sBT);
  SG_EPI;
  #pragma unroll
  for (int i = 0; i < 4; ++i)
    #pragma unroll
    for (int j = 0; j < 4; ++j)
      part[(((long)ks*NBH + bh)*QB + ty*4 + i)*HD + tx*4 + j] = acc[i][j];
}

__global__ void k_pvred32(const float* __restrict__ part, float* __restrict__ O, int q0) {
  long id = (long)blockIdx.x*256 + threadIdx.x;   // < NBH*QB*HD
  int d = (int)(id & 63); long r = id >> 6;
  int m = (int)(r % QB); int bh = (int)(r / QB);
  const long st = (long)NBH*QB*HD;
  float o = part[id] + part[id+st] + part[id+2*st] + part[id+3*st];
  int b = bh >> 4, h = bh & 15;
  long tok = (long)b*SEQ + q0 + m;
  O[tok*DM + h*HD + d] = o;
}

// out_proj fp32: attn[t,i] = O[t,:] . wo[i,:] + bo[i]
__global__ __launch_bounds__(256) void k_outproj32(
    const float* __restrict__ O, const float* __restrict__ W,
    const float* __restrict__ bias, float* __restrict__ attn)
{
  SG_SHARED;
  const int n0 = blockIdx.x*64, m0 = blockIdx.y*64;
  float acc[4][4] = {};
  sgemm_core(O, W, 1024, 1024, 1024, m0, n0, acc, sAT, sBT);
  SG_EPI;
  #pragma unroll
  for (int i = 0; i < 4; ++i)
    #pragma unroll
    for (int j = 0; j < 4; ++j) {
      int row = m0 + ty*4 + i, col = n0 + tx*4 + j;
      attn[(long)row*DM + col] = acc[i][j] + bias[col];
    }
}

// LayerNorm over D=1024 of (A + Badd); optional fp32 out, f16(x*16) out, direct out
__global__ __launch_bounds__(256) void k_ln(
    const float* __restrict__ A, const float* __restrict__ Badd,
    const float* __restrict__ g, const float* __restrict__ be,
    float* __restrict__ xout, h16* __restrict__ xh, float* __restrict__ dout)
{
  int wave = threadIdx.x >> 6, lane = threadIdx.x & 63;
  long row = (long)blockIdx.x*4 + wave;
  const float* ar = A + row*DM; const float* br = Badd + row*DM;
  float v[16]; float s = 0.0f;
  #pragma unroll
  for (int p = 0; p < 4; ++p) {
    int d = p*256 + lane*4;
    float4 a = *(const float4*)(ar + d);
    float4 b = *(const float4*)(br + d);
    float t0=a.x+b.x, t1=a.y+b.y, t2=a.z+b.z, t3=a.w+b.w;
    v[4*p+0]=t0; v[4*p+1]=t1; v[4*p+2]=t2; v[4*p+3]=t3;
    s += t0+t1+t2+t3;
  }
  s = wave_sum(s);
  float m = s * (1.0f/1024.0f);
  float q = 0.0f;
  #pragma unroll
  for (int i = 0; i < 16; ++i) { float dd = v[i]-m; q += dd*dd; }
  q = wave_sum(q);
  float rs = (float)(1.0 / sqrt((double)(q * (1.0f/1024.0f) + 1e-5f)));
  #pragma unroll
  for (int p = 0; p < 4; ++p) {
    int d = p*256 + lane*4;
    float4 gv = *(const float4*)(g + d);
    float4 bv = *(const float4*)(be + d);
    float y0 = (v[4*p+0]-m)*rs*gv.x + bv.x;
    float y1 = (v[4*p+1]-m)*rs*gv.y + bv.y;
    float y2 = (v[4*p+2]-m)*rs*gv.z + bv.z;
    float y3 = (v[4*p+3]-m)*rs*gv.w + bv.w;
    if (xout) { float4 o = {y0,y1,y2,y3}; *(float4*)(xout + row*DM + d) = o; }
    if (xh) {
      h16x4 hv; hv[0]=(h16)(y0*16.f); hv[1]=(h16)(y1*16.f);
      hv[2]=(h16)(y2*16.f); hv[3]=(h16)(y3*16.f);
      *(h16x4*)(xh + row*DM + d) = hv;
    }
    if (dout) { float4 o = {y0,y1,y2,y3}; *(float4*)(dout + row*DM + d) = o; }
  }
}

// ---------------------------------------------------------------------------
// threefry2x32 (key=[0,42]) -> gumbel -> argmax expert choice.
// jax_threefry_partitionable=True, bit_width=32:
//   (b1,b2) = threefry2x32(key, counts_hi, counts_lo) with counts = 64b iota
//   bits = b1 ^ b2        (jax/_src/prng.py, partitionable path)
// ---------------------------------------------------------------------------
__device__ __forceinline__ void threefry(u32 x0, u32 x1, u32& y0, u32& y1) {
  const u32 ks0 = 0u, ks1 = 42u, ks2 = 0x1BD11BDAu ^ 42u;
  x0 += ks0; x1 += ks1;
  #define TF_R(r) { x0 += x1; x1 = (x1 << r) | (x1 >> (32 - r)); x1 ^= x0; }
  TF_R(13) TF_R(15) TF_R(26) TF_R(6)  x0 += ks1; x1 += ks2 + 1u;
  TF_R(17) TF_R(29) TF_R(16) TF_R(24) x0 += ks2; x1 += ks0 + 2u;
  TF_R(13) TF_R(15) TF_R(26) TF_R(6)  x0 += ks0; x1 += ks1 + 3u;
  TF_R(17) TF_R(29) TF_R(16) TF_R(24) x0 += ks1; x1 += ks2 + 4u;
  TF_R(13) TF_R(15) TF_R(26) TF_R(6)  x0 += ks2; x1 += ks0 + 5u;
  #undef TF_R
  y0 = x0; y1 = x1;
}

__device__ __forceinline__ float gumbel_from(u32 bits) {
  float f = __uint_as_float((bits >> 9) | 0x3F800000u) - 1.0f;
  float u = (f > 0.0f) ? f : 1.17549435e-38f;
  float nl = (float)(-log((double)u));       // fp32-rounded inner, like reference
  return -(float)log((double)nl);
}

__global__ __launch_bounds__(256) void k_gate(
    const float* __restrict__ x, const float* __restrict__ gw,
    const float* __restrict__ gb, int* __restrict__ chosen)
{
  int wave = threadIdx.x >> 6, lane = threadIdx.x & 63;
  long t = (long)blockIdx.x*4 + wave;
  const float* xr = x + t*DM;
  float p[4] = {0.f,0.f,0.f,0.f};
  #pragma unroll
  for (int pp = 0; pp < 4; ++pp) {
    int d = pp*256 + lane*4;
    float4 xv = *(const float4*)(xr + d);
    #pragma unroll
    for (int e = 0; e < 4; ++e) {
      float4 gv = *(const float4*)(gw + e*DM + d);
      p[e] += xv.x*gv.x + xv.y*gv.y + xv.z*gv.z + xv.w*gv.w;
    }
  }
  #pragma unroll
  for (int e = 0; e < 4; ++e) p[e] = wave_sum(p[e]);
  if (lane == 0) {
    float best = -3.0e38f; int arg = 0;
    #pragma unroll
    for (int e = 0; e < 4; ++e) {
      float logit = p[e] + gb[e];
      u32 j = (u32)(4*t + e);          // flat 64b iota (< 2^32): counter = (0, j)
      u32 y0, y1;
      threefry(0u, j, y0, y1);
      float v = gumbel_from(y0 ^ y1) + logit;   // partitionable 32-bit: b1 ^ b2
      if (v > best) { best = v; arg = e; }   // strict > == argmax first-max rule
    }
    chosen[(int)t] = arg;
  }
}

// MoE layer 1 dense: h[t, e*1024+f] = relu(x.w1[e][f] + b1[e][f]), f16 MFMA
__global__ __launch_bounds__(256) void k_e1(
    const h16* __restrict__ Xh, const h16* __restrict__ W1,
    const float* __restrict__ b1, h16* __restrict__ Hh)
{
  __shared__ h16 lds[2*64*LDK];
  const int n0 = blockIdx.x*64, m0 = blockIdx.y*64;
  f32x4 acc[2][2] = {};
  hgemm_core(Xh, W1, 1024, 1024, 1024, m0, n0, acc, lds);
  HG_EPI;
  #pragma unroll
  for (int i = 0; i < 2; ++i)
    #pragma unroll
    for (int j = 0; j < 2; ++j)
      #pragma unroll
      for (int r = 0; r < 4; ++r) {
        int row = m0 + wm + i*16 + rb + r;
        int col = n0 + wn + j*16 + fr;
        float c = acc[i][j][r] * (1.0f/1024.0f) + b1[col];
        c = fmaxf(c, 0.0f);
        Hh[(long)row*(NE*DFE) + col] = (h16)(c * 16.0f);
      }
}

// MoE layer 2 block-diagonal dense + select: y[t] = h[t,e*1024:] . w2[e]^T + b2[e]
__global__ __launch_bounds__(256) void k_e2(
    const h16* __restrict__ Hh, const h16* __restrict__ W2,
    const float* __restrict__ b2, const int* __restrict__ chosen,
    float* __restrict__ y)
{
  __shared__ h16 lds[2*64*LDK];
  const int n0 = blockIdx.x*64, m0 = blockIdx.y*64;
  const int e = blockIdx.z;
  f32x4 acc[2][2] = {};
  hgemm_core(Hh + (long)e*DFE, W2 + (long)e*DM*DFE, 1024, NE*DFE, DFE, m0, n0, acc, lds);
  HG_EPI;
  #pragma unroll
  for (int i = 0; i < 2; ++i)
    #pragma unroll
    for (int j = 0; j < 2; ++j)
      #pragma unroll
      for (int r = 0; r < 4; ++r) {
        int row = m0 + wm + i*16 + rb + r;
        int col = n0 + wn + j*16 + fr;
        if (chosen[row] == e)
          y[(long)row*DM + col] = acc[i][j][r] * (1.0f/1024.0f) + b2[e*DM + col];
      }
}

// ---------------------------------------------------------------------------
extern "C" void kernel_launch(void* const* d_in, const int* in_sizes, int n_in,
                              void* d_out, int out_size, void* d_ws, size_t ws_size,
                              hipStream_t stream) {
  const float* src = (const float*)d_in[0];
  const float* pos = (const float*)d_in[1];
  const float* w3  = (const float*)d_in[2];
  const float* b3  = (const float*)d_in[3];
  const float* wo  = (const float*)d_in[4];
  const float* bo  = (const float*)d_in[5];
  const float* gw  = (const float*)d_in[6];
  const float* gb  = (const float*)d_in[7];
  const float* w1  = (const float*)d_in[8];
  const float* b1  = (const float*)d_in[9];
  const float* w2  = (const float*)d_in[10];
  const float* b2  = (const float*)d_in[11];
  const float* g1  = (const float*)d_in[12];
  const float* be1 = (const float*)d_in[13];
  const float* g2  = (const float*)d_in[14];
  const float* be2 = (const float*)d_in[15];
  float* out = (float*)d_out;
  char* ws = (char*)d_ws;
  if (ws_size < WS_NEEDED) return;

  auto H = [&](size_t off) { return (h16*)(ws + off); };
  auto F = [&](size_t off) { return (float*)(ws + off); };
  auto I = [&](size_t off) { return (int*)(ws + off); };

  // qk = src + pos
  k_add<<<BS*DM/4/256, 256, 0, stream>>>(src, pos, F(OFF_QK));

  // QKV projection (fp32)
  k_qkv32<<<dim3(48, 128), 256, 0, stream>>>(
      F(OFF_QK), src, w3, b3, F(OFF_Q), F(OFF_K), F(OFF_V));

  // attention, chunked over query rows (all fp32)
  for (int qc = 0; qc < NCHUNK; ++qc) {
    int q0 = qc * QB;
    k_scores32<<<dim3(16, 1, NBH), 256, 0, stream>>>(
        F(OFF_Q), F(OFF_K), F(OFF_S), q0);
    k_softmax32<<<NBH*QB/4, 256, 0, stream>>>(F(OFF_S), F(OFF_P));
    k_pv32<<<dim3(1, 1, NBH*4), 256, 0, stream>>>(
        F(OFF_P), F(OFF_V), F(OFF_PART));
    k_pvred32<<<NBH*QB*HD/256, 256, 0, stream>>>(F(OFF_PART), F(OFF_O), q0);
  }

  // out projection + LN1
  k_outproj32<<<dim3(16, 128), 256, 0, stream>>>(F(OFF_O), wo, bo, F(OFF_ATT));
  k_ln<<<BS/4, 256, 0, stream>>>(src, F(OFF_ATT), g1, be1, F(OFF_X), H(OFF_XH), nullptr);

  // gate -> chosen expert per token (partitionable threefry: b1^b2)
  k_gate<<<BS/4, 256, 0, stream>>>(F(OFF_X), gw, gb, I(OFF_CHOSEN));

  // MoE FFN dense all-expert (f16 MFMA) + select
  k_tof16<<<NE*DFE*DM/4/256, 256, 0, stream>>>(w1, H(OFF_W1H), 64.0f, NE*DFE*DM/4);
  k_tof16<<<NE*DM*DFE/4/256, 256, 0, stream>>>(w2, H(OFF_W2H), 64.0f, NE*DM*DFE/4);
  k_e1<<<dim3(64, 128), 256, 0, stream>>>(H(OFF_XH), H(OFF_W1H), b1, H(OFF_HH));
  k_e2<<<dim3(16, 128, NE), 256, 0, stream>>>(
      H(OFF_HH), H(OFF_W2H), b2, I(OFF_CHOSEN), F(OFF_YSEL));

  // final LN2 -> output
  k_ln<<<BS/4, 256, 0, stream>>>(F(OFF_X), F(OFF_YSEL), g2, be2, nullptr, nullptr, out);
}

// Round 6
// 1589.917 us; speedup vs baseline: 1.4041x; 1.4041x over previous
//
#include <hip/hip_runtime.h>
#include <cstdint>
#include <cstddef>

// ---------------------------------------------------------------------------
// TransformerEncoderLayer on MI355X (gfx950).
// Pre-gate path on MFMA via f16 hi/lo split (Markidis, 3 mfma per product):
//   x ~ (hi + lo/4096)/s ; per-product residual ~2^-23 -> fp32-level accuracy.
//   (Empirically validated: wrong-RNG rounds with split vs fp32 pipelines gave
//    bit-identical outputs -> identical expert routing on this dataset.)
// Gate RNG: jax_threefry_partitionable categorical, bits = b1 ^ b2 (VERIFIED).
// MoE FFN dense all-expert f16 MFMA + select (error ~1e-3 << threshold).
// ---------------------------------------------------------------------------

typedef _Float16 h16;
typedef h16 h16x8 __attribute__((ext_vector_type(8)));
typedef h16 h16x4 __attribute__((ext_vector_type(4)));
typedef float f32x4 __attribute__((ext_vector_type(4)));
typedef uint32_t u32;

#define DM 1024
#define NH 16
#define HD 64
#define SEQ 1024
#define BB 8
#define BS (BB*SEQ)      /* 8192 tokens */
#define NBH (BB*NH)      /* 128 (b,h) pairs */
#define NE 4
#define DFE 1024
#define QB 64            /* query rows per attention chunk */
#define NCHUNK (SEQ/QB)  /* 16 */
#define LDK 40           /* padded LDS row (h16): 80B stride -> 2-way bank alias (free) */

// ---- workspace layout (bytes). E = one h16 plane of [8192][1024]. ----
static constexpr size_t E = (size_t)BS*DM*2;            // 16,777,216
static constexpr size_t OFF_QKH = 0;                    // qk split (dead after qkv)
static constexpr size_t OFF_QKL = E;
static constexpr size_t OFF_SRCH= 2*E;                  // src split (dead after qkv)
static constexpr size_t OFF_SRCL= 3*E;
static constexpr size_t OFF_W3H = 4*E;                  // in_proj split (12.6MB)
static constexpr size_t OFF_W3L = 4*E + (size_t)3*DM*DM*2;
static constexpr size_t OFF_WOH = 4*E + (size_t)6*DM*DM*2;   // out_proj split (4.2MB)
static constexpr size_t OFF_WOL = 4*E + (size_t)7*DM*DM*2;   // ends at 5E exactly
static constexpr size_t OFF_QH  = 5*E;                  // Q,K,V splits [bh][s][d] / V^T [bh][d][s]
static constexpr size_t OFF_QL  = 6*E;
static constexpr size_t OFF_KH  = 7*E;
static constexpr size_t OFF_KL  = 8*E;
static constexpr size_t OFF_VH  = 9*E;
static constexpr size_t OFF_VL  = 10*E;
static constexpr size_t OFF_S   = 11*E;                 // scores chunk fp32 (2E)
static constexpr size_t OFF_PH  = 13*E;                 // P split per chunk
static constexpr size_t OFF_PL  = 14*E;
static constexpr size_t OFF_PART= 15*E;                 // PV k-split partials (E/2)
static constexpr size_t OFF_OH  = 0;                    // O split (QK region dead)
static constexpr size_t OFF_OL  = E;
static constexpr size_t OFF_ATT = 2*E;                  // attn fp32 (src splits dead)
static constexpr size_t OFF_X   = 13*E;                 // LN1 out fp32 (P dead)
static constexpr size_t OFF_XH  = 11*E;                 // x*16 f16 (S dead)
static constexpr size_t OFF_W1H = 12*E;                 // w1 f16 (S upper dead)
static constexpr size_t OFF_W2H = 12*E + (size_t)NE*DFE*DM*2;
static constexpr size_t OFF_HH  = 5*E;                  // h f16 [8192][4096] (Q..KL dead)
static constexpr size_t OFF_YSEL= 9*E;                  // moe out fp32 (V dead)
static constexpr size_t OFF_CHOSEN = 15*E + E/2;
static constexpr size_t WS_NEEDED  = OFF_CHOSEN + (size_t)BS*4;   // ~260MB (round-0-proven size)

// ---------------------------------------------------------------------------
__device__ __forceinline__ void store_split(h16* H, h16* L, size_t idx, float v) {
  h16 h = (h16)v;
  H[idx] = h;
  L[idx] = (h16)((v - (float)h) * 4096.0f);
}

__device__ __forceinline__ float wave_sum(float v) {
  #pragma unroll
  for (int o = 32; o; o >>= 1) v += __shfl_xor(v, o);
  return v;
}
__device__ __forceinline__ float wave_max(float v) {
  #pragma unroll
  for (int o = 32; o; o >>= 1) v = fmaxf(v, __shfl_xor(v, o));
  return v;
}

// ---------------------------------------------------------------------------
// 64x64 split-f16 MFMA core (round-1, numerics validated vs fp32):
// C = A(M,K;lda) * B(N,K;ldb)^T. 4 waves 2x2, each 32x32 = 2x2 frags 16x16x32.
// ---------------------------------------------------------------------------
__device__ __forceinline__ void gemm64_core(
    const h16* __restrict__ Ah, const h16* __restrict__ Al,
    const h16* __restrict__ Bh, const h16* __restrict__ Bl,
    int K, int lda, int ldb, int m0, int n0,
    f32x4 (&a1)[2][2], f32x4 (&a2)[2][2], h16* lds)
{
  const int tid = threadIdx.x, lane = tid & 63, wave = tid >> 6;
  const int wm = (wave >> 1) * 32, wn = (wave & 1) * 32;
  h16* sA  = lds;              h16* sB  = lds + 64*LDK;
  h16* sA2 = lds + 2*64*LDK;   h16* sB2 = lds + 3*64*LDK;
  const int srow = tid >> 2, skc = (tid & 3) << 3;
  const long arow = (long)(m0 + srow) * lda + skc;
  const long brow = (long)(n0 + srow) * ldb + skc;
  const int fr = lane & 15, kg = (lane >> 4) << 3;
  for (int k0 = 0; k0 < K; k0 += 32) {
    __syncthreads();
    *(uint4*)(sA  + srow*LDK + skc) = *(const uint4*)(Ah + arow + k0);
    *(uint4*)(sB  + srow*LDK + skc) = *(const uint4*)(Bh + brow + k0);
    *(uint4*)(sA2 + srow*LDK + skc) = *(const uint4*)(Al + arow + k0);
    *(uint4*)(sB2 + srow*LDK + skc) = *(const uint4*)(Bl + brow + k0);
    __syncthreads();
    #pragma unroll
    for (int i = 0; i < 2; ++i) {
      h16x8 ah = *(const h16x8*)(sA  + (wm + i*16 + fr)*LDK + kg);
      h16x8 al = *(const h16x8*)(sA2 + (wm + i*16 + fr)*LDK + kg);
      #pragma unroll
      for (int j = 0; j < 2; ++j) {
        h16x8 bh = *(const h16x8*)(sB  + (wn + j*16 + fr)*LDK + kg);
        h16x8 bl = *(const h16x8*)(sB2 + (wn + j*16 + fr)*LDK + kg);
        a1[i][j] = __builtin_amdgcn_mfma_f32_16x16x32_f16(ah, bh, a1[i][j], 0, 0, 0);
        a2[i][j] = __builtin_amdgcn_mfma_f32_16x16x32_f16(ah, bl, a2[i][j], 0, 0, 0);
        a2[i][j] = __builtin_amdgcn_mfma_f32_16x16x32_f16(al, bh, a2[i][j], 0, 0, 0);
      }
    }
  }
}

#define EPI64 \
  const int lane = threadIdx.x & 63, wave = threadIdx.x >> 6; \
  const int wm = (wave>>1)*32, wn = (wave&1)*32; \
  const int fr = lane & 15, rb = (lane>>4)*4;

// ---------------------------------------------------------------------------
// 128x128 split-f16 MFMA core: 4 waves 2x2, each 64x64 = 4x4 frags 16x16x32.
// 48 MFMA : 16 ds_read_b128 per wave per K-step. LDS 40KB.
// ---------------------------------------------------------------------------
__device__ __forceinline__ void gemm128_core(
    const h16* __restrict__ Ah, const h16* __restrict__ Al,
    const h16* __restrict__ Bh, const h16* __restrict__ Bl,
    int K, int lda, int ldb, int m0, int n0,
    f32x4 (&a1)[4][4], f32x4 (&a2)[4][4], h16* lds)
{
  const int tid = threadIdx.x, lane = tid & 63, wave = tid >> 6;
  const int wr = (wave >> 1) * 64, wc = (wave & 1) * 64;
  h16* sAh = lds;                h16* sAl = lds + 128*LDK;
  h16* sBh = lds + 2*128*LDK;    h16* sBl = lds + 3*128*LDK;
  const int srow = tid >> 1, skc = (tid & 1) * 16;   // 2 threads/row, 16 h16 each
  const long abase = (long)(m0 + srow) * lda + skc;
  const long bbase = (long)(n0 + srow) * ldb + skc;
  const int fr = lane & 15, kg = (lane >> 4) << 3;
  for (int k0 = 0; k0 < K; k0 += 32) {
    __syncthreads();
    *(uint4*)(sAh + srow*LDK + skc)     = *(const uint4*)(Ah + abase + k0);
    *(uint4*)(sAh + srow*LDK + skc + 8) = *(const uint4*)(Ah + abase + k0 + 8);
    *(uint4*)(sAl + srow*LDK + skc)     = *(const uint4*)(Al + abase + k0);
    *(uint4*)(sAl + srow*LDK + skc + 8) = *(const uint4*)(Al + abase + k0 + 8);
    *(uint4*)(sBh + srow*LDK + skc)     = *(const uint4*)(Bh + bbase + k0);
    *(uint4*)(sBh + srow*LDK + skc + 8) = *(const uint4*)(Bh + bbase + k0 + 8);
    *(uint4*)(sBl + srow*LDK + skc)     = *(const uint4*)(Bl + bbase + k0);
    *(uint4*)(sBl + srow*LDK + skc + 8) = *(const uint4*)(Bl + bbase + k0 + 8);
    __syncthreads();
    h16x8 ah[4], al[4], bh[4], bl[4];
    #pragma unroll
    for (int i = 0; i < 4; ++i) {
      ah[i] = *(const h16x8*)(sAh + (wr + i*16 + fr)*LDK + kg);
      al[i] = *(const h16x8*)(sAl + (wr + i*16 + fr)*LDK + kg);
    }
    #pragma unroll
    for (int j = 0; j < 4; ++j) {
      bh[j] = *(const h16x8*)(sBh + (wc + j*16 + fr)*LDK + kg);
      bl[j] = *(const h16x8*)(sBl + (wc + j*16 + fr)*LDK + kg);
    }
    #pragma unroll
    for (int i = 0; i < 4; ++i)
      #pragma unroll
      for (int j = 0; j < 4; ++j) {
        a1[i][j] = __builtin_amdgcn_mfma_f32_16x16x32_f16(ah[i], bh[j], a1[i][j], 0, 0, 0);
        a2[i][j] = __builtin_amdgcn_mfma_f32_16x16x32_f16(ah[i], bl[j], a2[i][j], 0, 0, 0);
        a2[i][j] = __builtin_amdgcn_mfma_f32_16x16x32_f16(al[i], bh[j], a2[i][j], 0, 0, 0);
      }
  }
}

#define EPI128 \
  const int lane = threadIdx.x & 63, wave = threadIdx.x >> 6; \
  const int wr = (wave>>1)*64, wc = (wave&1)*64; \
  const int fr = lane & 15, rb = (lane>>4)*4;

// ---------------------------------------------------------------------------
// f16 single MFMA core (dense NT) for MoE — verified (round 5).
// ---------------------------------------------------------------------------
__device__ __forceinline__ void hgemm_core(
    const h16* __restrict__ A, const h16* __restrict__ B,
    int K, int lda, int ldb, int m0, int n0,
    f32x4 (&acc)[2][2], h16* lds)
{
  const int tid = threadIdx.x, lane = tid & 63, wave = tid >> 6;
  const int wm = (wave >> 1) * 32, wn = (wave & 1) * 32;
  h16* sA = lds; h16* sB = lds + 64*LDK;
  const int srow = tid >> 2, skc = (tid & 3) << 3;
  const long arow = (long)(m0 + srow) * lda + skc;
  const long brow = (long)(n0 + srow) * ldb + skc;
  const int fr = lane & 15, kg = (lane >> 4) << 3;
  for (int k0 = 0; k0 < K; k0 += 32) {
    __syncthreads();
    *(uint4*)(sA + srow*LDK + skc) = *(const uint4*)(A + arow + k0);
    *(uint4*)(sB + srow*LDK + skc) = *(const uint4*)(B + brow + k0);
    __syncthreads();
    #pragma unroll
    for (int i = 0; i < 2; ++i) {
      h16x8 ah = *(const h16x8*)(sA + (wm + i*16 + fr)*LDK + kg);
      #pragma unroll
      for (int j = 0; j < 2; ++j) {
        h16x8 bh = *(const h16x8*)(sB + (wn + j*16 + fr)*LDK + kg);
        acc[i][j] = __builtin_amdgcn_mfma_f32_16x16x32_f16(ah, bh, acc[i][j], 0, 0, 0);
      }
    }
  }
}

// ---------------------------------------------------------------------------
// split / convert kernels
// ---------------------------------------------------------------------------
__global__ void k_split2(const float* __restrict__ a, const float* __restrict__ b,
                         h16* __restrict__ H, h16* __restrict__ L, float scale, int n4) {
  int i = blockIdx.x*256 + threadIdx.x;
  if (i >= n4) return;
  float4 v = ((const float4*)a)[i];
  if (b) { float4 w = ((const float4*)b)[i]; v.x += w.x; v.y += w.y; v.z += w.z; v.w += w.w; }
  float vv[4] = {v.x, v.y, v.z, v.w};
  h16x4 hv, lv;
  #pragma unroll
  for (int q = 0; q < 4; ++q) {
    float x = vv[q] * scale;
    h16 h = (h16)x;
    hv[q] = h;
    lv[q] = (h16)((x - (float)h) * 4096.0f);
  }
  ((h16x4*)H)[i] = hv;
  ((h16x4*)L)[i] = lv;
}

__global__ void k_tof16(const float* __restrict__ a, h16* __restrict__ H, float scale, int n4) {
  int i = blockIdx.x*256 + threadIdx.x;
  if (i >= n4) return;
  float4 v = ((const float4*)a)[i];
  h16x4 hv;
  hv[0] = (h16)(v.x*scale); hv[1] = (h16)(v.y*scale);
  hv[2] = (h16)(v.z*scale); hv[3] = (h16)(v.w*scale);
  ((h16x4*)H)[i] = hv;
}

// ---------------------------------------------------------------------------
// QKV projection (128^2 split MFMA): scatter to Q,K [bh][s][d], V^T [bh][d][s],
// all as f16 splits with scale 16.
// ---------------------------------------------------------------------------
__global__ __launch_bounds__(256) void k_qkv128(
    const h16* __restrict__ qkh, const h16* __restrict__ qkl,
    const h16* __restrict__ sh,  const h16* __restrict__ sl,
    const h16* __restrict__ Wh,  const h16* __restrict__ Wl, const float* __restrict__ bias,
    h16* __restrict__ Qh, h16* __restrict__ Ql, h16* __restrict__ Kh, h16* __restrict__ Kl,
    h16* __restrict__ Vh, h16* __restrict__ Vl)
{
  __shared__ h16 lds[4*128*LDK];
  const int n0 = blockIdx.x*128, m0 = blockIdx.y*128;
  const bool isV = (n0 >= 2048);
  f32x4 a1[4][4] = {}; f32x4 a2[4][4] = {};
  gemm128_core(isV ? sh : qkh, isV ? sl : qkl, Wh, Wl,
               1024, 1024, 1024, m0, n0, a1, a2, lds);
  EPI128;
  #pragma unroll
  for (int i = 0; i < 4; ++i)
    #pragma unroll
    for (int j = 0; j < 4; ++j)
      #pragma unroll
      for (int r = 0; r < 4; ++r) {
        int row = m0 + wr + i*16 + rb + r;
        int col = n0 + wc + j*16 + fr;
        float c = (a1[i][j][r] + a2[i][j][r]*(1.0f/4096.0f)) * (1.0f/1024.0f) + bias[col];
        int b = row >> 10, s = row & 1023;
        int cc = col & 1023, h = cc >> 6, d = cc & 63;
        long bh = (long)b*NH + h;
        float cs = c * 16.0f;
        if (col < 1024)      store_split(Qh, Ql, (bh*SEQ + s)*HD + d, cs);
        else if (col < 2048) store_split(Kh, Kl, (bh*SEQ + s)*HD + d, cs);
        else                 store_split(Vh, Vl, (bh*HD + d)*SEQ + s, cs);
      }
}

// scores chunk (64^2 split): S[bh][m][n] = (Q . K) * 0.125, scales 16*16
__global__ __launch_bounds__(256) void k_scores(
    const h16* __restrict__ Qh, const h16* __restrict__ Ql,
    const h16* __restrict__ Kh, const h16* __restrict__ Kl,
    float* __restrict__ S, int q0)
{
  __shared__ h16 lds[4*64*LDK];
  const int n0 = blockIdx.x*64;
  const int bh = blockIdx.z;
  const long base = (long)bh*SEQ*HD;
  f32x4 a1[2][2] = {}; f32x4 a2[2][2] = {};
  gemm64_core(Qh+base, Ql+base, Kh+base, Kl+base, HD, HD, HD, q0, n0, a1, a2, lds);
  EPI64;
  #pragma unroll
  for (int i = 0; i < 2; ++i)
    #pragma unroll
    for (int j = 0; j < 2; ++j)
      #pragma unroll
      for (int r = 0; r < 4; ++r) {
        int lrow = wm + i*16 + rb + r;
        int col  = n0 + wn + j*16 + fr;
        S[((long)bh*QB + lrow)*SEQ + col] =
            (a1[i][j][r] + a2[i][j][r]*(1.0f/4096.0f)) * (0.125f/256.0f);
      }
}

// row softmax over 1024, write P split (scale 512)
__global__ __launch_bounds__(256) void k_softmax(const float* __restrict__ S,
                                                 h16* __restrict__ Ph, h16* __restrict__ Pl) {
  int wave = threadIdx.x >> 6, lane = threadIdx.x & 63;
  long row = (long)blockIdx.x*4 + wave;
  const float* sr = S + row*SEQ;
  float v[16]; float mx = -3.0e38f;
  #pragma unroll
  for (int p = 0; p < 4; ++p) {
    int d = p*256 + lane*4;
    float4 a = *(const float4*)(sr + d);
    v[4*p+0]=a.x; v[4*p+1]=a.y; v[4*p+2]=a.z; v[4*p+3]=a.w;
    mx = fmaxf(mx, fmaxf(fmaxf(a.x,a.y), fmaxf(a.z,a.w)));
  }
  mx = wave_max(mx);
  float s = 0.0f;
  #pragma unroll
  for (int i = 0; i < 16; ++i) { float e = expf(v[i]-mx); v[i]=e; s += e; }
  s = wave_sum(s);
  float inv = 512.0f / s;
  #pragma unroll
  for (int p = 0; p < 4; ++p) {
    int d = p*256 + lane*4;
    h16x4 hv, lv;
    #pragma unroll
    for (int q = 0; q < 4; ++q) {
      float pr = v[4*p+q] * inv;
      h16 h = (h16)pr; hv[q] = h; lv[q] = (h16)((pr - (float)h)*4096.0f);
    }
    *(h16x4*)(Ph + row*SEQ + d) = hv;
    *(h16x4*)(Pl + row*SEQ + d) = lv;
  }
}

// PV (64^2 split) with K split in 4 segments of 256 (deterministic partials)
__global__ __launch_bounds__(256) void k_pv(
    const h16* __restrict__ Ph, const h16* __restrict__ Pl,
    const h16* __restrict__ Vh, const h16* __restrict__ Vl, float* __restrict__ part)
{
  __shared__ h16 lds[4*64*LDK];
  int z = blockIdx.z; int bh = z >> 2, ks = z & 3;
  const long pb = (long)bh*QB*SEQ + ks*256;
  const long vb = (long)bh*HD*SEQ + ks*256;
  f32x4 a1[2][2] = {}; f32x4 a2[2][2] = {};
  gemm64_core(Ph+pb, Pl+pb, Vh+vb, Vl+vb, 256, SEQ, SEQ, 0, 0, a1, a2, lds);
  EPI64;
  #pragma unroll
  for (int i = 0; i < 2; ++i)
    #pragma unroll
    for (int j = 0; j < 2; ++j)
      #pragma unroll
      for (int r = 0; r < 4; ++r) {
        int m = wm + i*16 + rb + r;
        int d = wn + j*16 + fr;
        part[(((long)ks*NBH + bh)*QB + m)*HD + d] = a1[i][j][r] + a2[i][j][r]*(1.0f/4096.0f);
      }
}

__global__ void k_pvred(const float* __restrict__ part, h16* __restrict__ Oh,
                        h16* __restrict__ Ol, int q0) {
  long id = (long)blockIdx.x*256 + threadIdx.x;   // < NBH*QB*HD
  int d = (int)(id & 63); long r = id >> 6;
  int m = (int)(r % QB); int bh = (int)(r / QB);
  const long st = (long)NBH*QB*HD;
  float o = part[id] + part[id+st] + part[id+2*st] + part[id+3*st];
  o *= (1.0f/(512.0f*16.0f));
  int b = bh >> 4, h = bh & 15;
  long tok = (long)b*SEQ + q0 + m;
  store_split(Oh, Ol, tok*DM + h*HD + d, o*16.0f);
}

// out_proj (128^2 split): attn[t,i] = O . Wo + bo, fp32 out
__global__ __launch_bounds__(256) void k_out128(
    const h16* __restrict__ Oh, const h16* __restrict__ Ol,
    const h16* __restrict__ Wh, const h16* __restrict__ Wl,
    const float* __restrict__ bias, float* __restrict__ attn)
{
  __shared__ h16 lds[4*128*LDK];
  const int n0 = blockIdx.x*128, m0 = blockIdx.y*128;
  f32x4 a1[4][4] = {}; f32x4 a2[4][4] = {};
  gemm128_core(Oh, Ol, Wh, Wl, 1024, 1024, 1024, m0, n0, a1, a2, lds);
  EPI128;
  #pragma unroll
  for (int i = 0; i < 4; ++i)
    #pragma unroll
    for (int j = 0; j < 4; ++j)
      #pragma unroll
      for (int r = 0; r < 4; ++r) {
        int row = m0 + wr + i*16 + rb + r;
        int col = n0 + wc + j*16 + fr;
        attn[(long)row*DM + col] =
            (a1[i][j][r] + a2[i][j][r]*(1.0f/4096.0f)) * (1.0f/1024.0f) + bias[col];
      }
}

// LayerNorm over D=1024 of (A + Badd); optional fp32 out, f16(x*16) out, direct out
__global__ __launch_bounds__(256) void k_ln(
    const float* __restrict__ A, const float* __restrict__ Badd,
    const float* __restrict__ g, const float* __restrict__ be,
    float* __restrict__ xout, h16* __restrict__ xh, float* __restrict__ dout)
{
  int wave = threadIdx.x >> 6, lane = threadIdx.x & 63;
  long row = (long)blockIdx.x*4 + wave;
  const float* ar = A + row*DM; const float* br = Badd + row*DM;
  float v[16]; float s = 0.0f;
  #pragma unroll
  for (int p = 0; p < 4; ++p) {
    int d = p*256 + lane*4;
    float4 a = *(const float4*)(ar + d);
    float4 b = *(const float4*)(br + d);
    float t0=a.x+b.x, t1=a.y+b.y, t2=a.z+b.z, t3=a.w+b.w;
    v[4*p+0]=t0; v[4*p+1]=t1; v[4*p+2]=t2; v[4*p+3]=t3;
    s += t0+t1+t2+t3;
  }
  s = wave_sum(s);
  float m = s * (1.0f/1024.0f);
  float q = 0.0f;
  #pragma unroll
  for (int i = 0; i < 16; ++i) { float dd = v[i]-m; q += dd*dd; }
  q = wave_sum(q);
  float rs = (float)(1.0 / sqrt((double)(q * (1.0f/1024.0f) + 1e-5f)));
  #pragma unroll
  for (int p = 0; p < 4; ++p) {
    int d = p*256 + lane*4;
    float4 gv = *(const float4*)(g + d);
    float4 bv = *(const float4*)(be + d);
    float y0 = (v[4*p+0]-m)*rs*gv.x + bv.x;
    float y1 = (v[4*p+1]-m)*rs*gv.y + bv.y;
    float y2 = (v[4*p+2]-m)*rs*gv.z + bv.z;
    float y3 = (v[4*p+3]-m)*rs*gv.w + bv.w;
    if (xout) { float4 o = {y0,y1,y2,y3}; *(float4*)(xout + row*DM + d) = o; }
    if (xh) {
      h16x4 hv; hv[0]=(h16)(y0*16.f); hv[1]=(h16)(y1*16.f);
      hv[2]=(h16)(y2*16.f); hv[3]=(h16)(y3*16.f);
      *(h16x4*)(xh + row*DM + d) = hv;
    }
    if (dout) { float4 o = {y0,y1,y2,y3}; *(float4*)(dout + row*DM + d) = o; }
  }
}

// ---------------------------------------------------------------------------
// threefry2x32 (key=[0,42]) -> gumbel -> argmax. VERIFIED round 5 — DO NOT TOUCH.
// partitionable bits = b1 ^ b2, counter = (0, i).
// ---------------------------------------------------------------------------
__device__ __forceinline__ void threefry(u32 x0, u32 x1, u32& y0, u32& y1) {
  const u32 ks0 = 0u, ks1 = 42u, ks2 = 0x1BD11BDAu ^ 42u;
  x0 += ks0; x1 += ks1;
  #define TF_R(r) { x0 += x1; x1 = (x1 << r) | (x1 >> (32 - r)); x1 ^= x0; }
  TF_R(13) TF_R(15) TF_R(26) TF_R(6)  x0 += ks1; x1 += ks2 + 1u;
  TF_R(17) TF_R(29) TF_R(16) TF_R(24) x0 += ks2; x1 += ks0 + 2u;
  TF_R(13) TF_R(15) TF_R(26) TF_R(6)  x0 += ks0; x1 += ks1 + 3u;
  TF_R(17) TF_R(29) TF_R(16) TF_R(24) x0 += ks1; x1 += ks2 + 4u;
  TF_R(13) TF_R(15) TF_R(26) TF_R(6)  x0 += ks2; x1 += ks0 + 5u;
  #undef TF_R
  y0 = x0; y1 = x1;
}

__device__ __forceinline__ float gumbel_from(u32 bits) {
  float f = __uint_as_float((bits >> 9) | 0x3F800000u) - 1.0f;
  float u = (f > 0.0f) ? f : 1.17549435e-38f;
  float nl = (float)(-log((double)u));
  return -(float)log((double)nl);
}

__global__ __launch_bounds__(256) void k_gate(
    const float* __restrict__ x, const float* __restrict__ gw,
    const float* __restrict__ gb, int* __restrict__ chosen)
{
  int wave = threadIdx.x >> 6, lane = threadIdx.x & 63;
  long t = (long)blockIdx.x*4 + wave;
  const float* xr = x + t*DM;
  float p[4] = {0.f,0.f,0.f,0.f};
  #pragma unroll
  for (int pp = 0; pp < 4; ++pp) {
    int d = pp*256 + lane*4;
    float4 xv = *(const float4*)(xr + d);
    #pragma unroll
    for (int e = 0; e < 4; ++e) {
      float4 gv = *(const float4*)(gw + e*DM + d);
      p[e] += xv.x*gv.x + xv.y*gv.y + xv.z*gv.z + xv.w*gv.w;
    }
  }
  #pragma unroll
  for (int e = 0; e < 4; ++e) p[e] = wave_sum(p[e]);
  if (lane == 0) {
    float best = -3.0e38f; int arg = 0;
    #pragma unroll
    for (int e = 0; e < 4; ++e) {
      float logit = p[e] + gb[e];
      u32 j = (u32)(4*t + e);
      u32 y0, y1;
      threefry(0u, j, y0, y1);
      float v = gumbel_from(y0 ^ y1) + logit;
      if (v > best) { best = v; arg = e; }
    }
    chosen[(int)t] = arg;
  }
}

// MoE layer 1 dense: h[t, e*1024+f] = relu(x.w1 + b1), f16 MFMA
__global__ __launch_bounds__(256) void k_e1(
    const h16* __restrict__ Xh, const h16* __restrict__ W1,
    const float* __restrict__ b1, h16* __restrict__ Hh)
{
  __shared__ h16 lds[2*64*LDK];
  const int n0 = blockIdx.x*64, m0 = blockIdx.y*64;
  f32x4 acc[2][2] = {};
  hgemm_core(Xh, W1, 1024, 1024, 1024, m0, n0, acc, lds);
  EPI64;
  #pragma unroll
  for (int i = 0; i < 2; ++i)
    #pragma unroll
    for (int j = 0; j < 2; ++j)
      #pragma unroll
      for (int r = 0; r < 4; ++r) {
        int row = m0 + wm + i*16 + rb + r;
        int col = n0 + wn + j*16 + fr;
        float c = acc[i][j][r] * (1.0f/1024.0f) + b1[col];
        c = fmaxf(c, 0.0f);
        Hh[(long)row*(NE*DFE) + col] = (h16)(c * 16.0f);
      }
}

// MoE layer 2 block-diagonal dense + select
__global__ __launch_bounds__(256) void k_e2(
    const h16* __restrict__ Hh, const h16* __restrict__ W2,
    const float* __restrict__ b2, const int* __restrict__ chosen,
    float* __restrict__ y)
{
  __shared__ h16 lds[2*64*LDK];
  const int n0 = blockIdx.x*64, m0 = blockIdx.y*64;
  const int e = blockIdx.z;
  f32x4 acc[2][2] = {};
  hgemm_core(Hh + (long)e*DFE, W2 + (long)e*DM*DFE, 1024, NE*DFE, DFE, m0, n0, acc, lds);
  EPI64;
  #pragma unroll
  for (int i = 0; i < 2; ++i)
    #pragma unroll
    for (int j = 0; j < 2; ++j)
      #pragma unroll
      for (int r = 0; r < 4; ++r) {
        int row = m0 + wm + i*16 + rb + r;
        int col = n0 + wn + j*16 + fr;
        if (chosen[row] == e)
          y[(long)row*DM + col] = acc[i][j][r] * (1.0f/1024.0f) + b2[e*DM + col];
      }
}

// ---------------------------------------------------------------------------
extern "C" void kernel_launch(void* const* d_in, const int* in_sizes, int n_in,
                              void* d_out, int out_size, void* d_ws, size_t ws_size,
                              hipStream_t stream) {
  const float* src = (const float*)d_in[0];
  const float* pos = (const float*)d_in[1];
  const float* w3  = (const float*)d_in[2];
  const float* b3  = (const float*)d_in[3];
  const float* wo  = (const float*)d_in[4];
  const float* bo  = (const float*)d_in[5];
  const float* gw  = (const float*)d_in[6];
  const float* gb  = (const float*)d_in[7];
  const float* w1  = (const float*)d_in[8];
  const float* b1  = (const float*)d_in[9];
  const float* w2  = (const float*)d_in[10];
  const float* b2  = (const float*)d_in[11];
  const float* g1  = (const float*)d_in[12];
  const float* be1 = (const float*)d_in[13];
  const float* g2  = (const float*)d_in[14];
  const float* be2 = (const float*)d_in[15];
  float* out = (float*)d_out;
  char* ws = (char*)d_ws;
  if (ws_size < WS_NEEDED) return;

  auto H = [&](size_t off) { return (h16*)(ws + off); };
  auto F = [&](size_t off) { return (float*)(ws + off); };
  auto I = [&](size_t off) { return (int*)(ws + off); };

  // input / weight splits (scales: activations 16, weights 64)
  k_split2<<<BS*DM/4/256, 256, 0, stream>>>(src, pos, H(OFF_QKH), H(OFF_QKL), 16.0f, BS*DM/4);
  k_split2<<<BS*DM/4/256, 256, 0, stream>>>(src, nullptr, H(OFF_SRCH), H(OFF_SRCL), 16.0f, BS*DM/4);
  k_split2<<<3*DM*DM/4/256, 256, 0, stream>>>(w3, nullptr, H(OFF_W3H), H(OFF_W3L), 64.0f, 3*DM*DM/4);
  k_split2<<<DM*DM/4/256, 256, 0, stream>>>(wo, nullptr, H(OFF_WOH), H(OFF_WOL), 64.0f, DM*DM/4);

  // QKV projection (split MFMA, 128^2 tile)
  k_qkv128<<<dim3(24, 64), 256, 0, stream>>>(
      H(OFF_QKH), H(OFF_QKL), H(OFF_SRCH), H(OFF_SRCL), H(OFF_W3H), H(OFF_W3L), b3,
      H(OFF_QH), H(OFF_QL), H(OFF_KH), H(OFF_KL), H(OFF_VH), H(OFF_VL));

  // attention, chunked over query rows (split MFMA)
  for (int qc = 0; qc < NCHUNK; ++qc) {
    int q0 = qc * QB;
    k_scores<<<dim3(16, 1, NBH), 256, 0, stream>>>(
        H(OFF_QH), H(OFF_QL), H(OFF_KH), H(OFF_KL), F(OFF_S), q0);
    k_softmax<<<NBH*QB/4, 256, 0, stream>>>(F(OFF_S), H(OFF_PH), H(OFF_PL));
    k_pv<<<dim3(1, 1, NBH*4), 256, 0, stream>>>(
        H(OFF_PH), H(OFF_PL), H(OFF_VH), H(OFF_VL), F(OFF_PART));
    k_pvred<<<NBH*QB*HD/256, 256, 0, stream>>>(F(OFF_PART), H(OFF_OH), H(OFF_OL), q0);
  }

  // out projection (split MFMA, 128^2) + LN1
  k_out128<<<dim3(8, 64), 256, 0, stream>>>(
      H(OFF_OH), H(OFF_OL), H(OFF_WOH), H(OFF_WOL), bo, F(OFF_ATT));
  k_ln<<<BS/4, 256, 0, stream>>>(src, F(OFF_ATT), g1, be1, F(OFF_X), H(OFF_XH), nullptr);

  // gate -> chosen expert per token (verified partitionable threefry)
  k_gate<<<BS/4, 256, 0, stream>>>(F(OFF_X), gw, gb, I(OFF_CHOSEN));

  // MoE FFN dense all-expert (f16 MFMA) + select
  k_tof16<<<NE*DFE*DM/4/256, 256, 0, stream>>>(w1, H(OFF_W1H), 64.0f, NE*DFE*DM/4);
  k_tof16<<<NE*DM*DFE/4/256, 256, 0, stream>>>(w2, H(OFF_W2H), 64.0f, NE*DM*DFE/4);
  k_e1<<<dim3(64, 128), 256, 0, stream>>>(H(OFF_XH), H(OFF_W1H), b1, H(OFF_HH));
  k_e2<<<dim3(16, 128, NE), 256, 0, stream>>>(
      H(OFF_HH), H(OFF_W2H), b2, I(OFF_CHOSEN), F(OFF_YSEL));

  // final LN2 -> output
  k_ln<<<BS/4, 256, 0, stream>>>(F(OFF_X), F(OFF_YSEL), g2, be2, nullptr, nullptr, out);
}

// Round 8
// 958.073 us; speedup vs baseline: 2.3301x; 1.6595x over previous
//
#include <hip/hip_runtime.h>
#include <cstdint>
#include <cstddef>

// ---------------------------------------------------------------------------
// TransformerEncoderLayer on MI355X (gfx950).
// Pre-gate GEMMs: f16 hi/lo split MFMA (3 mfma/product) — validated bit-equal
// to fp32 routing (rounds 1 vs 2). Attention: fused flash kernel (split QK^T,
// online softmax, split PV) — LDS tiles use stride FLD=72 (64-wide tiles; the
// round-7 bug was reusing the 32-wide stride LDK=40 here). Gate RNG:
// partitionable threefry, bits=b1^b2 (VERIFIED round 5 — DO NOT TOUCH).
// MoE: bucketed per-expert f16 MFMA.
// ---------------------------------------------------------------------------

typedef _Float16 h16;
typedef h16 h16x8 __attribute__((ext_vector_type(8)));
typedef h16 h16x4 __attribute__((ext_vector_type(4)));
typedef float f32x4 __attribute__((ext_vector_type(4)));
typedef uint32_t u32;

#define DM 1024
#define NH 16
#define HD 64
#define SEQ 1024
#define BB 8
#define BS (BB*SEQ)      /* 8192 tokens */
#define NBH (BB*NH)      /* 128 (b,h) pairs */
#define NE 4
#define DFE 1024
#define QB 64            /* query rows per attention chunk */
#define NCHUNK (SEQ/QB)  /* 16 */
#define LDK 40           /* LDS stride for 32-wide K-step slabs (GEMM cores) */
#define FLD 72           /* LDS stride for 64-wide flash tiles (64+8 pad) */
#define NPOS (132*64)    /* 8448 padded bucket capacity */

#define MFMA16(a,b,c) __builtin_amdgcn_mfma_f32_16x16x32_f16(a,b,c,0,0,0)

// ---- workspace layout (bytes). E = one h16 plane of [8192][1024]. ----
static constexpr size_t E = (size_t)BS*DM*2;            // 16,777,216
static constexpr size_t OFF_QKH = 0;                    // qk split (dead after qkv)
static constexpr size_t OFF_QKL = E;
static constexpr size_t OFF_SRCH= 2*E;
static constexpr size_t OFF_SRCL= 3*E;
static constexpr size_t OFF_W3H = 4*E;
static constexpr size_t OFF_W3L = 4*E + (size_t)3*DM*DM*2;
static constexpr size_t OFF_WOH = 4*E + (size_t)6*DM*DM*2;
static constexpr size_t OFF_WOL = 4*E + (size_t)7*DM*DM*2;   // ends at 5E
static constexpr size_t OFF_QH  = 5*E;                  // Q,K [bh][s][d]; V^T [bh][d][s]
static constexpr size_t OFF_QL  = 6*E;
static constexpr size_t OFF_KH  = 7*E;
static constexpr size_t OFF_KL  = 8*E;
static constexpr size_t OFF_VH  = 9*E;
static constexpr size_t OFF_VL  = 10*E;
static constexpr size_t OFF_OH  = 0;                    // after flash (qk dead)
static constexpr size_t OFF_OL  = E;
static constexpr size_t OFF_ATT = 2*E;                  // fp32 (src splits dead)
static constexpr size_t OFF_X   = 5*E;                  // fp32 2E (Q,Ql dead)
static constexpr size_t OFF_XH  = 7*E;                  // f16 x*16 (Kh dead)
static constexpr size_t OFF_W1H = 8*E;                  // f16 (Kl dead)
static constexpr size_t OFF_W2H = 8*E + (size_t)NE*DFE*DM*2;  // ends at 9E
static constexpr size_t OFF_HH  = 9*E;                  // bucket h f16 [NPOS][1024] (V dead)
static constexpr size_t OFF_Y   = 11*E;                 // fp32 2E
static constexpr size_t OFF_CHOSEN = 13*E;
static constexpr size_t OFF_COUNTS = 13*E + 32768;
static constexpr size_t OFF_CURSOR = OFF_COUNTS + 16;
static constexpr size_t OFF_EOFF   = OFF_CURSOR + 16;
static constexpr size_t OFF_PLIST  = OFF_EOFF + 16;
static constexpr size_t WS_NEEDED  = OFF_PLIST + (size_t)NPOS*4;

// ---------------------------------------------------------------------------
__device__ __forceinline__ void store_split(h16* H, h16* L, size_t idx, float v) {
  h16 h = (h16)v;
  H[idx] = h;
  L[idx] = (h16)((v - (float)h) * 4096.0f);
}

__device__ __forceinline__ float wave_sum(float v) {
  #pragma unroll
  for (int o = 32; o; o >>= 1) v += __shfl_xor(v, o);
  return v;
}

// ---------------------------------------------------------------------------
// 128(M)x64(N) split-f16 MFMA core. 4 waves, each 64x32 (4x2 frags 16x16x32).
// ---------------------------------------------------------------------------
__device__ __forceinline__ void gemm128x64_core(
    const h16* __restrict__ Ah, const h16* __restrict__ Al,
    const h16* __restrict__ Bh, const h16* __restrict__ Bl,
    int K, int lda, int ldb, int m0, int n0,
    f32x4 (&a1)[4][2], f32x4 (&a2)[4][2], h16* lds)
{
  const int tid = threadIdx.x, lane = tid & 63, wid = tid >> 6;
  const int wr = (wid >> 1) * 64, wc = (wid & 1) * 32;
  h16* sAh = lds;               h16* sAl = lds + 128*LDK;
  h16* sBh = lds + 2*128*LDK;   h16* sBl = lds + 2*128*LDK + 64*LDK;
  const int arow = tid >> 1, akc = (tid & 1) * 16;
  const int brow = tid >> 2, bkc = (tid & 3) * 8;
  const long abase = (long)(m0 + arow) * lda + akc;
  const long bbase = (long)(n0 + brow) * ldb + bkc;
  const int fr = lane & 15, kg = (lane >> 4) << 3;
  for (int k0 = 0; k0 < K; k0 += 32) {
    __syncthreads();
    *(uint4*)(sAh + arow*LDK + akc)     = *(const uint4*)(Ah + abase + k0);
    *(uint4*)(sAh + arow*LDK + akc + 8) = *(const uint4*)(Ah + abase + k0 + 8);
    *(uint4*)(sAl + arow*LDK + akc)     = *(const uint4*)(Al + abase + k0);
    *(uint4*)(sAl + arow*LDK + akc + 8) = *(const uint4*)(Al + abase + k0 + 8);
    *(uint4*)(sBh + brow*LDK + bkc)     = *(const uint4*)(Bh + bbase + k0);
    *(uint4*)(sBl + brow*LDK + bkc)     = *(const uint4*)(Bl + bbase + k0);
    __syncthreads();
    h16x8 ah[4], al[4], bh[2], bl[2];
    #pragma unroll
    for (int i = 0; i < 4; ++i) {
      ah[i] = *(const h16x8*)(sAh + (wr + i*16 + fr)*LDK + kg);
      al[i] = *(const h16x8*)(sAl + (wr + i*16 + fr)*LDK + kg);
    }
    #pragma unroll
    for (int j = 0; j < 2; ++j) {
      bh[j] = *(const h16x8*)(sBh + (wc + j*16 + fr)*LDK + kg);
      bl[j] = *(const h16x8*)(sBl + (wc + j*16 + fr)*LDK + kg);
    }
    #pragma unroll
    for (int i = 0; i < 4; ++i)
      #pragma unroll
      for (int j = 0; j < 2; ++j) {
        a1[i][j] = MFMA16(ah[i], bh[j], a1[i][j]);
        a2[i][j] = MFMA16(ah[i], bl[j], a2[i][j]);
        a2[i][j] = MFMA16(al[i], bh[j], a2[i][j]);
      }
  }
}

#define EPI_W \
  const int lane = threadIdx.x & 63, wid = threadIdx.x >> 6; \
  const int wr = (wid>>1)*64, wc = (wid&1)*32; \
  const int fr = lane & 15, rb = (lane>>4)*4;

// ---------------------------------------------------------------------------
// f16 single MFMA core (validated) + optional row gather on A.
// ---------------------------------------------------------------------------
template<bool GATHER>
__device__ __forceinline__ void hgemm_core(
    const h16* __restrict__ A, const h16* __restrict__ B,
    int K, int lda, int ldb, int m0, int n0, const int* __restrict__ rowmap,
    f32x4 (&acc)[2][2], h16* lds)
{
  const int tid = threadIdx.x, lane = tid & 63, wave = tid >> 6;
  const int wm = (wave >> 1) * 32, wn = (wave & 1) * 32;
  h16* sA = lds; h16* sB = lds + 64*LDK;
  const int srow = tid >> 2, skc = (tid & 3) << 3;
  long arow; bool aval = true;
  if (GATHER) { int t = rowmap[m0 + srow]; aval = (t >= 0); arow = (long)(aval ? t : 0) * lda + skc; }
  else        { arow = (long)(m0 + srow) * lda + skc; }
  const long brow = (long)(n0 + srow) * ldb + skc;
  const int fr = lane & 15, kg = (lane >> 4) << 3;
  for (int k0 = 0; k0 < K; k0 += 32) {
    __syncthreads();
    uint4 va = (!GATHER || aval) ? *(const uint4*)(A + arow + k0) : make_uint4(0,0,0,0);
    *(uint4*)(sA + srow*LDK + skc) = va;
    *(uint4*)(sB + srow*LDK + skc) = *(const uint4*)(B + brow + k0);
    __syncthreads();
    #pragma unroll
    for (int i = 0; i < 2; ++i) {
      h16x8 ah = *(const h16x8*)(sA + (wm + i*16 + fr)*LDK + kg);
      #pragma unroll
      for (int j = 0; j < 2; ++j) {
        h16x8 bh = *(const h16x8*)(sB + (wn + j*16 + fr)*LDK + kg);
        acc[i][j] = MFMA16(ah, bh, acc[i][j]);
      }
    }
  }
}

#define EPI64 \
  const int lane = threadIdx.x & 63, wave = threadIdx.x >> 6; \
  const int wm = (wave>>1)*32, wn = (wave&1)*32; \
  const int fr = lane & 15, rb = (lane>>4)*4;

// ---------------------------------------------------------------------------
// prep kernels
// ---------------------------------------------------------------------------
__global__ void k_zero8(int* __restrict__ p) {
  if (threadIdx.x < 8) p[threadIdx.x] = 0;   // counts[4] + cursor[4]
}

__global__ void k_split_in(const float* __restrict__ src, const float* __restrict__ pos,
                           h16* __restrict__ qkH, h16* __restrict__ qkL,
                           h16* __restrict__ sH,  h16* __restrict__ sL) {
  int i = blockIdx.x*256 + threadIdx.x;
  float4 s = ((const float4*)src)[i];
  float4 p = ((const float4*)pos)[i];
  float sv[4] = {s.x, s.y, s.z, s.w};
  float qv[4] = {s.x+p.x, s.y+p.y, s.z+p.z, s.w+p.w};
  h16x4 sh, sl, qh, ql;
  #pragma unroll
  for (int q = 0; q < 4; ++q) {
    float xs = sv[q] * 16.0f; h16 hs = (h16)xs;
    sh[q] = hs; sl[q] = (h16)((xs - (float)hs) * 4096.0f);
    float xq = qv[q] * 16.0f; h16 hq = (h16)xq;
    qh[q] = hq; ql[q] = (h16)((xq - (float)hq) * 4096.0f);
  }
  ((h16x4*)sH)[i] = sh; ((h16x4*)sL)[i] = sl;
  ((h16x4*)qkH)[i] = qh; ((h16x4*)qkL)[i] = ql;
}

__global__ void k_split2(const float* __restrict__ a,
                         h16* __restrict__ H, h16* __restrict__ L, float scale, int n4) {
  int i = blockIdx.x*256 + threadIdx.x;
  if (i >= n4) return;
  float4 v = ((const float4*)a)[i];
  float vv[4] = {v.x, v.y, v.z, v.w};
  h16x4 hv, lv;
  #pragma unroll
  for (int q = 0; q < 4; ++q) {
    float x = vv[q] * scale;
    h16 h = (h16)x;
    hv[q] = h;
    lv[q] = (h16)((x - (float)h) * 4096.0f);
  }
  ((h16x4*)H)[i] = hv;
  ((h16x4*)L)[i] = lv;
}

__global__ void k_tof16(const float* __restrict__ a, h16* __restrict__ H, float scale, int n4) {
  int i = blockIdx.x*256 + threadIdx.x;
  if (i >= n4) return;
  float4 v = ((const float4*)a)[i];
  h16x4 hv;
  hv[0] = (h16)(v.x*scale); hv[1] = (h16)(v.y*scale);
  hv[2] = (h16)(v.z*scale); hv[3] = (h16)(v.w*scale);
  ((h16x4*)H)[i] = hv;
}

// ---------------------------------------------------------------------------
// QKV projection (128x64 split MFMA tiles)
// ---------------------------------------------------------------------------
__global__ __launch_bounds__(256) void k_qkv(
    const h16* __restrict__ qkh, const h16* __restrict__ qkl,
    const h16* __restrict__ sh,  const h16* __restrict__ sl,
    const h16* __restrict__ Wh,  const h16* __restrict__ Wl, const float* __restrict__ bias,
    h16* __restrict__ Qh, h16* __restrict__ Ql, h16* __restrict__ Kh, h16* __restrict__ Kl,
    h16* __restrict__ Vh, h16* __restrict__ Vl)
{
  __shared__ h16 lds[(2*128 + 2*64)*LDK];
  const int n0 = blockIdx.x*64, m0 = blockIdx.y*128;
  const bool isV = (n0 >= 2048);
  f32x4 a1[4][2] = {}; f32x4 a2[4][2] = {};
  gemm128x64_core(isV ? sh : qkh, isV ? sl : qkl, Wh, Wl,
                  1024, 1024, 1024, m0, n0, a1, a2, lds);
  EPI_W;
  #pragma unroll
  for (int i = 0; i < 4; ++i)
    #pragma unroll
    for (int j = 0; j < 2; ++j)
      #pragma unroll
      for (int r = 0; r < 4; ++r) {
        int row = m0 + wr + i*16 + rb + r;
        int col = n0 + wc + j*16 + fr;
        float c = (a1[i][j][r] + a2[i][j][r]*(1.0f/4096.0f)) * (1.0f/1024.0f) + bias[col];
        int b = row >> 10, s = row & 1023;
        int cc = col & 1023, h = cc >> 6, d = cc & 63;
        long bh = (long)b*NH + h;
        float cs = c * 16.0f;
        if (col < 1024)      store_split(Qh, Ql, (bh*SEQ + s)*HD + d, cs);
        else if (col < 2048) store_split(Kh, Kl, (bh*SEQ + s)*HD + d, cs);
        else                 store_split(Vh, Vl, (bh*HD + d)*SEQ + s, cs);
      }
}

// ---------------------------------------------------------------------------
// Fused flash attention. One block per (q-chunk, bh). 4 waves, each owns 16
// q-rows. Split QK^T -> in-reg online softmax -> P split via LDS -> split PV.
// All flash LDS tiles are 64x64 h16 with row stride FLD=72.
// ---------------------------------------------------------------------------
__global__ __launch_bounds__(256) void k_attn(
    const h16* __restrict__ Qh, const h16* __restrict__ Ql,
    const h16* __restrict__ Kh, const h16* __restrict__ Kl,
    const h16* __restrict__ Vh, const h16* __restrict__ Vl,
    h16* __restrict__ Oh, h16* __restrict__ Ol)
{
  __shared__ h16 lds[6*64*FLD];   // 55,296 B
  h16* sKh = lds;            h16* sKl = lds + 64*FLD;
  h16* sVh = lds + 2*64*FLD; h16* sVl = lds + 3*64*FLD;
  h16* sPh = lds + 4*64*FLD; h16* sPl = lds + 5*64*FLD;
  const int tid = threadIdx.x, lane = tid & 63, w = tid >> 6;
  const int q0 = blockIdx.x * QB;
  const int bh = blockIdx.y;
  const int fr = lane & 15, hg = lane >> 4;   // 0..3
  const int kg = hg << 3;
  // Q fragments (A layout), scale 16
  const long qbase = ((long)bh*SEQ + q0 + w*16 + fr) * HD;
  h16x8 qh[2], ql[2];
  qh[0] = *(const h16x8*)(Qh + qbase + kg);
  qh[1] = *(const h16x8*)(Qh + qbase + 32 + kg);
  ql[0] = *(const h16x8*)(Ql + qbase + kg);
  ql[1] = *(const h16x8*)(Ql + qbase + 32 + kg);
  f32x4 o1[4] = {}, o2[4] = {};
  float mrow[4] = {-3.0e38f, -3.0e38f, -3.0e38f, -3.0e38f};
  float lrow[4] = {0.f, 0.f, 0.f, 0.f};
  // staging: 64 rows x 64 h16, 4 threads/row, 16 h16 each
  const int srow = tid >> 2, skc = (tid & 3) << 4;
  const long kbase = ((long)bh*SEQ + srow) * HD + skc;
  const long vbase = ((long)bh*HD + srow) * SEQ + skc;
  for (int kt = 0; kt < NCHUNK; ++kt) {
    const int n0 = kt * QB;
    __syncthreads();
    {
      const long ka = kbase + (long)n0*HD;
      *(uint4*)(sKh + srow*FLD + skc)     = *(const uint4*)(Kh + ka);
      *(uint4*)(sKh + srow*FLD + skc + 8) = *(const uint4*)(Kh + ka + 8);
      *(uint4*)(sKl + srow*FLD + skc)     = *(const uint4*)(Kl + ka);
      *(uint4*)(sKl + srow*FLD + skc + 8) = *(const uint4*)(Kl + ka + 8);
      const long va = vbase + n0;
      *(uint4*)(sVh + srow*FLD + skc)     = *(const uint4*)(Vh + va);
      *(uint4*)(sVh + srow*FLD + skc + 8) = *(const uint4*)(Vh + va + 8);
      *(uint4*)(sVl + srow*FLD + skc)     = *(const uint4*)(Vl + va);
      *(uint4*)(sVl + srow*FLD + skc + 8) = *(const uint4*)(Vl + va + 8);
    }
    __syncthreads();
    // S = Q.K^T (split)
    f32x4 s1[4] = {}, s2[4] = {};
    #pragma unroll
    for (int ks = 0; ks < 2; ++ks)
      #pragma unroll
      for (int j = 0; j < 4; ++j) {
        h16x8 kh = *(const h16x8*)(sKh + (j*16 + fr)*FLD + ks*32 + kg);
        h16x8 kl = *(const h16x8*)(sKl + (j*16 + fr)*FLD + ks*32 + kg);
        s1[j] = MFMA16(qh[ks], kh, s1[j]);
        s2[j] = MFMA16(qh[ks], kl, s2[j]);
        s2[j] = MFMA16(ql[ks], kh, s2[j]);
      }
    // online softmax (rows = hg*4 + r; cols spread over lanes fr of same hg group)
    float p[4][4];   // [j][r]
    float tmax[4] = {-3.0e38f, -3.0e38f, -3.0e38f, -3.0e38f};
    #pragma unroll
    for (int j = 0; j < 4; ++j)
      #pragma unroll
      for (int r = 0; r < 4; ++r) {
        float sc = (s1[j][r] + s2[j][r]*(1.0f/4096.0f)) * (0.125f/256.0f);
        p[j][r] = sc;
        tmax[r] = fmaxf(tmax[r], sc);
      }
    #pragma unroll
    for (int o = 1; o < 16; o <<= 1)
      #pragma unroll
      for (int r = 0; r < 4; ++r) tmax[r] = fmaxf(tmax[r], __shfl_xor(tmax[r], o));
    float scl[4], psum[4];
    #pragma unroll
    for (int r = 0; r < 4; ++r) {
      float mn = fmaxf(mrow[r], tmax[r]);
      scl[r] = expf(mrow[r] - mn);
      mrow[r] = mn;
      psum[r] = 0.f;
      #pragma unroll
      for (int j = 0; j < 4; ++j) { p[j][r] = expf(p[j][r] - mn); psum[r] += p[j][r]; }
    }
    #pragma unroll
    for (int o = 1; o < 16; o <<= 1)
      #pragma unroll
      for (int r = 0; r < 4; ++r) psum[r] += __shfl_xor(psum[r], o);
    #pragma unroll
    for (int r = 0; r < 4; ++r) lrow[r] = lrow[r]*scl[r] + psum[r];
    #pragma unroll
    for (int j = 0; j < 4; ++j)
      #pragma unroll
      for (int r = 0; r < 4; ++r) { o1[j][r] *= scl[r]; o2[j][r] *= scl[r]; }
    // write P split (scale 512) to LDS, rows w*16 + hg*4 + r, cols j*16+fr
    #pragma unroll
    for (int j = 0; j < 4; ++j)
      #pragma unroll
      for (int r = 0; r < 4; ++r) {
        float pv = p[j][r] * 512.0f;
        h16 ph = (h16)pv;
        h16 pl = (h16)((pv - (float)ph) * 4096.0f);
        int off = (w*16 + hg*4 + r)*FLD + j*16 + fr;
        sPh[off] = ph;
        sPl[off] = pl;
      }
    __syncthreads();
    // PV (split): O += P.V
    #pragma unroll
    for (int ks = 0; ks < 2; ++ks) {
      h16x8 pa = *(const h16x8*)(sPh + (w*16 + fr)*FLD + ks*32 + kg);
      h16x8 pb = *(const h16x8*)(sPl + (w*16 + fr)*FLD + ks*32 + kg);
      #pragma unroll
      for (int jd = 0; jd < 4; ++jd) {
        h16x8 vh = *(const h16x8*)(sVh + (jd*16 + fr)*FLD + ks*32 + kg);
        h16x8 vl = *(const h16x8*)(sVl + (jd*16 + fr)*FLD + ks*32 + kg);
        o1[jd] = MFMA16(pa, vh, o1[jd]);
        o2[jd] = MFMA16(pa, vl, o2[jd]);
        o2[jd] = MFMA16(pb, vh, o2[jd]);
      }
    }
  }
  // epilogue: normalize and store O split (scale 16)
  const int b = bh >> 4, h = bh & 15;
  #pragma unroll
  for (int jd = 0; jd < 4; ++jd)
    #pragma unroll
    for (int r = 0; r < 4; ++r) {
      int qrow = q0 + w*16 + hg*4 + r;
      int d = jd*16 + fr;
      float ov = (o1[jd][r] + o2[jd][r]*(1.0f/4096.0f)) / (512.0f*16.0f*lrow[r]);
      store_split(Oh, Ol, ((long)b*SEQ + qrow)*DM + h*HD + d, ov*16.0f);
    }
}

// out_proj (128x64 split): attn = O.Wo^T + bo, fp32
__global__ __launch_bounds__(256) void k_out(
    const h16* __restrict__ Oh, const h16* __restrict__ Ol,
    const h16* __restrict__ Wh, const h16* __restrict__ Wl,
    const float* __restrict__ bias, float* __restrict__ attn)
{
  __shared__ h16 lds[(2*128 + 2*64)*LDK];
  const int n0 = blockIdx.x*64, m0 = blockIdx.y*128;
  f32x4 a1[4][2] = {}; f32x4 a2[4][2] = {};
  gemm128x64_core(Oh, Ol, Wh, Wl, 1024, 1024, 1024, m0, n0, a1, a2, lds);
  EPI_W;
  #pragma unroll
  for (int i = 0; i < 4; ++i)
    #pragma unroll
    for (int j = 0; j < 2; ++j)
      #pragma unroll
      for (int r = 0; r < 4; ++r) {
        int row = m0 + wr + i*16 + rb + r;
        int col = n0 + wc + j*16 + fr;
        attn[(long)row*DM + col] =
            (a1[i][j][r] + a2[i][j][r]*(1.0f/4096.0f)) * (1.0f/1024.0f) + bias[col];
      }
}

// LayerNorm of (A + Badd): optional fp32 out, f16(x*16) out, direct out
__global__ __launch_bounds__(256) void k_ln(
    const float* __restrict__ A, const float* __restrict__ Badd,
    const float* __restrict__ g, const float* __restrict__ be,
    float* __restrict__ xout, h16* __restrict__ xh, float* __restrict__ dout)
{
  int wave = threadIdx.x >> 6, lane = threadIdx.x & 63;
  long row = (long)blockIdx.x*4 + wave;
  const float* ar = A + row*DM; const float* br = Badd + row*DM;
  float v[16]; float s = 0.0f;
  #pragma unroll
  for (int p = 0; p < 4; ++p) {
    int d = p*256 + lane*4;
    float4 a = *(const float4*)(ar + d);
    float4 b = *(const float4*)(br + d);
    float t0=a.x+b.x, t1=a.y+b.y, t2=a.z+b.z, t3=a.w+b.w;
    v[4*p+0]=t0; v[4*p+1]=t1; v[4*p+2]=t2; v[4*p+3]=t3;
    s += t0+t1+t2+t3;
  }
  s = wave_sum(s);
  float m = s * (1.0f/1024.0f);
  float q = 0.0f;
  #pragma unroll
  for (int i = 0; i < 16; ++i) { float dd = v[i]-m; q += dd*dd; }
  q = wave_sum(q);
  float rs = (float)(1.0 / sqrt((double)(q * (1.0f/1024.0f) + 1e-5f)));
  #pragma unroll
  for (int p = 0; p < 4; ++p) {
    int d = p*256 + lane*4;
    float4 gv = *(const float4*)(g + d);
    float4 bv = *(const float4*)(be + d);
    float y0 = (v[4*p+0]-m)*rs*gv.x + bv.x;
    float y1 = (v[4*p+1]-m)*rs*gv.y + bv.y;
    float y2 = (v[4*p+2]-m)*rs*gv.z + bv.z;
    float y3 = (v[4*p+3]-m)*rs*gv.w + bv.w;
    if (xout) { float4 o = {y0,y1,y2,y3}; *(float4*)(xout + row*DM + d) = o; }
    if (xh) {
      h16x4 hv; hv[0]=(h16)(y0*16.f); hv[1]=(h16)(y1*16.f);
      hv[2]=(h16)(y2*16.f); hv[3]=(h16)(y3*16.f);
      *(h16x4*)(xh + row*DM + d) = hv;
    }
    if (dout) { float4 o = {y0,y1,y2,y3}; *(float4*)(dout + row*DM + d) = o; }
  }
}

// ---------------------------------------------------------------------------
// threefry2x32 (key=[0,42]) -> gumbel -> argmax. VERIFIED round 5 — DO NOT TOUCH.
// partitionable bits = b1 ^ b2, counter = (0, i).
// ---------------------------------------------------------------------------
__device__ __forceinline__ void threefry(u32 x0, u32 x1, u32& y0, u32& y1) {
  const u32 ks0 = 0u, ks1 = 42u, ks2 = 0x1BD11BDAu ^ 42u;
  x0 += ks0; x1 += ks1;
  #define TF_R(r) { x0 += x1; x1 = (x1 << r) | (x1 >> (32 - r)); x1 ^= x0; }
  TF_R(13) TF_R(15) TF_R(26) TF_R(6)  x0 += ks1; x1 += ks2 + 1u;
  TF_R(17) TF_R(29) TF_R(16) TF_R(24) x0 += ks2; x1 += ks0 + 2u;
  TF_R(13) TF_R(15) TF_R(26) TF_R(6)  x0 += ks0; x1 += ks1 + 3u;
  TF_R(17) TF_R(29) TF_R(16) TF_R(24) x0 += ks1; x1 += ks2 + 4u;
  TF_R(13) TF_R(15) TF_R(26) TF_R(6)  x0 += ks2; x1 += ks0 + 5u;
  #undef TF_R
  y0 = x0; y1 = x1;
}

__device__ __forceinline__ float gumbel_from(u32 bits) {
  float f = __uint_as_float((bits >> 9) | 0x3F800000u) - 1.0f;
  float u = (f > 0.0f) ? f : 1.17549435e-38f;
  float nl = (float)(-log((double)u));
  return -(float)log((double)nl);
}

__global__ __launch_bounds__(256) void k_gate(
    const float* __restrict__ x, const float* __restrict__ gw,
    const float* __restrict__ gb, int* __restrict__ chosen, int* __restrict__ counts)
{
  int wave = threadIdx.x >> 6, lane = threadIdx.x & 63;
  long t = (long)blockIdx.x*4 + wave;
  const float* xr = x + t*DM;
  float p[4] = {0.f,0.f,0.f,0.f};
  #pragma unroll
  for (int pp = 0; pp < 4; ++pp) {
    int d = pp*256 + lane*4;
    float4 xv = *(const float4*)(xr + d);
    #pragma unroll
    for (int e = 0; e < 4; ++e) {
      float4 gv = *(const float4*)(gw + e*DM + d);
      p[e] += xv.x*gv.x + xv.y*gv.y + xv.z*gv.z + xv.w*gv.w;
    }
  }
  #pragma unroll
  for (int e = 0; e < 4; ++e) p[e] = wave_sum(p[e]);
  if (lane == 0) {
    float best = -3.0e38f; int arg = 0;
    #pragma unroll
    for (int e = 0; e < 4; ++e) {
      float logit = p[e] + gb[e];
      u32 j = (u32)(4*t + e);
      u32 y0, y1;
      threefry(0u, j, y0, y1);
      float v = gumbel_from(y0 ^ y1) + logit;
      if (v > best) { best = v; arg = e; }
    }
    chosen[(int)t] = arg;
    atomicAdd(&counts[arg], 1);
  }
}

__global__ void k_offsets(const int* __restrict__ counts, int* __restrict__ eoff) {
  if (threadIdx.x == 0 && blockIdx.x == 0) {
    int o = 0;
    for (int e = 0; e < 4; ++e) { eoff[e] = o; o += (counts[e] + 63) & ~63; }
  }
}

__global__ void k_fill(int* __restrict__ p, int n) {
  int i = blockIdx.x*256 + threadIdx.x;
  if (i < n) p[i] = -1;
}

__global__ void k_scatter(const int* __restrict__ chosen, const int* __restrict__ eoff,
                          int* __restrict__ cursor, int* __restrict__ plist) {
  int t = blockIdx.x*256 + threadIdx.x;
  if (t >= BS) return;
  int e = chosen[t];
  int slot = atomicAdd(&cursor[e], 1);
  plist[eoff[e] + slot] = t;
}

// MoE layer 1 (gathered rows): h = relu(x.w1[e]^T + b1[e]), f16 MFMA
__global__ __launch_bounds__(256) void k_e1(
    const h16* __restrict__ Xh, const h16* __restrict__ W1, const float* __restrict__ b1,
    const int* __restrict__ plist, const int* __restrict__ eoff, h16* __restrict__ Hh)
{
  __shared__ h16 lds[2*64*LDK];
  const int n0 = blockIdx.x*64, m0 = blockIdx.y*64;
  const int e = (m0 >= eoff[1]) + (m0 >= eoff[2]) + (m0 >= eoff[3]);
  f32x4 acc[2][2] = {};
  hgemm_core<true>(Xh, W1 + (long)e*DFE*DM, 1024, 1024, 1024, m0, n0, plist, acc, lds);
  EPI64;
  #pragma unroll
  for (int i = 0; i < 2; ++i)
    #pragma unroll
    for (int j = 0; j < 2; ++j)
      #pragma unroll
      for (int r = 0; r < 4; ++r) {
        int row = m0 + wm + i*16 + rb + r;
        int col = n0 + wn + j*16 + fr;
        float c = acc[i][j][r] * (1.0f/1024.0f) + b1[e*DFE + col];
        c = fmaxf(c, 0.0f);
        Hh[(long)row*DFE + col] = (h16)(c * 16.0f);
      }
}

// MoE layer 2 (bucket rows, scatter out): y[t] = h.w2[e]^T + b2[e]
__global__ __launch_bounds__(256) void k_e2(
    const h16* __restrict__ Hh, const h16* __restrict__ W2, const float* __restrict__ b2,
    const int* __restrict__ plist, const int* __restrict__ eoff, float* __restrict__ y)
{
  __shared__ h16 lds[2*64*LDK];
  const int n0 = blockIdx.x*64, m0 = blockIdx.y*64;
  const int e = (m0 >= eoff[1]) + (m0 >= eoff[2]) + (m0 >= eoff[3]);
  f32x4 acc[2][2] = {};
  hgemm_core<false>(Hh, W2 + (long)e*DM*DFE, 1024, DFE, DFE, m0, n0, nullptr, acc, lds);
  EPI64;
  #pragma unroll
  for (int i = 0; i < 2; ++i)
    #pragma unroll
    for (int j = 0; j < 2; ++j)
      #pragma unroll
      for (int r = 0; r < 4; ++r) {
        int row = m0 + wm + i*16 + rb + r;
        int col = n0 + wn + j*16 + fr;
        int t = plist[row];
        if (t >= 0)
          y[(long)t*DM + col] = acc[i][j][r] * (1.0f/1024.0f) + b2[e*DM + col];
      }
}

// ---------------------------------------------------------------------------
extern "C" void kernel_launch(void* const* d_in, const int* in_sizes, int n_in,
                              void* d_out, int out_size, void* d_ws, size_t ws_size,
                              hipStream_t stream) {
  const float* src = (const float*)d_in[0];
  const float* pos = (const float*)d_in[1];
  const float* w3  = (const float*)d_in[2];
  const float* b3  = (const float*)d_in[3];
  const float* wo  = (const float*)d_in[4];
  const float* bo  = (const float*)d_in[5];
  const float* gw  = (const float*)d_in[6];
  const float* gb  = (const float*)d_in[7];
  const float* w1  = (const float*)d_in[8];
  const float* b1  = (const float*)d_in[9];
  const float* w2  = (const float*)d_in[10];
  const float* b2  = (const float*)d_in[11];
  const float* g1  = (const float*)d_in[12];
  const float* be1 = (const float*)d_in[13];
  const float* g2  = (const float*)d_in[14];
  const float* be2 = (const float*)d_in[15];
  float* out = (float*)d_out;
  char* ws = (char*)d_ws;
  if (ws_size < WS_NEEDED) return;

  auto H = [&](size_t off) { return (h16*)(ws + off); };
  auto F = [&](size_t off) { return (float*)(ws + off); };
  auto I = [&](size_t off) { return (int*)(ws + off); };

  // zero atomic counters (counts[4] + cursor[4] contiguous)
  k_zero8<<<1, 64, 0, stream>>>(I(OFF_COUNTS));

  // input + weight splits
  k_split_in<<<BS*DM/4/256, 256, 0, stream>>>(src, pos,
      H(OFF_QKH), H(OFF_QKL), H(OFF_SRCH), H(OFF_SRCL));
  k_split2<<<3*DM*DM/4/256, 256, 0, stream>>>(w3, H(OFF_W3H), H(OFF_W3L), 64.0f, 3*DM*DM/4);
  k_split2<<<DM*DM/4/256, 256, 0, stream>>>(wo, H(OFF_WOH), H(OFF_WOL), 64.0f, DM*DM/4);

  // QKV projection
  k_qkv<<<dim3(48, 64), 256, 0, stream>>>(
      H(OFF_QKH), H(OFF_QKL), H(OFF_SRCH), H(OFF_SRCL), H(OFF_W3H), H(OFF_W3L), b3,
      H(OFF_QH), H(OFF_QL), H(OFF_KH), H(OFF_KL), H(OFF_VH), H(OFF_VL));

  // fused flash attention (one dispatch)
  k_attn<<<dim3(NCHUNK, NBH), 256, 0, stream>>>(
      H(OFF_QH), H(OFF_QL), H(OFF_KH), H(OFF_KL), H(OFF_VH), H(OFF_VL),
      H(OFF_OH), H(OFF_OL));

  // out projection + LN1
  k_out<<<dim3(16, 64), 256, 0, stream>>>(
      H(OFF_OH), H(OFF_OL), H(OFF_WOH), H(OFF_WOL), bo, F(OFF_ATT));
  k_ln<<<BS/4, 256, 0, stream>>>(src, F(OFF_ATT), g1, be1, F(OFF_X), H(OFF_XH), nullptr);

  // gate + expert bucketing
  k_gate<<<BS/4, 256, 0, stream>>>(F(OFF_X), gw, gb, I(OFF_CHOSEN), I(OFF_COUNTS));
  k_offsets<<<1, 64, 0, stream>>>(I(OFF_COUNTS), I(OFF_EOFF));
  k_fill<<<(NPOS+255)/256, 256, 0, stream>>>(I(OFF_PLIST), NPOS);
  k_scatter<<<BS/256, 256, 0, stream>>>(I(OFF_CHOSEN), I(OFF_EOFF), I(OFF_CURSOR), I(OFF_PLIST));

  // MoE weights to f16 (regions freed by flash) and bucketed expert FFN
  k_tof16<<<NE*DFE*DM/4/256, 256, 0, stream>>>(w1, H(OFF_W1H), 64.0f, NE*DFE*DM/4);
  k_tof16<<<NE*DM*DFE/4/256, 256, 0, stream>>>(w2, H(OFF_W2H), 64.0f, NE*DM*DFE/4);
  k_e1<<<dim3(16, NPOS/64), 256, 0, stream>>>(
      H(OFF_XH), H(OFF_W1H), b1, I(OFF_PLIST), I(OFF_EOFF), H(OFF_HH));
  k_e2<<<dim3(16, NPOS/64), 256, 0, stream>>>(
      H(OFF_HH), H(OFF_W2H), b2, I(OFF_PLIST), I(OFF_EOFF), F(OFF_Y));

  // final LN2 -> output
  k_ln<<<BS/4, 256, 0, stream>>>(F(OFF_X), F(OFF_Y), g2, be2, nullptr, nullptr, out);
}

// Round 9
// 951.955 us; speedup vs baseline: 2.3451x; 1.0064x over previous
//
#include <hip/hip_runtime.h>
#include <cstdint>
#include <cstddef>

// ---------------------------------------------------------------------------
// TransformerEncoderLayer on MI355X (gfx950).
// Pre-gate GEMMs: f16 hi/lo split MFMA (3 mfma/product) — validated bit-equal
// to fp32 routing. Attention: fused flash kernel, XCD-swizzled grid so each
// bh's K/V stays in one XCD's L2. Gate RNG: partitionable threefry, b1^b2
// (VERIFIED round 5 — DO NOT TOUCH). MoE: bucketed per-expert f16 MFMA on a
// 128x64 core (8 MFMA : 6 ds_read per wave K-step); buckets 128-padded.
// ---------------------------------------------------------------------------

typedef _Float16 h16;
typedef h16 h16x8 __attribute__((ext_vector_type(8)));
typedef h16 h16x4 __attribute__((ext_vector_type(4)));
typedef float f32x4 __attribute__((ext_vector_type(4)));
typedef uint32_t u32;

#define DM 1024
#define NH 16
#define HD 64
#define SEQ 1024
#define BB 8
#define BS (BB*SEQ)      /* 8192 tokens */
#define NBH (BB*NH)      /* 128 (b,h) pairs */
#define NE 4
#define DFE 1024
#define QB 64            /* query rows per attention chunk */
#define NCHUNK (SEQ/QB)  /* 16 */
#define LDK 40           /* LDS stride for 32-wide K-step slabs (GEMM cores) */
#define FLD 72           /* LDS stride for 64-wide flash tiles (64+8 pad) */
#define NPOS (68*128)    /* 8704: bucket capacity, 128-padded per expert */

#define MFMA16(a,b,c) __builtin_amdgcn_mfma_f32_16x16x32_f16(a,b,c,0,0,0)

// ---- workspace layout (bytes). E = one h16 plane of [8192][1024]. ----
static constexpr size_t E = (size_t)BS*DM*2;            // 16,777,216
static constexpr size_t OFF_QKH = 0;                    // qk split (dead after qkv)
static constexpr size_t OFF_QKL = E;
static constexpr size_t OFF_SRCH= 2*E;
static constexpr size_t OFF_SRCL= 3*E;
static constexpr size_t OFF_W3H = 4*E;
static constexpr size_t OFF_W3L = 4*E + (size_t)3*DM*DM*2;
static constexpr size_t OFF_WOH = 4*E + (size_t)6*DM*DM*2;
static constexpr size_t OFF_WOL = 4*E + (size_t)7*DM*DM*2;   // ends at 5E
static constexpr size_t OFF_QH  = 5*E;                  // Q,K [bh][s][d]; V^T [bh][d][s]
static constexpr size_t OFF_QL  = 6*E;
static constexpr size_t OFF_KH  = 7*E;
static constexpr size_t OFF_KL  = 8*E;
static constexpr size_t OFF_VH  = 9*E;
static constexpr size_t OFF_VL  = 10*E;
static constexpr size_t OFF_OH  = 0;                    // after flash (qk dead)
static constexpr size_t OFF_OL  = E;
static constexpr size_t OFF_ATT = 2*E;                  // fp32 (src splits dead)
static constexpr size_t OFF_X   = 5*E;                  // fp32 2E (Q,Ql dead)
static constexpr size_t OFF_XH  = 7*E;                  // f16 x*16 (Kh dead)
static constexpr size_t OFF_W1H = 8*E;                  // f16 (Kl dead)
static constexpr size_t OFF_W2H = 8*E + (size_t)NE*DFE*DM*2;  // ends at 9E
static constexpr size_t OFF_HH  = 9*E;                  // bucket h f16 [NPOS][1024] (V dead)
static constexpr size_t OFF_Y   = 11*E;                 // fp32 2E
static constexpr size_t OFF_CHOSEN = 13*E;
static constexpr size_t OFF_COUNTS = 13*E + 32768;
static constexpr size_t OFF_CURSOR = OFF_COUNTS + 16;
static constexpr size_t OFF_EOFF   = OFF_CURSOR + 16;
static constexpr size_t OFF_PLIST  = OFF_EOFF + 16;
static constexpr size_t WS_NEEDED  = OFF_PLIST + (size_t)NPOS*4;

// ---------------------------------------------------------------------------
__device__ __forceinline__ void store_split(h16* H, h16* L, size_t idx, float v) {
  h16 h = (h16)v;
  H[idx] = h;
  L[idx] = (h16)((v - (float)h) * 4096.0f);
}

__device__ __forceinline__ float wave_sum(float v) {
  #pragma unroll
  for (int o = 32; o; o >>= 1) v += __shfl_xor(v, o);
  return v;
}

// ---------------------------------------------------------------------------
// 128(M)x64(N) split-f16 MFMA core. 4 waves, each 64x32 (4x2 frags 16x16x32).
// ---------------------------------------------------------------------------
__device__ __forceinline__ void gemm128x64_core(
    const h16* __restrict__ Ah, const h16* __restrict__ Al,
    const h16* __restrict__ Bh, const h16* __restrict__ Bl,
    int K, int lda, int ldb, int m0, int n0,
    f32x4 (&a1)[4][2], f32x4 (&a2)[4][2], h16* lds)
{
  const int tid = threadIdx.x, lane = tid & 63, wid = tid >> 6;
  const int wr = (wid >> 1) * 64, wc = (wid & 1) * 32;
  h16* sAh = lds;               h16* sAl = lds + 128*LDK;
  h16* sBh = lds + 2*128*LDK;   h16* sBl = lds + 2*128*LDK + 64*LDK;
  const int arow = tid >> 1, akc = (tid & 1) * 16;
  const int brow = tid >> 2, bkc = (tid & 3) * 8;
  const long abase = (long)(m0 + arow) * lda + akc;
  const long bbase = (long)(n0 + brow) * ldb + bkc;
  const int fr = lane & 15, kg = (lane >> 4) << 3;
  for (int k0 = 0; k0 < K; k0 += 32) {
    __syncthreads();
    *(uint4*)(sAh + arow*LDK + akc)     = *(const uint4*)(Ah + abase + k0);
    *(uint4*)(sAh + arow*LDK + akc + 8) = *(const uint4*)(Ah + abase + k0 + 8);
    *(uint4*)(sAl + arow*LDK + akc)     = *(const uint4*)(Al + abase + k0);
    *(uint4*)(sAl + arow*LDK + akc + 8) = *(const uint4*)(Al + abase + k0 + 8);
    *(uint4*)(sBh + brow*LDK + bkc)     = *(const uint4*)(Bh + bbase + k0);
    *(uint4*)(sBl + brow*LDK + bkc)     = *(const uint4*)(Bl + bbase + k0);
    __syncthreads();
    h16x8 ah[4], al[4], bh[2], bl[2];
    #pragma unroll
    for (int i = 0; i < 4; ++i) {
      ah[i] = *(const h16x8*)(sAh + (wr + i*16 + fr)*LDK + kg);
      al[i] = *(const h16x8*)(sAl + (wr + i*16 + fr)*LDK + kg);
    }
    #pragma unroll
    for (int j = 0; j < 2; ++j) {
      bh[j] = *(const h16x8*)(sBh + (wc + j*16 + fr)*LDK + kg);
      bl[j] = *(const h16x8*)(sBl + (wc + j*16 + fr)*LDK + kg);
    }
    #pragma unroll
    for (int i = 0; i < 4; ++i)
      #pragma unroll
      for (int j = 0; j < 2; ++j) {
        a1[i][j] = MFMA16(ah[i], bh[j], a1[i][j]);
        a2[i][j] = MFMA16(ah[i], bl[j], a2[i][j]);
        a2[i][j] = MFMA16(al[i], bh[j], a2[i][j]);
      }
  }
}

#define EPI_W \
  const int lane = threadIdx.x & 63, wid = threadIdx.x >> 6; \
  const int wr = (wid>>1)*64, wc = (wid&1)*32; \
  const int fr = lane & 15, rb = (lane>>4)*4;

// ---------------------------------------------------------------------------
// 128(M)x64(N) f16 single MFMA core for MoE (8 MFMA : 6 ds_read_b128 per wave
// K-step), optional row gather on A. acc = 32 regs/thread.
// ---------------------------------------------------------------------------
template<bool GATHER>
__device__ __forceinline__ void hgemm128_core(
    const h16* __restrict__ A, const h16* __restrict__ B,
    int K, int lda, int ldb, int m0, int n0, const int* __restrict__ rowmap,
    f32x4 (&acc)[4][2], h16* lds)
{
  const int tid = threadIdx.x, lane = tid & 63, wid = tid >> 6;
  const int wr = (wid >> 1) * 64, wc = (wid & 1) * 32;
  h16* sA = lds;              // [128][LDK]
  h16* sB = lds + 128*LDK;    // [64][LDK]
  const int arow = tid >> 1, akc = (tid & 1) * 16;
  const int brow = tid >> 2, bkc = (tid & 3) * 8;
  long abase; bool aval = true;
  if (GATHER) { int t = rowmap[m0 + arow]; aval = (t >= 0);
                abase = (long)(aval ? t : 0) * lda + akc; }
  else          abase = (long)(m0 + arow) * lda + akc;
  const long bbase = (long)(n0 + brow) * ldb + bkc;
  const int fr = lane & 15, kg = (lane >> 4) << 3;
  for (int k0 = 0; k0 < K; k0 += 32) {
    __syncthreads();
    uint4 va0 = (!GATHER || aval) ? *(const uint4*)(A + abase + k0)     : make_uint4(0,0,0,0);
    uint4 va1 = (!GATHER || aval) ? *(const uint4*)(A + abase + k0 + 8) : make_uint4(0,0,0,0);
    *(uint4*)(sA + arow*LDK + akc)     = va0;
    *(uint4*)(sA + arow*LDK + akc + 8) = va1;
    *(uint4*)(sB + brow*LDK + bkc)     = *(const uint4*)(B + bbase + k0);
    __syncthreads();
    h16x8 a_[4], b_[2];
    #pragma unroll
    for (int i = 0; i < 4; ++i)
      a_[i] = *(const h16x8*)(sA + (wr + i*16 + fr)*LDK + kg);
    #pragma unroll
    for (int j = 0; j < 2; ++j)
      b_[j] = *(const h16x8*)(sB + (wc + j*16 + fr)*LDK + kg);
    #pragma unroll
    for (int i = 0; i < 4; ++i)
      #pragma unroll
      for (int j = 0; j < 2; ++j)
        acc[i][j] = MFMA16(a_[i], b_[j], acc[i][j]);
  }
}

// ---------------------------------------------------------------------------
// prep kernels
// ---------------------------------------------------------------------------
__global__ void k_zero8(int* __restrict__ p) {
  if (threadIdx.x < 8) p[threadIdx.x] = 0;   // counts[4] + cursor[4]
}

__global__ void k_split_in(const float* __restrict__ src, const float* __restrict__ pos,
                           h16* __restrict__ qkH, h16* __restrict__ qkL,
                           h16* __restrict__ sH,  h16* __restrict__ sL) {
  int i = blockIdx.x*256 + threadIdx.x;
  float4 s = ((const float4*)src)[i];
  float4 p = ((const float4*)pos)[i];
  float sv[4] = {s.x, s.y, s.z, s.w};
  float qv[4] = {s.x+p.x, s.y+p.y, s.z+p.z, s.w+p.w};
  h16x4 sh, sl, qh, ql;
  #pragma unroll
  for (int q = 0; q < 4; ++q) {
    float xs = sv[q] * 16.0f; h16 hs = (h16)xs;
    sh[q] = hs; sl[q] = (h16)((xs - (float)hs) * 4096.0f);
    float xq = qv[q] * 16.0f; h16 hq = (h16)xq;
    qh[q] = hq; ql[q] = (h16)((xq - (float)hq) * 4096.0f);
  }
  ((h16x4*)sH)[i] = sh; ((h16x4*)sL)[i] = sl;
  ((h16x4*)qkH)[i] = qh; ((h16x4*)qkL)[i] = ql;
}

__global__ void k_split2(const float* __restrict__ a,
                         h16* __restrict__ H, h16* __restrict__ L, float scale, int n4) {
  int i = blockIdx.x*256 + threadIdx.x;
  if (i >= n4) return;
  float4 v = ((const float4*)a)[i];
  float vv[4] = {v.x, v.y, v.z, v.w};
  h16x4 hv, lv;
  #pragma unroll
  for (int q = 0; q < 4; ++q) {
    float x = vv[q] * scale;
    h16 h = (h16)x;
    hv[q] = h;
    lv[q] = (h16)((x - (float)h) * 4096.0f);
  }
  ((h16x4*)H)[i] = hv;
  ((h16x4*)L)[i] = lv;
}

__global__ void k_tof16(const float* __restrict__ a, h16* __restrict__ H, float scale, int n4) {
  int i = blockIdx.x*256 + threadIdx.x;
  if (i >= n4) return;
  float4 v = ((const float4*)a)[i];
  h16x4 hv;
  hv[0] = (h16)(v.x*scale); hv[1] = (h16)(v.y*scale);
  hv[2] = (h16)(v.z*scale); hv[3] = (h16)(v.w*scale);
  ((h16x4*)H)[i] = hv;
}

// ---------------------------------------------------------------------------
// QKV projection (128x64 split MFMA tiles)
// ---------------------------------------------------------------------------
__global__ __launch_bounds__(256) void k_qkv(
    const h16* __restrict__ qkh, const h16* __restrict__ qkl,
    const h16* __restrict__ sh,  const h16* __restrict__ sl,
    const h16* __restrict__ Wh,  const h16* __restrict__ Wl, const float* __restrict__ bias,
    h16* __restrict__ Qh, h16* __restrict__ Ql, h16* __restrict__ Kh, h16* __restrict__ Kl,
    h16* __restrict__ Vh, h16* __restrict__ Vl)
{
  __shared__ h16 lds[(2*128 + 2*64)*LDK];
  const int n0 = blockIdx.x*64, m0 = blockIdx.y*128;
  const bool isV = (n0 >= 2048);
  f32x4 a1[4][2] = {}; f32x4 a2[4][2] = {};
  gemm128x64_core(isV ? sh : qkh, isV ? sl : qkl, Wh, Wl,
                  1024, 1024, 1024, m0, n0, a1, a2, lds);
  EPI_W;
  #pragma unroll
  for (int i = 0; i < 4; ++i)
    #pragma unroll
    for (int j = 0; j < 2; ++j)
      #pragma unroll
      for (int r = 0; r < 4; ++r) {
        int row = m0 + wr + i*16 + rb + r;
        int col = n0 + wc + j*16 + fr;
        float c = (a1[i][j][r] + a2[i][j][r]*(1.0f/4096.0f)) * (1.0f/1024.0f) + bias[col];
        int b = row >> 10, s = row & 1023;
        int cc = col & 1023, h = cc >> 6, d = cc & 63;
        long bh = (long)b*NH + h;
        float cs = c * 16.0f;
        if (col < 1024)      store_split(Qh, Ql, (bh*SEQ + s)*HD + d, cs);
        else if (col < 2048) store_split(Kh, Kl, (bh*SEQ + s)*HD + d, cs);
        else                 store_split(Vh, Vl, (bh*HD + d)*SEQ + s, cs);
      }
}

// ---------------------------------------------------------------------------
// Fused flash attention. 1D grid of 2048 blocks with bijective XCD swizzle:
// all 16 q-chunks of a bh land on one XCD (K/V stay L2-resident there).
// 4 waves, each owns 16 q-rows. LDS tiles 64x64 h16, stride FLD=72.
// ---------------------------------------------------------------------------
__global__ __launch_bounds__(256) void k_attn(
    const h16* __restrict__ Qh, const h16* __restrict__ Ql,
    const h16* __restrict__ Kh, const h16* __restrict__ Kl,
    const h16* __restrict__ Vh, const h16* __restrict__ Vl,
    h16* __restrict__ Oh, h16* __restrict__ Ol)
{
  __shared__ h16 lds[6*64*FLD];   // 55,296 B
  h16* sKh = lds;            h16* sKl = lds + 64*FLD;
  h16* sVh = lds + 2*64*FLD; h16* sVl = lds + 3*64*FLD;
  h16* sPh = lds + 4*64*FLD; h16* sPl = lds + 5*64*FLD;
  const int bid = blockIdx.x;                  // 0..2047
  const int swz = (bid & 7) * 256 + (bid >> 3);   // bijective (2048 = 8*256)
  const int bh = swz >> 4;
  const int q0 = (swz & 15) * QB;
  const int tid = threadIdx.x, lane = tid & 63, w = tid >> 6;
  const int fr = lane & 15, hg = lane >> 4;   // 0..3
  const int kg = hg << 3;
  // Q fragments (A layout), scale 16
  const long qbase = ((long)bh*SEQ + q0 + w*16 + fr) * HD;
  h16x8 qh[2], ql[2];
  qh[0] = *(const h16x8*)(Qh + qbase + kg);
  qh[1] = *(const h16x8*)(Qh + qbase + 32 + kg);
  ql[0] = *(const h16x8*)(Ql + qbase + kg);
  ql[1] = *(const h16x8*)(Ql + qbase + 32 + kg);
  f32x4 o1[4] = {}, o2[4] = {};
  float mrow[4] = {-3.0e38f, -3.0e38f, -3.0e38f, -3.0e38f};
  float lrow[4] = {0.f, 0.f, 0.f, 0.f};
  // staging: 64 rows x 64 h16, 4 threads/row, 16 h16 each
  const int srow = tid >> 2, skc = (tid & 3) << 4;
  const long kbase = ((long)bh*SEQ + srow) * HD + skc;
  const long vbase = ((long)bh*HD + srow) * SEQ + skc;
  for (int kt = 0; kt < NCHUNK; ++kt) {
    const int n0 = kt * QB;
    __syncthreads();
    {
      const long ka = kbase + (long)n0*HD;
      *(uint4*)(sKh + srow*FLD + skc)     = *(const uint4*)(Kh + ka);
      *(uint4*)(sKh + srow*FLD + skc + 8) = *(const uint4*)(Kh + ka + 8);
      *(uint4*)(sKl + srow*FLD + skc)     = *(const uint4*)(Kl + ka);
      *(uint4*)(sKl + srow*FLD + skc + 8) = *(const uint4*)(Kl + ka + 8);
      const long va = vbase + n0;
      *(uint4*)(sVh + srow*FLD + skc)     = *(const uint4*)(Vh + va);
      *(uint4*)(sVh + srow*FLD + skc + 8) = *(const uint4*)(Vh + va + 8);
      *(uint4*)(sVl + srow*FLD + skc)     = *(const uint4*)(Vl + va);
      *(uint4*)(sVl + srow*FLD + skc + 8) = *(const uint4*)(Vl + va + 8);
    }
    __syncthreads();
    // S = Q.K^T (split)
    f32x4 s1[4] = {}, s2[4] = {};
    #pragma unroll
    for (int ks = 0; ks < 2; ++ks)
      #pragma unroll
      for (int j = 0; j < 4; ++j) {
        h16x8 kh = *(const h16x8*)(sKh + (j*16 + fr)*FLD + ks*32 + kg);
        h16x8 kl = *(const h16x8*)(sKl + (j*16 + fr)*FLD + ks*32 + kg);
        s1[j] = MFMA16(qh[ks], kh, s1[j]);
        s2[j] = MFMA16(qh[ks], kl, s2[j]);
        s2[j] = MFMA16(ql[ks], kh, s2[j]);
      }
    // online softmax (rows = hg*4 + r)
    float p[4][4];   // [j][r]
    float tmax[4] = {-3.0e38f, -3.0e38f, -3.0e38f, -3.0e38f};
    #pragma unroll
    for (int j = 0; j < 4; ++j)
      #pragma unroll
      for (int r = 0; r < 4; ++r) {
        float sc = (s1[j][r] + s2[j][r]*(1.0f/4096.0f)) * (0.125f/256.0f);
        p[j][r] = sc;
        tmax[r] = fmaxf(tmax[r], sc);
      }
    #pragma unroll
    for (int o = 1; o < 16; o <<= 1)
      #pragma unroll
      for (int r = 0; r < 4; ++r) tmax[r] = fmaxf(tmax[r], __shfl_xor(tmax[r], o));
    float scl[4], psum[4];
    #pragma unroll
    for (int r = 0; r < 4; ++r) {
      float mn = fmaxf(mrow[r], tmax[r]);
      scl[r] = expf(mrow[r] - mn);
      mrow[r] = mn;
      psum[r] = 0.f;
      #pragma unroll
      for (int j = 0; j < 4; ++j) { p[j][r] = expf(p[j][r] - mn); psum[r] += p[j][r]; }
    }
    #pragma unroll
    for (int o = 1; o < 16; o <<= 1)
      #pragma unroll
      for (int r = 0; r < 4; ++r) psum[r] += __shfl_xor(psum[r], o);
    #pragma unroll
    for (int r = 0; r < 4; ++r) lrow[r] = lrow[r]*scl[r] + psum[r];
    #pragma unroll
    for (int j = 0; j < 4; ++j)
      #pragma unroll
      for (int r = 0; r < 4; ++r) { o1[j][r] *= scl[r]; o2[j][r] *= scl[r]; }
    // write P split (scale 512) to LDS, rows w*16 + hg*4 + r, cols j*16+fr
    #pragma unroll
    for (int j = 0; j < 4; ++j)
      #pragma unroll
      for (int r = 0; r < 4; ++r) {
        float pv = p[j][r] * 512.0f;
        h16 ph = (h16)pv;
        h16 pl = (h16)((pv - (float)ph) * 4096.0f);
        int off = (w*16 + hg*4 + r)*FLD + j*16 + fr;
        sPh[off] = ph;
        sPl[off] = pl;
      }
    __syncthreads();
    // PV (split): O += P.V
    #pragma unroll
    for (int ks = 0; ks < 2; ++ks) {
      h16x8 pa = *(const h16x8*)(sPh + (w*16 + fr)*FLD + ks*32 + kg);
      h16x8 pb = *(const h16x8*)(sPl + (w*16 + fr)*FLD + ks*32 + kg);
      #pragma unroll
      for (int jd = 0; jd < 4; ++jd) {
        h16x8 vh = *(const h16x8*)(sVh + (jd*16 + fr)*FLD + ks*32 + kg);
        h16x8 vl = *(const h16x8*)(sVl + (jd*16 + fr)*FLD + ks*32 + kg);
        o1[jd] = MFMA16(pa, vh, o1[jd]);
        o2[jd] = MFMA16(pa, vl, o2[jd]);
        o2[jd] = MFMA16(pb, vh, o2[jd]);
      }
    }
  }
  // epilogue: normalize and store O split (scale 16)
  const int b = bh >> 4, h = bh & 15;
  #pragma unroll
  for (int jd = 0; jd < 4; ++jd)
    #pragma unroll
    for (int r = 0; r < 4; ++r) {
      int qrow = q0 + w*16 + hg*4 + r;
      int d = jd*16 + fr;
      float ov = (o1[jd][r] + o2[jd][r]*(1.0f/4096.0f)) / (512.0f*16.0f*lrow[r]);
      store_split(Oh, Ol, ((long)b*SEQ + qrow)*DM + h*HD + d, ov*16.0f);
    }
}

// out_proj (128x64 split): attn = O.Wo^T + bo, fp32
__global__ __launch_bounds__(256) void k_out(
    const h16* __restrict__ Oh, const h16* __restrict__ Ol,
    const h16* __restrict__ Wh, const h16* __restrict__ Wl,
    const float* __restrict__ bias, float* __restrict__ attn)
{
  __shared__ h16 lds[(2*128 + 2*64)*LDK];
  const int n0 = blockIdx.x*64, m0 = blockIdx.y*128;
  f32x4 a1[4][2] = {}; f32x4 a2[4][2] = {};
  gemm128x64_core(Oh, Ol, Wh, Wl, 1024, 1024, 1024, m0, n0, a1, a2, lds);
  EPI_W;
  #pragma unroll
  for (int i = 0; i < 4; ++i)
    #pragma unroll
    for (int j = 0; j < 2; ++j)
      #pragma unroll
      for (int r = 0; r < 4; ++r) {
        int row = m0 + wr + i*16 + rb + r;
        int col = n0 + wc + j*16 + fr;
        attn[(long)row*DM + col] =
            (a1[i][j][r] + a2[i][j][r]*(1.0f/4096.0f)) * (1.0f/1024.0f) + bias[col];
      }
}

// LayerNorm of (A + Badd): optional fp32 out, f16(x*16) out, direct out
__global__ __launch_bounds__(256) void k_ln(
    const float* __restrict__ A, const float* __restrict__ Badd,
    const float* __restrict__ g, const float* __restrict__ be,
    float* __restrict__ xout, h16* __restrict__ xh, float* __restrict__ dout)
{
  int wave = threadIdx.x >> 6, lane = threadIdx.x & 63;
  long row = (long)blockIdx.x*4 + wave;
  const float* ar = A + row*DM; const float* br = Badd + row*DM;
  float v[16]; float s = 0.0f;
  #pragma unroll
  for (int p = 0; p < 4; ++p) {
    int d = p*256 + lane*4;
    float4 a = *(const float4*)(ar + d);
    float4 b = *(const float4*)(br + d);
    float t0=a.x+b.x, t1=a.y+b.y, t2=a.z+b.z, t3=a.w+b.w;
    v[4*p+0]=t0; v[4*p+1]=t1; v[4*p+2]=t2; v[4*p+3]=t3;
    s += t0+t1+t2+t3;
  }
  s = wave_sum(s);
  float m = s * (1.0f/1024.0f);
  float q = 0.0f;
  #pragma unroll
  for (int i = 0; i < 16; ++i) { float dd = v[i]-m; q += dd*dd; }
  q = wave_sum(q);
  float rs = (float)(1.0 / sqrt((double)(q * (1.0f/1024.0f) + 1e-5f)));
  #pragma unroll
  for (int p = 0; p < 4; ++p) {
    int d = p*256 + lane*4;
    float4 gv = *(const float4*)(g + d);
    float4 bv = *(const float4*)(be + d);
    float y0 = (v[4*p+0]-m)*rs*gv.x + bv.x;
    float y1 = (v[4*p+1]-m)*rs*gv.y + bv.y;
    float y2 = (v[4*p+2]-m)*rs*gv.z + bv.z;
    float y3 = (v[4*p+3]-m)*rs*gv.w + bv.w;
    if (xout) { float4 o = {y0,y1,y2,y3}; *(float4*)(xout + row*DM + d) = o; }
    if (xh) {
      h16x4 hv; hv[0]=(h16)(y0*16.f); hv[1]=(h16)(y1*16.f);
      hv[2]=(h16)(y2*16.f); hv[3]=(h16)(y3*16.f);
      *(h16x4*)(xh + row*DM + d) = hv;
    }
    if (dout) { float4 o = {y0,y1,y2,y3}; *(float4*)(dout + row*DM + d) = o; }
  }
}

// ---------------------------------------------------------------------------
// threefry2x32 (key=[0,42]) -> gumbel -> argmax. VERIFIED round 5 — DO NOT TOUCH.
// partitionable bits = b1 ^ b2, counter = (0, i).
// ---------------------------------------------------------------------------
__device__ __forceinline__ void threefry(u32 x0, u32 x1, u32& y0, u32& y1) {
  const u32 ks0 = 0u, ks1 = 42u, ks2 = 0x1BD11BDAu ^ 42u;
  x0 += ks0; x1 += ks1;
  #define TF_R(r) { x0 += x1; x1 = (x1 << r) | (x1 >> (32 - r)); x1 ^= x0; }
  TF_R(13) TF_R(15) TF_R(26) TF_R(6)  x0 += ks1; x1 += ks2 + 1u;
  TF_R(17) TF_R(29) TF_R(16) TF_R(24) x0 += ks2; x1 += ks0 + 2u;
  TF_R(13) TF_R(15) TF_R(26) TF_R(6)  x0 += ks0; x1 += ks1 + 3u;
  TF_R(17) TF_R(29) TF_R(16) TF_R(24) x0 += ks1; x1 += ks2 + 4u;
  TF_R(13) TF_R(15) TF_R(26) TF_R(6)  x0 += ks2; x1 += ks0 + 5u;
  #undef TF_R
  y0 = x0; y1 = x1;
}

__device__ __forceinline__ float gumbel_from(u32 bits) {
  float f = __uint_as_float((bits >> 9) | 0x3F800000u) - 1.0f;
  float u = (f > 0.0f) ? f : 1.17549435e-38f;
  float nl = (float)(-log((double)u));
  return -(float)log((double)nl);
}

__global__ __launch_bounds__(256) void k_gate(
    const float* __restrict__ x, const float* __restrict__ gw,
    const float* __restrict__ gb, int* __restrict__ chosen, int* __restrict__ counts)
{
  int wave = threadIdx.x >> 6, lane = threadIdx.x & 63;
  long t = (long)blockIdx.x*4 + wave;
  const float* xr = x + t*DM;
  float p[4] = {0.f,0.f,0.f,0.f};
  #pragma unroll
  for (int pp = 0; pp < 4; ++pp) {
    int d = pp*256 + lane*4;
    float4 xv = *(const float4*)(xr + d);
    #pragma unroll
    for (int e = 0; e < 4; ++e) {
      float4 gv = *(const float4*)(gw + e*DM + d);
      p[e] += xv.x*gv.x + xv.y*gv.y + xv.z*gv.z + xv.w*gv.w;
    }
  }
  #pragma unroll
  for (int e = 0; e < 4; ++e) p[e] = wave_sum(p[e]);
  if (lane == 0) {
    float best = -3.0e38f; int arg = 0;
    #pragma unroll
    for (int e = 0; e < 4; ++e) {
      float logit = p[e] + gb[e];
      u32 j = (u32)(4*t + e);
      u32 y0, y1;
      threefry(0u, j, y0, y1);
      float v = gumbel_from(y0 ^ y1) + logit;
      if (v > best) { best = v; arg = e; }
    }
    chosen[(int)t] = arg;
    atomicAdd(&counts[arg], 1);
  }
}

__global__ void k_offsets(const int* __restrict__ counts, int* __restrict__ eoff) {
  if (threadIdx.x == 0 && blockIdx.x == 0) {
    int o = 0;
    for (int e = 0; e < 4; ++e) { eoff[e] = o; o += (counts[e] + 127) & ~127; }
  }
}

__global__ void k_fill(int* __restrict__ p, int n) {
  int i = blockIdx.x*256 + threadIdx.x;
  if (i < n) p[i] = -1;
}

__global__ void k_scatter(const int* __restrict__ chosen, const int* __restrict__ eoff,
                          int* __restrict__ cursor, int* __restrict__ plist) {
  int t = blockIdx.x*256 + threadIdx.x;
  if (t >= BS) return;
  int e = chosen[t];
  int slot = atomicAdd(&cursor[e], 1);
  plist[eoff[e] + slot] = t;
}

// MoE layer 1 (gathered rows, 128x64 core): h = relu(x.w1[e]^T + b1[e])
__global__ __launch_bounds__(256) void k_e1(
    const h16* __restrict__ Xh, const h16* __restrict__ W1, const float* __restrict__ b1,
    const int* __restrict__ plist, const int* __restrict__ eoff, h16* __restrict__ Hh)
{
  __shared__ h16 lds[(128 + 64)*LDK];
  const int n0 = blockIdx.x*64, m0 = blockIdx.y*128;
  const int e = (m0 >= eoff[1]) + (m0 >= eoff[2]) + (m0 >= eoff[3]);
  f32x4 acc[4][2] = {};
  hgemm128_core<true>(Xh, W1 + (long)e*DFE*DM, 1024, 1024, 1024, m0, n0, plist, acc, lds);
  EPI_W;
  #pragma unroll
  for (int i = 0; i < 4; ++i)
    #pragma unroll
    for (int j = 0; j < 2; ++j)
      #pragma unroll
      for (int r = 0; r < 4; ++r) {
        int row = m0 + wr + i*16 + rb + r;
        int col = n0 + wc + j*16 + fr;
        float c = acc[i][j][r] * (1.0f/1024.0f) + b1[e*DFE + col];
        c = fmaxf(c, 0.0f);
        Hh[(long)row*DFE + col] = (h16)(c * 16.0f);
      }
}

// MoE layer 2 (bucket rows, 128x64 core, scatter out): y[t] = h.w2[e]^T + b2[e]
__global__ __launch_bounds__(256) void k_e2(
    const h16* __restrict__ Hh, const h16* __restrict__ W2, const float* __restrict__ b2,
    const int* __restrict__ plist, const int* __restrict__ eoff, float* __restrict__ y)
{
  __shared__ h16 lds[(128 + 64)*LDK];
  const int n0 = blockIdx.x*64, m0 = blockIdx.y*128;
  const int e = (m0 >= eoff[1]) + (m0 >= eoff[2]) + (m0 >= eoff[3]);
  f32x4 acc[4][2] = {};
  hgemm128_core<false>(Hh, W2 + (long)e*DM*DFE, 1024, DFE, DFE, m0, n0, nullptr, acc, lds);
  EPI_W;
  #pragma unroll
  for (int i = 0; i < 4; ++i)
    #pragma unroll
    for (int j = 0; j < 2; ++j)
      #pragma unroll
      for (int r = 0; r < 4; ++r) {
        int row = m0 + wr + i*16 + rb + r;
        int col = n0 + wc + j*16 + fr;
        int t = plist[row];
        if (t >= 0)
          y[(long)t*DM + col] = acc[i][j][r] * (1.0f/1024.0f) + b2[e*DM + col];
      }
}

// ---------------------------------------------------------------------------
extern "C" void kernel_launch(void* const* d_in, const int* in_sizes, int n_in,
                              void* d_out, int out_size, void* d_ws, size_t ws_size,
                              hipStream_t stream) {
  const float* src = (const float*)d_in[0];
  const float* pos = (const float*)d_in[1];
  const float* w3  = (const float*)d_in[2];
  const float* b3  = (const float*)d_in[3];
  const float* wo  = (const float*)d_in[4];
  const float* bo  = (const float*)d_in[5];
  const float* gw  = (const float*)d_in[6];
  const float* gb  = (const float*)d_in[7];
  const float* w1  = (const float*)d_in[8];
  const float* b1  = (const float*)d_in[9];
  const float* w2  = (const float*)d_in[10];
  const float* b2  = (const float*)d_in[11];
  const float* g1  = (const float*)d_in[12];
  const float* be1 = (const float*)d_in[13];
  const float* g2  = (const float*)d_in[14];
  const float* be2 = (const float*)d_in[15];
  float* out = (float*)d_out;
  char* ws = (char*)d_ws;
  if (ws_size < WS_NEEDED) return;

  auto H = [&](size_t off) { return (h16*)(ws + off); };
  auto F = [&](size_t off) { return (float*)(ws + off); };
  auto I = [&](size_t off) { return (int*)(ws + off); };

  // zero atomic counters (counts[4] + cursor[4] contiguous)
  k_zero8<<<1, 64, 0, stream>>>(I(OFF_COUNTS));

  // input + weight splits
  k_split_in<<<BS*DM/4/256, 256, 0, stream>>>(src, pos,
      H(OFF_QKH), H(OFF_QKL), H(OFF_SRCH), H(OFF_SRCL));
  k_split2<<<3*DM*DM/4/256, 256, 0, stream>>>(w3, H(OFF_W3H), H(OFF_W3L), 64.0f, 3*DM*DM/4);
  k_split2<<<DM*DM/4/256, 256, 0, stream>>>(wo, H(OFF_WOH), H(OFF_WOL), 64.0f, DM*DM/4);

  // QKV projection
  k_qkv<<<dim3(48, 64), 256, 0, stream>>>(
      H(OFF_QKH), H(OFF_QKL), H(OFF_SRCH), H(OFF_SRCL), H(OFF_W3H), H(OFF_W3L), b3,
      H(OFF_QH), H(OFF_QL), H(OFF_KH), H(OFF_KL), H(OFF_VH), H(OFF_VL));

  // fused flash attention (one dispatch, XCD-swizzled)
  k_attn<<<dim3(NCHUNK*NBH), 256, 0, stream>>>(
      H(OFF_QH), H(OFF_QL), H(OFF_KH), H(OFF_KL), H(OFF_VH), H(OFF_VL),
      H(OFF_OH), H(OFF_OL));

  // out projection + LN1
  k_out<<<dim3(16, 64), 256, 0, stream>>>(
      H(OFF_OH), H(OFF_OL), H(OFF_WOH), H(OFF_WOL), bo, F(OFF_ATT));
  k_ln<<<BS/4, 256, 0, stream>>>(src, F(OFF_ATT), g1, be1, F(OFF_X), H(OFF_XH), nullptr);

  // gate + expert bucketing (buckets padded to 128 rows)
  k_gate<<<BS/4, 256, 0, stream>>>(F(OFF_X), gw, gb, I(OFF_CHOSEN), I(OFF_COUNTS));
  k_offsets<<<1, 64, 0, stream>>>(I(OFF_COUNTS), I(OFF_EOFF));
  k_fill<<<(NPOS+255)/256, 256, 0, stream>>>(I(OFF_PLIST), NPOS);
  k_scatter<<<BS/256, 256, 0, stream>>>(I(OFF_CHOSEN), I(OFF_EOFF), I(OFF_CURSOR), I(OFF_PLIST));

  // MoE weights to f16 and bucketed expert FFN (128x64 core)
  k_tof16<<<NE*DFE*DM/4/256, 256, 0, stream>>>(w1, H(OFF_W1H), 64.0f, NE*DFE*DM/4);
  k_tof16<<<NE*DM*DFE/4/256, 256, 0, stream>>>(w2, H(OFF_W2H), 64.0f, NE*DM*DFE/4);
  k_e1<<<dim3(16, NPOS/128), 256, 0, stream>>>(
      H(OFF_XH), H(OFF_W1H), b1, I(OFF_PLIST), I(OFF_EOFF), H(OFF_HH));
  k_e2<<<dim3(16, NPOS/128), 256, 0, stream>>>(
      H(OFF_HH), H(OFF_W2H), b2, I(OFF_PLIST), I(OFF_EOFF), F(OFF_Y));

  // final LN2 -> output
  k_ln<<<BS/4, 256, 0, stream>>>(F(OFF_X), F(OFF_Y), g2, be2, nullptr, nullptr, out);
}

// Round 10
// 917.547 us; speedup vs baseline: 2.4330x; 1.0375x over previous
//
#include <hip/hip_runtime.h>
#include <cstdint>
#include <cstddef>

// ---------------------------------------------------------------------------
// TransformerEncoderLayer on MI355X (gfx950).
// Pre-gate GEMMs: f16 hi/lo split MFMA (3 mfma/product) — validated bit-equal
// to fp32 routing. QKV/out_proj GEMM core stages via global_load_lds width=16
// with XOR-swizzled per-lane source addresses (linear LDS, conflict-free
// ds_read_b128). Attention: fused flash kernel. Gate RNG: partitionable
// threefry, b1^b2 (VERIFIED round 5 — DO NOT TOUCH). MoE: bucketed f16 MFMA.
// ---------------------------------------------------------------------------

typedef _Float16 h16;
typedef h16 h16x8 __attribute__((ext_vector_type(8)));
typedef h16 h16x4 __attribute__((ext_vector_type(4)));
typedef float f32x4 __attribute__((ext_vector_type(4)));
typedef uint32_t u32;

#define DM 1024
#define NH 16
#define HD 64
#define SEQ 1024
#define BB 8
#define BS (BB*SEQ)      /* 8192 tokens */
#define NBH (BB*NH)      /* 128 (b,h) pairs */
#define NE 4
#define DFE 1024
#define QB 64            /* query rows per attention chunk */
#define NCHUNK (SEQ/QB)  /* 16 */
#define LDK 40           /* LDS stride (h16) for MoE core slabs */
#define SLDA 32          /* linear LDS stride (h16) for gload_lds slabs */
#define FLD 72           /* LDS stride for 64-wide flash tiles (64+8 pad) */
#define NPOS (68*128)    /* 8704: bucket capacity, 128-padded per expert */

#define MFMA16(a,b,c) __builtin_amdgcn_mfma_f32_16x16x32_f16(a,b,c,0,0,0)

// ---- workspace layout (bytes). E = one h16 plane of [8192][1024]. ----
static constexpr size_t E = (size_t)BS*DM*2;            // 16,777,216
static constexpr size_t OFF_QKH = 0;                    // qk split (dead after qkv)
static constexpr size_t OFF_QKL = E;
static constexpr size_t OFF_SRCH= 2*E;
static constexpr size_t OFF_SRCL= 3*E;
static constexpr size_t OFF_W3H = 4*E;
static constexpr size_t OFF_W3L = 4*E + (size_t)3*DM*DM*2;
static constexpr size_t OFF_WOH = 4*E + (size_t)6*DM*DM*2;
static constexpr size_t OFF_WOL = 4*E + (size_t)7*DM*DM*2;   // ends at 5E
static constexpr size_t OFF_QH  = 5*E;                  // Q,K [bh][s][d]; V^T [bh][d][s]
static constexpr size_t OFF_QL  = 6*E;
static constexpr size_t OFF_KH  = 7*E;
static constexpr size_t OFF_KL  = 8*E;
static constexpr size_t OFF_VH  = 9*E;
static constexpr size_t OFF_VL  = 10*E;
static constexpr size_t OFF_OH  = 0;                    // after flash (qk dead)
static constexpr size_t OFF_OL  = E;
static constexpr size_t OFF_ATT = 2*E;                  // fp32 (src splits dead)
static constexpr size_t OFF_X   = 5*E;                  // fp32 2E (Q,Ql dead)
static constexpr size_t OFF_XH  = 7*E;                  // f16 x*16 (Kh dead)
static constexpr size_t OFF_W1H = 8*E;                  // f16 (Kl dead)
static constexpr size_t OFF_W2H = 8*E + (size_t)NE*DFE*DM*2;  // ends at 9E
static constexpr size_t OFF_HH  = 9*E;                  // bucket h f16 [NPOS][1024] (V dead)
static constexpr size_t OFF_Y   = 11*E;                 // fp32 2E
static constexpr size_t OFF_CHOSEN = 13*E;
static constexpr size_t OFF_COUNTS = 13*E + 32768;
static constexpr size_t OFF_CURSOR = OFF_COUNTS + 16;
static constexpr size_t OFF_EOFF   = OFF_CURSOR + 16;
static constexpr size_t OFF_PLIST  = OFF_EOFF + 16;
static constexpr size_t WS_NEEDED  = OFF_PLIST + (size_t)NPOS*4;

// ---------------------------------------------------------------------------
__device__ __forceinline__ void store_split(h16* H, h16* L, size_t idx, float v) {
  h16 h = (h16)v;
  H[idx] = h;
  L[idx] = (h16)((v - (float)h) * 4096.0f);
}

__device__ __forceinline__ float wave_sum(float v) {
  #pragma unroll
  for (int o = 32; o; o >>= 1) v += __shfl_xor(v, o);
  return v;
}

// async global->LDS, 16B per lane; LDS dest = uniform base + lane*16
__device__ __forceinline__ void gload16(const void* g, void* l) {
  __builtin_amdgcn_global_load_lds(
      (const __attribute__((address_space(1))) u32*)g,
      (__attribute__((address_space(3))) u32*)l, 16, 0, 0);
}

// ---------------------------------------------------------------------------
// 128(M)x64(N) split-f16 MFMA core, global_load_lds staging.
// Linear LDS slabs sA*[128][32], sB*[64][32] h16 (64B rows). One gload16
// covers 16 rows x 64B: lane L -> row L>>2, 16B-group L&3. To avoid the
// 8-way read conflict of 64B-stride rows, the 16B group is XOR-swizzled by
// ((local_row>>1)&3) in the per-lane GLOBAL source address; ds_read applies
// the same XOR -> lanes of one b128 read cover all 8 slot classes x2 (2-way
// aliasing = free). 4 waves, each 64x32 out (4x2 frags), 24 MFMA : 12 reads.
// ---------------------------------------------------------------------------
__device__ __forceinline__ void gemm128x64_core(
    const h16* __restrict__ Ah, const h16* __restrict__ Al,
    const h16* __restrict__ Bh, const h16* __restrict__ Bl,
    int K, int lda, int ldb, int m0, int n0,
    f32x4 (&a1)[4][2], f32x4 (&a2)[4][2], h16* lds)
{
  const int tid = threadIdx.x, lane = tid & 63, wid = tid >> 6;
  const int wr = (wid >> 1) * 64, wc = (wid & 1) * 32;
  h16* sAh = lds;                      // [128][32]
  h16* sAl = lds + 128*SLDA;
  h16* sBh = lds + 2*128*SLDA;         // [64][32]
  h16* sBl = lds + 2*128*SLDA + 64*SLDA;
  // staging addresses (per-lane global, uniform LDS base per wave)
  const int lr16 = lane >> 2, lgrp = lane & 3;
  const int rA0 = wid*32 + lr16;                  // local A row (t=0); t=1 adds 16
  const int rB  = wid*16 + lr16;                  // local B row
  const int swA = (rA0 >> 1) & 3;                 // period-8 in row -> same for t=1
  const int swB = (rB  >> 1) & 3;
  const long gA0 = (long)(m0 + rA0)      * lda + ((lgrp ^ swA) << 3);
  const long gA1 = (long)(m0 + rA0 + 16) * lda + ((lgrp ^ swA) << 3);
  const long gB  = (long)(n0 + rB)       * ldb + ((lgrp ^ swB) << 3);
  h16* lA0h = sAh + (wid*32)*SLDA;      h16* lA0l = sAl + (wid*32)*SLDA;
  h16* lA1h = sAh + (wid*32+16)*SLDA;   h16* lA1l = sAl + (wid*32+16)*SLDA;
  h16* lBh  = sBh + (wid*16)*SLDA;      h16* lBl  = sBl + (wid*16)*SLDA;
  // read addressing: logical k-group gi, swizzled col = (gi ^ ((row>>1)&3))<<3;
  // row = (mult of 16) + fr  =>  (row>>1)&3 == (lane>>1)&3
  const int fr = lane & 15, gi = lane >> 4;
  const int pcol = ((gi ^ ((lane >> 1) & 3)) << 3);
  for (int k0 = 0; k0 < K; k0 += 32) {
    __syncthreads();                      // readers of prev tile done
    gload16(Ah + gA0 + k0, lA0h);
    gload16(Ah + gA1 + k0, lA1h);
    gload16(Al + gA0 + k0, lA0l);
    gload16(Al + gA1 + k0, lA1l);
    gload16(Bh + gB  + k0, lBh);
    gload16(Bl + gB  + k0, lBl);
    __syncthreads();                      // vmcnt(0) drain -> tile ready
    h16x8 ah[4], al[4], bh[2], bl[2];
    #pragma unroll
    for (int i = 0; i < 4; ++i) {
      ah[i] = *(const h16x8*)(sAh + (wr + i*16 + fr)*SLDA + pcol);
      al[i] = *(const h16x8*)(sAl + (wr + i*16 + fr)*SLDA + pcol);
    }
    #pragma unroll
    for (int j = 0; j < 2; ++j) {
      bh[j] = *(const h16x8*)(sBh + (wc + j*16 + fr)*SLDA + pcol);
      bl[j] = *(const h16x8*)(sBl + (wc + j*16 + fr)*SLDA + pcol);
    }
    #pragma unroll
    for (int i = 0; i < 4; ++i)
      #pragma unroll
      for (int j = 0; j < 2; ++j) {
        a1[i][j] = MFMA16(ah[i], bh[j], a1[i][j]);
        a2[i][j] = MFMA16(ah[i], bl[j], a2[i][j]);
        a2[i][j] = MFMA16(al[i], bh[j], a2[i][j]);
      }
  }
}

#define EPI_W \
  const int lane = threadIdx.x & 63, wid = threadIdx.x >> 6; \
  const int wr = (wid>>1)*64, wc = (wid&1)*32; \
  const int fr = lane & 15, rb = (lane>>4)*4;

// ---------------------------------------------------------------------------
// 128(M)x64(N) f16 single MFMA core for MoE (unchanged, validated).
// ---------------------------------------------------------------------------
template<bool GATHER>
__device__ __forceinline__ void hgemm128_core(
    const h16* __restrict__ A, const h16* __restrict__ B,
    int K, int lda, int ldb, int m0, int n0, const int* __restrict__ rowmap,
    f32x4 (&acc)[4][2], h16* lds)
{
  const int tid = threadIdx.x, lane = tid & 63, wid = tid >> 6;
  const int wr = (wid >> 1) * 64, wc = (wid & 1) * 32;
  h16* sA = lds;              // [128][LDK]
  h16* sB = lds + 128*LDK;    // [64][LDK]
  const int arow = tid >> 1, akc = (tid & 1) * 16;
  const int brow = tid >> 2, bkc = (tid & 3) * 8;
  long abase; bool aval = true;
  if (GATHER) { int t = rowmap[m0 + arow]; aval = (t >= 0);
                abase = (long)(aval ? t : 0) * lda + akc; }
  else          abase = (long)(m0 + arow) * lda + akc;
  const long bbase = (long)(n0 + brow) * ldb + bkc;
  const int fr = lane & 15, kg = (lane >> 4) << 3;
  for (int k0 = 0; k0 < K; k0 += 32) {
    __syncthreads();
    uint4 va0 = (!GATHER || aval) ? *(const uint4*)(A + abase + k0)     : make_uint4(0,0,0,0);
    uint4 va1 = (!GATHER || aval) ? *(const uint4*)(A + abase + k0 + 8) : make_uint4(0,0,0,0);
    *(uint4*)(sA + arow*LDK + akc)     = va0;
    *(uint4*)(sA + arow*LDK + akc + 8) = va1;
    *(uint4*)(sB + brow*LDK + bkc)     = *(const uint4*)(B + bbase + k0);
    __syncthreads();
    h16x8 a_[4], b_[2];
    #pragma unroll
    for (int i = 0; i < 4; ++i)
      a_[i] = *(const h16x8*)(sA + (wr + i*16 + fr)*LDK + kg);
    #pragma unroll
    for (int j = 0; j < 2; ++j)
      b_[j] = *(const h16x8*)(sB + (wc + j*16 + fr)*LDK + kg);
    #pragma unroll
    for (int i = 0; i < 4; ++i)
      #pragma unroll
      for (int j = 0; j < 2; ++j)
        acc[i][j] = MFMA16(a_[i], b_[j], acc[i][j]);
  }
}

// ---------------------------------------------------------------------------
// prep kernels
// ---------------------------------------------------------------------------
__global__ void k_zero8(int* __restrict__ p) {
  if (threadIdx.x < 8) p[threadIdx.x] = 0;   // counts[4] + cursor[4]
}

__global__ void k_split_in(const float* __restrict__ src, const float* __restrict__ pos,
                           h16* __restrict__ qkH, h16* __restrict__ qkL,
                           h16* __restrict__ sH,  h16* __restrict__ sL) {
  int i = blockIdx.x*256 + threadIdx.x;
  float4 s = ((const float4*)src)[i];
  float4 p = ((const float4*)pos)[i];
  float sv[4] = {s.x, s.y, s.z, s.w};
  float qv[4] = {s.x+p.x, s.y+p.y, s.z+p.z, s.w+p.w};
  h16x4 sh, sl, qh, ql;
  #pragma unroll
  for (int q = 0; q < 4; ++q) {
    float xs = sv[q] * 16.0f; h16 hs = (h16)xs;
    sh[q] = hs; sl[q] = (h16)((xs - (float)hs) * 4096.0f);
    float xq = qv[q] * 16.0f; h16 hq = (h16)xq;
    qh[q] = hq; ql[q] = (h16)((xq - (float)hq) * 4096.0f);
  }
  ((h16x4*)sH)[i] = sh; ((h16x4*)sL)[i] = sl;
  ((h16x4*)qkH)[i] = qh; ((h16x4*)qkL)[i] = ql;
}

__global__ void k_split2(const float* __restrict__ a,
                         h16* __restrict__ H, h16* __restrict__ L, float scale, int n4) {
  int i = blockIdx.x*256 + threadIdx.x;
  if (i >= n4) return;
  float4 v = ((const float4*)a)[i];
  float vv[4] = {v.x, v.y, v.z, v.w};
  h16x4 hv, lv;
  #pragma unroll
  for (int q = 0; q < 4; ++q) {
    float x = vv[q] * scale;
    h16 h = (h16)x;
    hv[q] = h;
    lv[q] = (h16)((x - (float)h) * 4096.0f);
  }
  ((h16x4*)H)[i] = hv;
  ((h16x4*)L)[i] = lv;
}

__global__ void k_tof16(const float* __restrict__ a, h16* __restrict__ H, float scale, int n4) {
  int i = blockIdx.x*256 + threadIdx.x;
  if (i >= n4) return;
  float4 v = ((const float4*)a)[i];
  h16x4 hv;
  hv[0] = (h16)(v.x*scale); hv[1] = (h16)(v.y*scale);
  hv[2] = (h16)(v.z*scale); hv[3] = (h16)(v.w*scale);
  ((h16x4*)H)[i] = hv;
}

// ---------------------------------------------------------------------------
// QKV projection (128x64 split MFMA tiles, gload_lds staging)
// ---------------------------------------------------------------------------
__global__ __launch_bounds__(256) void k_qkv(
    const h16* __restrict__ qkh, const h16* __restrict__ qkl,
    const h16* __restrict__ sh,  const h16* __restrict__ sl,
    const h16* __restrict__ Wh,  const h16* __restrict__ Wl, const float* __restrict__ bias,
    h16* __restrict__ Qh, h16* __restrict__ Ql, h16* __restrict__ Kh, h16* __restrict__ Kl,
    h16* __restrict__ Vh, h16* __restrict__ Vl)
{
  __shared__ h16 lds[(2*128 + 2*64)*SLDA];
  const int n0 = blockIdx.x*64, m0 = blockIdx.y*128;
  const bool isV = (n0 >= 2048);
  f32x4 a1[4][2] = {}; f32x4 a2[4][2] = {};
  gemm128x64_core(isV ? sh : qkh, isV ? sl : qkl, Wh, Wl,
                  1024, 1024, 1024, m0, n0, a1, a2, lds);
  EPI_W;
  #pragma unroll
  for (int i = 0; i < 4; ++i)
    #pragma unroll
    for (int j = 0; j < 2; ++j)
      #pragma unroll
      for (int r = 0; r < 4; ++r) {
        int row = m0 + wr + i*16 + rb + r;
        int col = n0 + wc + j*16 + fr;
        float c = (a1[i][j][r] + a2[i][j][r]*(1.0f/4096.0f)) * (1.0f/1024.0f) + bias[col];
        int b = row >> 10, s = row & 1023;
        int cc = col & 1023, h = cc >> 6, d = cc & 63;
        long bh = (long)b*NH + h;
        float cs = c * 16.0f;
        if (col < 1024)      store_split(Qh, Ql, (bh*SEQ + s)*HD + d, cs);
        else if (col < 2048) store_split(Kh, Kl, (bh*SEQ + s)*HD + d, cs);
        else                 store_split(Vh, Vl, (bh*HD + d)*SEQ + s, cs);
      }
}

// ---------------------------------------------------------------------------
// Fused flash attention (unchanged from round 8/9, XCD swizzle kept).
// ---------------------------------------------------------------------------
__global__ __launch_bounds__(256) void k_attn(
    const h16* __restrict__ Qh, const h16* __restrict__ Ql,
    const h16* __restrict__ Kh, const h16* __restrict__ Kl,
    const h16* __restrict__ Vh, const h16* __restrict__ Vl,
    h16* __restrict__ Oh, h16* __restrict__ Ol)
{
  __shared__ h16 lds[6*64*FLD];   // 55,296 B
  h16* sKh = lds;            h16* sKl = lds + 64*FLD;
  h16* sVh = lds + 2*64*FLD; h16* sVl = lds + 3*64*FLD;
  h16* sPh = lds + 4*64*FLD; h16* sPl = lds + 5*64*FLD;
  const int bid = blockIdx.x;                  // 0..2047
  const int swz = (bid & 7) * 256 + (bid >> 3);   // bijective (2048 = 8*256)
  const int bh = swz >> 4;
  const int q0 = (swz & 15) * QB;
  const int tid = threadIdx.x, lane = tid & 63, w = tid >> 6;
  const int fr = lane & 15, hg = lane >> 4;   // 0..3
  const int kg = hg << 3;
  const long qbase = ((long)bh*SEQ + q0 + w*16 + fr) * HD;
  h16x8 qh[2], ql[2];
  qh[0] = *(const h16x8*)(Qh + qbase + kg);
  qh[1] = *(const h16x8*)(Qh + qbase + 32 + kg);
  ql[0] = *(const h16x8*)(Ql + qbase + kg);
  ql[1] = *(const h16x8*)(Ql + qbase + 32 + kg);
  f32x4 o1[4] = {}, o2[4] = {};
  float mrow[4] = {-3.0e38f, -3.0e38f, -3.0e38f, -3.0e38f};
  float lrow[4] = {0.f, 0.f, 0.f, 0.f};
  const int srow = tid >> 2, skc = (tid & 3) << 4;
  const long kbase = ((long)bh*SEQ + srow) * HD + skc;
  const long vbase = ((long)bh*HD + srow) * SEQ + skc;
  for (int kt = 0; kt < NCHUNK; ++kt) {
    const int n0 = kt * QB;
    __syncthreads();
    {
      const long ka = kbase + (long)n0*HD;
      *(uint4*)(sKh + srow*FLD + skc)     = *(const uint4*)(Kh + ka);
      *(uint4*)(sKh + srow*FLD + skc + 8) = *(const uint4*)(Kh + ka + 8);
      *(uint4*)(sKl + srow*FLD + skc)     = *(const uint4*)(Kl + ka);
      *(uint4*)(sKl + srow*FLD + skc + 8) = *(const uint4*)(Kl + ka + 8);
      const long va = vbase + n0;
      *(uint4*)(sVh + srow*FLD + skc)     = *(const uint4*)(Vh + va);
      *(uint4*)(sVh + srow*FLD + skc + 8) = *(const uint4*)(Vh + va + 8);
      *(uint4*)(sVl + srow*FLD + skc)     = *(const uint4*)(Vl + va);
      *(uint4*)(sVl + srow*FLD + skc + 8) = *(const uint4*)(Vl + va + 8);
    }
    __syncthreads();
    f32x4 s1[4] = {}, s2[4] = {};
    #pragma unroll
    for (int ks = 0; ks < 2; ++ks)
      #pragma unroll
      for (int j = 0; j < 4; ++j) {
        h16x8 kh = *(const h16x8*)(sKh + (j*16 + fr)*FLD + ks*32 + kg);
        h16x8 kl = *(const h16x8*)(sKl + (j*16 + fr)*FLD + ks*32 + kg);
        s1[j] = MFMA16(qh[ks], kh, s1[j]);
        s2[j] = MFMA16(qh[ks], kl, s2[j]);
        s2[j] = MFMA16(ql[ks], kh, s2[j]);
      }
    float p[4][4];
    float tmax[4] = {-3.0e38f, -3.0e38f, -3.0e38f, -3.0e38f};
    #pragma unroll
    for (int j = 0; j < 4; ++j)
      #pragma unroll
      for (int r = 0; r < 4; ++r) {
        float sc = (s1[j][r] + s2[j][r]*(1.0f/4096.0f)) * (0.125f/256.0f);
        p[j][r] = sc;
        tmax[r] = fmaxf(tmax[r], sc);
      }
    #pragma unroll
    for (int o = 1; o < 16; o <<= 1)
      #pragma unroll
      for (int r = 0; r < 4; ++r) tmax[r] = fmaxf(tmax[r], __shfl_xor(tmax[r], o));
    float scl[4], psum[4];
    #pragma unroll
    for (int r = 0; r < 4; ++r) {
      float mn = fmaxf(mrow[r], tmax[r]);
      scl[r] = expf(mrow[r] - mn);
      mrow[r] = mn;
      psum[r] = 0.f;
      #pragma unroll
      for (int j = 0; j < 4; ++j) { p[j][r] = expf(p[j][r] - mn); psum[r] += p[j][r]; }
    }
    #pragma unroll
    for (int o = 1; o < 16; o <<= 1)
      #pragma unroll
      for (int r = 0; r < 4; ++r) psum[r] += __shfl_xor(psum[r], o);
    #pragma unroll
    for (int r = 0; r < 4; ++r) lrow[r] = lrow[r]*scl[r] + psum[r];
    #pragma unroll
    for (int j = 0; j < 4; ++j)
      #pragma unroll
      for (int r = 0; r < 4; ++r) { o1[j][r] *= scl[r]; o2[j][r] *= scl[r]; }
    #pragma unroll
    for (int j = 0; j < 4; ++j)
      #pragma unroll
      for (int r = 0; r < 4; ++r) {
        float pv = p[j][r] * 512.0f;
        h16 ph = (h16)pv;
        h16 pl = (h16)((pv - (float)ph) * 4096.0f);
        int off = (w*16 + hg*4 + r)*FLD + j*16 + fr;
        sPh[off] = ph;
        sPl[off] = pl;
      }
    __syncthreads();
    #pragma unroll
    for (int ks = 0; ks < 2; ++ks) {
      h16x8 pa = *(const h16x8*)(sPh + (w*16 + fr)*FLD + ks*32 + kg);
      h16x8 pb = *(const h16x8*)(sPl + (w*16 + fr)*FLD + ks*32 + kg);
      #pragma unroll
      for (int jd = 0; jd < 4; ++jd) {
        h16x8 vh = *(const h16x8*)(sVh + (jd*16 + fr)*FLD + ks*32 + kg);
        h16x8 vl = *(const h16x8*)(sVl + (jd*16 + fr)*FLD + ks*32 + kg);
        o1[jd] = MFMA16(pa, vh, o1[jd]);
        o2[jd] = MFMA16(pa, vl, o2[jd]);
        o2[jd] = MFMA16(pb, vh, o2[jd]);
      }
    }
  }
  const int b = bh >> 4, h = bh & 15;
  #pragma unroll
  for (int jd = 0; jd < 4; ++jd)
    #pragma unroll
    for (int r = 0; r < 4; ++r) {
      int qrow = q0 + w*16 + hg*4 + r;
      int d = jd*16 + fr;
      float ov = (o1[jd][r] + o2[jd][r]*(1.0f/4096.0f)) / (512.0f*16.0f*lrow[r]);
      store_split(Oh, Ol, ((long)b*SEQ + qrow)*DM + h*HD + d, ov*16.0f);
    }
}

// out_proj (128x64 split, gload_lds staging): attn = O.Wo^T + bo, fp32
__global__ __launch_bounds__(256) void k_out(
    const h16* __restrict__ Oh, const h16* __restrict__ Ol,
    const h16* __restrict__ Wh, const h16* __restrict__ Wl,
    const float* __restrict__ bias, float* __restrict__ attn)
{
  __shared__ h16 lds[(2*128 + 2*64)*SLDA];
  const int n0 = blockIdx.x*64, m0 = blockIdx.y*128;
  f32x4 a1[4][2] = {}; f32x4 a2[4][2] = {};
  gemm128x64_core(Oh, Ol, Wh, Wl, 1024, 1024, 1024, m0, n0, a1, a2, lds);
  EPI_W;
  #pragma unroll
  for (int i = 0; i < 4; ++i)
    #pragma unroll
    for (int j = 0; j < 2; ++j)
      #pragma unroll
      for (int r = 0; r < 4; ++r) {
        int row = m0 + wr + i*16 + rb + r;
        int col = n0 + wc + j*16 + fr;
        attn[(long)row*DM + col] =
            (a1[i][j][r] + a2[i][j][r]*(1.0f/4096.0f)) * (1.0f/1024.0f) + bias[col];
      }
}

// LayerNorm of (A + Badd): optional fp32 out, f16(x*16) out, direct out
__global__ __launch_bounds__(256) void k_ln(
    const float* __restrict__ A, const float* __restrict__ Badd,
    const float* __restrict__ g, const float* __restrict__ be,
    float* __restrict__ xout, h16* __restrict__ xh, float* __restrict__ dout)
{
  int wave = threadIdx.x >> 6, lane = threadIdx.x & 63;
  long row = (long)blockIdx.x*4 + wave;
  const float* ar = A + row*DM; const float* br = Badd + row*DM;
  float v[16]; float s = 0.0f;
  #pragma unroll
  for (int p = 0; p < 4; ++p) {
    int d = p*256 + lane*4;
    float4 a = *(const float4*)(ar + d);
    float4 b = *(const float4*)(br + d);
    float t0=a.x+b.x, t1=a.y+b.y, t2=a.z+b.z, t3=a.w+b.w;
    v[4*p+0]=t0; v[4*p+1]=t1; v[4*p+2]=t2; v[4*p+3]=t3;
    s += t0+t1+t2+t3;
  }
  s = wave_sum(s);
  float m = s * (1.0f/1024.0f);
  float q = 0.0f;
  #pragma unroll
  for (int i = 0; i < 16; ++i) { float dd = v[i]-m; q += dd*dd; }
  q = wave_sum(q);
  float rs = (float)(1.0 / sqrt((double)(q * (1.0f/1024.0f) + 1e-5f)));
  #pragma unroll
  for (int p = 0; p < 4; ++p) {
    int d = p*256 + lane*4;
    float4 gv = *(const float4*)(g + d);
    float4 bv = *(const float4*)(be + d);
    float y0 = (v[4*p+0]-m)*rs*gv.x + bv.x;
    float y1 = (v[4*p+1]-m)*rs*gv.y + bv.y;
    float y2 = (v[4*p+2]-m)*rs*gv.z + bv.z;
    float y3 = (v[4*p+3]-m)*rs*gv.w + bv.w;
    if (xout) { float4 o = {y0,y1,y2,y3}; *(float4*)(xout + row*DM + d) = o; }
    if (xh) {
      h16x4 hv; hv[0]=(h16)(y0*16.f); hv[1]=(h16)(y1*16.f);
      hv[2]=(h16)(y2*16.f); hv[3]=(h16)(y3*16.f);
      *(h16x4*)(xh + row*DM + d) = hv;
    }
    if (dout) { float4 o = {y0,y1,y2,y3}; *(float4*)(dout + row*DM + d) = o; }
  }
}

// ---------------------------------------------------------------------------
// threefry2x32 (key=[0,42]) -> gumbel -> argmax. VERIFIED round 5 — DO NOT TOUCH.
// partitionable bits = b1 ^ b2, counter = (0, i).
// ---------------------------------------------------------------------------
__device__ __forceinline__ void threefry(u32 x0, u32 x1, u32& y0, u32& y1) {
  const u32 ks0 = 0u, ks1 = 42u, ks2 = 0x1BD11BDAu ^ 42u;
  x0 += ks0; x1 += ks1;
  #define TF_R(r) { x0 += x1; x1 = (x1 << r) | (x1 >> (32 - r)); x1 ^= x0; }
  TF_R(13) TF_R(15) TF_R(26) TF_R(6)  x0 += ks1; x1 += ks2 + 1u;
  TF_R(17) TF_R(29) TF_R(16) TF_R(24) x0 += ks2; x1 += ks0 + 2u;
  TF_R(13) TF_R(15) TF_R(26) TF_R(6)  x0 += ks0; x1 += ks1 + 3u;
  TF_R(17) TF_R(29) TF_R(16) TF_R(24) x0 += ks1; x1 += ks2 + 4u;
  TF_R(13) TF_R(15) TF_R(26) TF_R(6)  x0 += ks2; x1 += ks0 + 5u;
  #undef TF_R
  y0 = x0; y1 = x1;
}

__device__ __forceinline__ float gumbel_from(u32 bits) {
  float f = __uint_as_float((bits >> 9) | 0x3F800000u) - 1.0f;
  float u = (f > 0.0f) ? f : 1.17549435e-38f;
  float nl = (float)(-log((double)u));
  return -(float)log((double)nl);
}

__global__ __launch_bounds__(256) void k_gate(
    const float* __restrict__ x, const float* __restrict__ gw,
    const float* __restrict__ gb, int* __restrict__ chosen, int* __restrict__ counts)
{
  int wave = threadIdx.x >> 6, lane = threadIdx.x & 63;
  long t = (long)blockIdx.x*4 + wave;
  const float* xr = x + t*DM;
  float p[4] = {0.f,0.f,0.f,0.f};
  #pragma unroll
  for (int pp = 0; pp < 4; ++pp) {
    int d = pp*256 + lane*4;
    float4 xv = *(const float4*)(xr + d);
    #pragma unroll
    for (int e = 0; e < 4; ++e) {
      float4 gv = *(const float4*)(gw + e*DM + d);
      p[e] += xv.x*gv.x + xv.y*gv.y + xv.z*gv.z + xv.w*gv.w;
    }
  }
  #pragma unroll
  for (int e = 0; e < 4; ++e) p[e] = wave_sum(p[e]);
  if (lane == 0) {
    float best = -3.0e38f; int arg = 0;
    #pragma unroll
    for (int e = 0; e < 4; ++e) {
      float logit = p[e] + gb[e];
      u32 j = (u32)(4*t + e);
      u32 y0, y1;
      threefry(0u, j, y0, y1);
      float v = gumbel_from(y0 ^ y1) + logit;
      if (v > best) { best = v; arg = e; }
    }
    chosen[(int)t] = arg;
    atomicAdd(&counts[arg], 1);
  }
}

__global__ void k_offsets(const int* __restrict__ counts, int* __restrict__ eoff) {
  if (threadIdx.x == 0 && blockIdx.x == 0) {
    int o = 0;
    for (int e = 0; e < 4; ++e) { eoff[e] = o; o += (counts[e] + 127) & ~127; }
  }
}

__global__ void k_fill(int* __restrict__ p, int n) {
  int i = blockIdx.x*256 + threadIdx.x;
  if (i < n) p[i] = -1;
}

__global__ void k_scatter(const int* __restrict__ chosen, const int* __restrict__ eoff,
                          int* __restrict__ cursor, int* __restrict__ plist) {
  int t = blockIdx.x*256 + threadIdx.x;
  if (t >= BS) return;
  int e = chosen[t];
  int slot = atomicAdd(&cursor[e], 1);
  plist[eoff[e] + slot] = t;
}

// MoE layer 1 (gathered rows, 128x64 core): h = relu(x.w1[e]^T + b1[e])
__global__ __launch_bounds__(256) void k_e1(
    const h16* __restrict__ Xh, const h16* __restrict__ W1, const float* __restrict__ b1,
    const int* __restrict__ plist, const int* __restrict__ eoff, h16* __restrict__ Hh)
{
  __shared__ h16 lds[(128 + 64)*LDK];
  const int n0 = blockIdx.x*64, m0 = blockIdx.y*128;
  const int e = (m0 >= eoff[1]) + (m0 >= eoff[2]) + (m0 >= eoff[3]);
  f32x4 acc[4][2] = {};
  hgemm128_core<true>(Xh, W1 + (long)e*DFE*DM, 1024, 1024, 1024, m0, n0, plist, acc, lds);
  EPI_W;
  #pragma unroll
  for (int i = 0; i < 4; ++i)
    #pragma unroll
    for (int j = 0; j < 2; ++j)
      #pragma unroll
      for (int r = 0; r < 4; ++r) {
        int row = m0 + wr + i*16 + rb + r;
        int col = n0 + wc + j*16 + fr;
        float c = acc[i][j][r] * (1.0f/1024.0f) + b1[e*DFE + col];
        c = fmaxf(c, 0.0f);
        Hh[(long)row*DFE + col] = (h16)(c * 16.0f);
      }
}

// MoE layer 2 (bucket rows, 128x64 core, scatter out): y[t] = h.w2[e]^T + b2[e]
__global__ __launch_bounds__(256) void k_e2(
    const h16* __restrict__ Hh, const h16* __restrict__ W2, const float* __restrict__ b2,
    const int* __restrict__ plist, const int* __restrict__ eoff, float* __restrict__ y)
{
  __shared__ h16 lds[(128 + 64)*LDK];
  const int n0 = blockIdx.x*64, m0 = blockIdx.y*128;
  const int e = (m0 >= eoff[1]) + (m0 >= eoff[2]) + (m0 >= eoff[3]);
  f32x4 acc[4][2] = {};
  hgemm128_core<false>(Hh, W2 + (long)e*DM*DFE, 1024, DFE, DFE, m0, n0, nullptr, acc, lds);
  EPI_W;
  #pragma unroll
  for (int i = 0; i < 4; ++i)
    #pragma unroll
    for (int j = 0; j < 2; ++j)
      #pragma unroll
      for (int r = 0; r < 4; ++r) {
        int row = m0 + wr + i*16 + rb + r;
        int col = n0 + wc + j*16 + fr;
        int t = plist[row];
        if (t >= 0)
          y[(long)t*DM + col] = acc[i][j][r] * (1.0f/1024.0f) + b2[e*DM + col];
      }
}

// ---------------------------------------------------------------------------
extern "C" void kernel_launch(void* const* d_in, const int* in_sizes, int n_in,
                              void* d_out, int out_size, void* d_ws, size_t ws_size,
                              hipStream_t stream) {
  const float* src = (const float*)d_in[0];
  const float* pos = (const float*)d_in[1];
  const float* w3  = (const float*)d_in[2];
  const float* b3  = (const float*)d_in[3];
  const float* wo  = (const float*)d_in[4];
  const float* bo  = (const float*)d_in[5];
  const float* gw  = (const float*)d_in[6];
  const float* gb  = (const float*)d_in[7];
  const float* w1  = (const float*)d_in[8];
  const float* b1  = (const float*)d_in[9];
  const float* w2  = (const float*)d_in[10];
  const float* b2  = (const float*)d_in[11];
  const float* g1  = (const float*)d_in[12];
  const float* be1 = (const float*)d_in[13];
  const float* g2  = (const float*)d_in[14];
  const float* be2 = (const float*)d_in[15];
  float* out = (float*)d_out;
  char* ws = (char*)d_ws;
  if (ws_size < WS_NEEDED) return;

  auto H = [&](size_t off) { return (h16*)(ws + off); };
  auto F = [&](size_t off) { return (float*)(ws + off); };
  auto I = [&](size_t off) { return (int*)(ws + off); };

  // zero atomic counters (counts[4] + cursor[4] contiguous)
  k_zero8<<<1, 64, 0, stream>>>(I(OFF_COUNTS));

  // input + weight splits
  k_split_in<<<BS*DM/4/256, 256, 0, stream>>>(src, pos,
      H(OFF_QKH), H(OFF_QKL), H(OFF_SRCH), H(OFF_SRCL));
  k_split2<<<3*DM*DM/4/256, 256, 0, stream>>>(w3, H(OFF_W3H), H(OFF_W3L), 64.0f, 3*DM*DM/4);
  k_split2<<<DM*DM/4/256, 256, 0, stream>>>(wo, H(OFF_WOH), H(OFF_WOL), 64.0f, DM*DM/4);

  // QKV projection
  k_qkv<<<dim3(48, 64), 256, 0, stream>>>(
      H(OFF_QKH), H(OFF_QKL), H(OFF_SRCH), H(OFF_SRCL), H(OFF_W3H), H(OFF_W3L), b3,
      H(OFF_QH), H(OFF_QL), H(OFF_KH), H(OFF_KL), H(OFF_VH), H(OFF_VL));

  // fused flash attention (one dispatch, XCD-swizzled)
  k_attn<<<dim3(NCHUNK*NBH), 256, 0, stream>>>(
      H(OFF_QH), H(OFF_QL), H(OFF_KH), H(OFF_KL), H(OFF_VH), H(OFF_VL),
      H(OFF_OH), H(OFF_OL));

  // out projection + LN1
  k_out<<<dim3(16, 64), 256, 0, stream>>>(
      H(OFF_OH), H(OFF_OL), H(OFF_WOH), H(OFF_WOL), bo, F(OFF_ATT));
  k_ln<<<BS/4, 256, 0, stream>>>(src, F(OFF_ATT), g1, be1, F(OFF_X), H(OFF_XH), nullptr);

  // gate + expert bucketing (buckets padded to 128 rows)
  k_gate<<<BS/4, 256, 0, stream>>>(F(OFF_X), gw, gb, I(OFF_CHOSEN), I(OFF_COUNTS));
  k_offsets<<<1, 64, 0, stream>>>(I(OFF_COUNTS), I(OFF_EOFF));
  k_fill<<<(NPOS+255)/256, 256, 0, stream>>>(I(OFF_PLIST), NPOS);
  k_scatter<<<BS/256, 256, 0, stream>>>(I(OFF_CHOSEN), I(OFF_EOFF), I(OFF_CURSOR), I(OFF_PLIST));

  // MoE weights to f16 and bucketed expert FFN (128x64 core)
  k_tof16<<<NE*DFE*DM/4/256, 256, 0, stream>>>(w1, H(OFF_W1H), 64.0f, NE*DFE*DM/4);
  k_tof16<<<NE*DM*DFE/4/256, 256, 0, stream>>>(w2, H(OFF_W2H), 64.0f, NE*DM*DFE/4);
  k_e1<<<dim3(16, NPOS/128), 256, 0, stream>>>(
      H(OFF_XH), H(OFF_W1H), b1, I(OFF_PLIST), I(OFF_EOFF), H(OFF_HH));
  k_e2<<<dim3(16, NPOS/128), 256, 0, stream>>>(
      H(OFF_HH), H(OFF_W2H), b2, I(OFF_PLIST), I(OFF_EOFF), F(OFF_Y));

  // final LN2 -> output
  k_ln<<<BS/4, 256, 0, stream>>>(F(OFF_X), F(OFF_Y), g2, be2, nullptr, nullptr, out);
}

// Round 12
// 851.374 us; speedup vs baseline: 2.6221x; 1.0777x over previous
//
#include <hip/hip_runtime.h>
#include <cstdint>
#include <cstddef>

// ---------------------------------------------------------------------------
// TransformerEncoderLayer on MI355X (gfx950).
// Pre-gate GEMMs: f16 hi/lo split MFMA (3 mfma/product) — validated bit-equal
// to fp32 routing. QKV/out_proj: global_load_lds staging + XOR-swizzled source.
// Attention: fused flash kernel with SWAPPED QK^T (S^T = mfma(K,Q)) so softmax
// is lane-local (2 shfl instead of 32) and P goes register->register to PV via
// cvt_pkrtz + 32 shfl pulls (no LDS round-trip, no extra barrier).
// Gate RNG: partitionable threefry, b1^b2 (VERIFIED round 5 — DO NOT TOUCH).
// MoE: bucketed per-expert f16 MFMA (128x64 core).
// ---------------------------------------------------------------------------

typedef _Float16 h16;
typedef h16 h16x8 __attribute__((ext_vector_type(8)));
typedef h16 h16x4 __attribute__((ext_vector_type(4)));
typedef __fp16 fp16x2 __attribute__((ext_vector_type(2)));   // cvt_pkrtz native type
typedef float f32x4 __attribute__((ext_vector_type(4)));
typedef uint32_t u32;

#define DM 1024
#define NH 16
#define HD 64
#define SEQ 1024
#define BB 8
#define BS (BB*SEQ)      /* 8192 tokens */
#define NBH (BB*NH)      /* 128 (b,h) pairs */
#define NE 4
#define DFE 1024
#define QB 64            /* query rows per attention chunk */
#define NCHUNK (SEQ/QB)  /* 16 */
#define LDK 40           /* LDS stride (h16) for MoE core slabs */
#define SLDA 32          /* linear LDS stride (h16) for gload_lds slabs */
#define FLD 72           /* LDS stride for 64-wide flash tiles (64+8 pad) */
#define NPOS (68*128)    /* 8704: bucket capacity, 128-padded per expert */

#define MFMA16(a,b,c) __builtin_amdgcn_mfma_f32_16x16x32_f16(a,b,c,0,0,0)

// ---- workspace layout (bytes). E = one h16 plane of [8192][1024]. ----
static constexpr size_t E = (size_t)BS*DM*2;            // 16,777,216
static constexpr size_t OFF_QKH = 0;                    // qk split (dead after qkv)
static constexpr size_t OFF_QKL = E;
static constexpr size_t OFF_SRCH= 2*E;
static constexpr size_t OFF_SRCL= 3*E;
static constexpr size_t OFF_W3H = 4*E;
static constexpr size_t OFF_W3L = 4*E + (size_t)3*DM*DM*2;
static constexpr size_t OFF_WOH = 4*E + (size_t)6*DM*DM*2;
static constexpr size_t OFF_WOL = 4*E + (size_t)7*DM*DM*2;   // ends at 5E
static constexpr size_t OFF_QH  = 5*E;                  // Q,K [bh][s][d]; V^T [bh][d][s]
static constexpr size_t OFF_QL  = 6*E;
static constexpr size_t OFF_KH  = 7*E;
static constexpr size_t OFF_KL  = 8*E;
static constexpr size_t OFF_VH  = 9*E;
static constexpr size_t OFF_VL  = 10*E;
static constexpr size_t OFF_OH  = 0;                    // after flash (qk dead)
static constexpr size_t OFF_OL  = E;
static constexpr size_t OFF_ATT = 2*E;                  // fp32 (src splits dead)
static constexpr size_t OFF_X   = 5*E;                  // fp32 2E (Q,Ql dead)
static constexpr size_t OFF_XH  = 7*E;                  // f16 x*16 (Kh dead)
static constexpr size_t OFF_W1H = 8*E;                  // f16 (Kl dead)
static constexpr size_t OFF_W2H = 8*E + (size_t)NE*DFE*DM*2;  // ends at 9E
static constexpr size_t OFF_HH  = 9*E;                  // bucket h f16 [NPOS][1024] (V dead)
static constexpr size_t OFF_Y   = 11*E;                 // fp32 2E
static constexpr size_t OFF_CHOSEN = 13*E;
static constexpr size_t OFF_COUNTS = 13*E + 32768;
static constexpr size_t OFF_CURSOR = OFF_COUNTS + 16;
static constexpr size_t OFF_EOFF   = OFF_CURSOR + 16;
static constexpr size_t OFF_PLIST  = OFF_EOFF + 16;
static constexpr size_t WS_NEEDED  = OFF_PLIST + (size_t)NPOS*4;

// ---------------------------------------------------------------------------
__device__ __forceinline__ void store_split(h16* H, h16* L, size_t idx, float v) {
  h16 h = (h16)v;
  H[idx] = h;
  L[idx] = (h16)((v - (float)h) * 4096.0f);
}

__device__ __forceinline__ float wave_sum(float v) {
  #pragma unroll
  for (int o = 32; o; o >>= 1) v += __shfl_xor(v, o);
  return v;
}

// pack two floats to f16x2 (RTZ) and return the u32 word + the two f16 values
__device__ __forceinline__ u32 pk2(float a, float b, float& fa, float& fb) {
  union { fp16x2 h; u32 w; } u;
  u.h = __builtin_amdgcn_cvt_pkrtz(a, b);
  fa = (float)u.h[0];
  fb = (float)u.h[1];
  return u.w;
}
__device__ __forceinline__ u32 pk2w(float a, float b) {
  union { fp16x2 h; u32 w; } u;
  u.h = __builtin_amdgcn_cvt_pkrtz(a, b);
  return u.w;
}

// async global->LDS, 16B per lane; LDS dest = uniform base + lane*16
__device__ __forceinline__ void gload16(const void* g, void* l) {
  __builtin_amdgcn_global_load_lds(
      (const __attribute__((address_space(1))) u32*)g,
      (__attribute__((address_space(3))) u32*)l, 16, 0, 0);
}

// ---------------------------------------------------------------------------
// 128(M)x64(N) split-f16 MFMA core, global_load_lds staging (round 10, kept).
// ---------------------------------------------------------------------------
__device__ __forceinline__ void gemm128x64_core(
    const h16* __restrict__ Ah, const h16* __restrict__ Al,
    const h16* __restrict__ Bh, const h16* __restrict__ Bl,
    int K, int lda, int ldb, int m0, int n0,
    f32x4 (&a1)[4][2], f32x4 (&a2)[4][2], h16* lds)
{
  const int tid = threadIdx.x, lane = tid & 63, wid = tid >> 6;
  const int wr = (wid >> 1) * 64, wc = (wid & 1) * 32;
  h16* sAh = lds;                      // [128][32]
  h16* sAl = lds + 128*SLDA;
  h16* sBh = lds + 2*128*SLDA;         // [64][32]
  h16* sBl = lds + 2*128*SLDA + 64*SLDA;
  const int lr16 = lane >> 2, lgrp = lane & 3;
  const int rA0 = wid*32 + lr16;
  const int rB  = wid*16 + lr16;
  const int swA = (rA0 >> 1) & 3;
  const int swB = (rB  >> 1) & 3;
  const long gA0 = (long)(m0 + rA0)      * lda + ((lgrp ^ swA) << 3);
  const long gA1 = (long)(m0 + rA0 + 16) * lda + ((lgrp ^ swA) << 3);
  const long gB  = (long)(n0 + rB)       * ldb + ((lgrp ^ swB) << 3);
  h16* lA0h = sAh + (wid*32)*SLDA;      h16* lA0l = sAl + (wid*32)*SLDA;
  h16* lA1h = sAh + (wid*32+16)*SLDA;   h16* lA1l = sAl + (wid*32+16)*SLDA;
  h16* lBh  = sBh + (wid*16)*SLDA;      h16* lBl  = sBl + (wid*16)*SLDA;
  const int fr = lane & 15, gi = lane >> 4;
  const int pcol = ((gi ^ ((lane >> 1) & 3)) << 3);
  for (int k0 = 0; k0 < K; k0 += 32) {
    __syncthreads();
    gload16(Ah + gA0 + k0, lA0h);
    gload16(Ah + gA1 + k0, lA1h);
    gload16(Al + gA0 + k0, lA0l);
    gload16(Al + gA1 + k0, lA1l);
    gload16(Bh + gB  + k0, lBh);
    gload16(Bl + gB  + k0, lBl);
    __syncthreads();
    h16x8 ah[4], al[4], bh[2], bl[2];
    #pragma unroll
    for (int i = 0; i < 4; ++i) {
      ah[i] = *(const h16x8*)(sAh + (wr + i*16 + fr)*SLDA + pcol);
      al[i] = *(const h16x8*)(sAl + (wr + i*16 + fr)*SLDA + pcol);
    }
    #pragma unroll
    for (int j = 0; j < 2; ++j) {
      bh[j] = *(const h16x8*)(sBh + (wc + j*16 + fr)*SLDA + pcol);
      bl[j] = *(const h16x8*)(sBl + (wc + j*16 + fr)*SLDA + pcol);
    }
    #pragma unroll
    for (int i = 0; i < 4; ++i)
      #pragma unroll
      for (int j = 0; j < 2; ++j) {
        a1[i][j] = MFMA16(ah[i], bh[j], a1[i][j]);
        a2[i][j] = MFMA16(ah[i], bl[j], a2[i][j]);
        a2[i][j] = MFMA16(al[i], bh[j], a2[i][j]);
      }
  }
}

#define EPI_W \
  const int lane = threadIdx.x & 63, wid = threadIdx.x >> 6; \
  const int wr = (wid>>1)*64, wc = (wid&1)*32; \
  const int fr = lane & 15, rb = (lane>>4)*4;

// ---------------------------------------------------------------------------
// 128(M)x64(N) f16 single MFMA core for MoE (unchanged, validated).
// ---------------------------------------------------------------------------
template<bool GATHER>
__device__ __forceinline__ void hgemm128_core(
    const h16* __restrict__ A, const h16* __restrict__ B,
    int K, int lda, int ldb, int m0, int n0, const int* __restrict__ rowmap,
    f32x4 (&acc)[4][2], h16* lds)
{
  const int tid = threadIdx.x, lane = tid & 63, wid = tid >> 6;
  const int wr = (wid >> 1) * 64, wc = (wid & 1) * 32;
  h16* sA = lds;              // [128][LDK]
  h16* sB = lds + 128*LDK;    // [64][LDK]
  const int arow = tid >> 1, akc = (tid & 1) * 16;
  const int brow = tid >> 2, bkc = (tid & 3) * 8;
  long abase; bool aval = true;
  if (GATHER) { int t = rowmap[m0 + arow]; aval = (t >= 0);
                abase = (long)(aval ? t : 0) * lda + akc; }
  else          abase = (long)(m0 + arow) * lda + akc;
  const long bbase = (long)(n0 + brow) * ldb + bkc;
  const int fr = lane & 15, kg = (lane >> 4) << 3;
  for (int k0 = 0; k0 < K; k0 += 32) {
    __syncthreads();
    uint4 va0 = (!GATHER || aval) ? *(const uint4*)(A + abase + k0)     : make_uint4(0,0,0,0);
    uint4 va1 = (!GATHER || aval) ? *(const uint4*)(A + abase + k0 + 8) : make_uint4(0,0,0,0);
    *(uint4*)(sA + arow*LDK + akc)     = va0;
    *(uint4*)(sA + arow*LDK + akc + 8) = va1;
    *(uint4*)(sB + brow*LDK + bkc)     = *(const uint4*)(B + bbase + k0);
    __syncthreads();
    h16x8 a_[4], b_[2];
    #pragma unroll
    for (int i = 0; i < 4; ++i)
      a_[i] = *(const h16x8*)(sA + (wr + i*16 + fr)*LDK + kg);
    #pragma unroll
    for (int j = 0; j < 2; ++j)
      b_[j] = *(const h16x8*)(sB + (wc + j*16 + fr)*LDK + kg);
    #pragma unroll
    for (int i = 0; i < 4; ++i)
      #pragma unroll
      for (int j = 0; j < 2; ++j)
        acc[i][j] = MFMA16(a_[i], b_[j], acc[i][j]);
  }
}

// ---------------------------------------------------------------------------
// prep kernels
// ---------------------------------------------------------------------------
__global__ void k_zero8(int* __restrict__ p) {
  if (threadIdx.x < 8) p[threadIdx.x] = 0;   // counts[4] + cursor[4]
}

__global__ void k_split_in(const float* __restrict__ src, const float* __restrict__ pos,
                           h16* __restrict__ qkH, h16* __restrict__ qkL,
                           h16* __restrict__ sH,  h16* __restrict__ sL) {
  int i = blockIdx.x*256 + threadIdx.x;
  float4 s = ((const float4*)src)[i];
  float4 p = ((const float4*)pos)[i];
  float sv[4] = {s.x, s.y, s.z, s.w};
  float qv[4] = {s.x+p.x, s.y+p.y, s.z+p.z, s.w+p.w};
  h16x4 sh, sl, qh, ql;
  #pragma unroll
  for (int q = 0; q < 4; ++q) {
    float xs = sv[q] * 16.0f; h16 hs = (h16)xs;
    sh[q] = hs; sl[q] = (h16)((xs - (float)hs) * 4096.0f);
    float xq = qv[q] * 16.0f; h16 hq = (h16)xq;
    qh[q] = hq; ql[q] = (h16)((xq - (float)hq) * 4096.0f);
  }
  ((h16x4*)sH)[i] = sh; ((h16x4*)sL)[i] = sl;
  ((h16x4*)qkH)[i] = qh; ((h16x4*)qkL)[i] = ql;
}

__global__ void k_split2(const float* __restrict__ a,
                         h16* __restrict__ H, h16* __restrict__ L, float scale, int n4) {
  int i = blockIdx.x*256 + threadIdx.x;
  if (i >= n4) return;
  float4 v = ((const float4*)a)[i];
  float vv[4] = {v.x, v.y, v.z, v.w};
  h16x4 hv, lv;
  #pragma unroll
  for (int q = 0; q < 4; ++q) {
    float x = vv[q] * scale;
    h16 h = (h16)x;
    hv[q] = h;
    lv[q] = (h16)((x - (float)h) * 4096.0f);
  }
  ((h16x4*)H)[i] = hv;
  ((h16x4*)L)[i] = lv;
}

__global__ void k_tof16(const float* __restrict__ a, h16* __restrict__ H, float scale, int n4) {
  int i = blockIdx.x*256 + threadIdx.x;
  if (i >= n4) return;
  float4 v = ((const float4*)a)[i];
  h16x4 hv;
  hv[0] = (h16)(v.x*scale); hv[1] = (h16)(v.y*scale);
  hv[2] = (h16)(v.z*scale); hv[3] = (h16)(v.w*scale);
  ((h16x4*)H)[i] = hv;
}

// ---------------------------------------------------------------------------
// QKV projection (128x64 split MFMA tiles, gload_lds staging)
// ---------------------------------------------------------------------------
__global__ __launch_bounds__(256) void k_qkv(
    const h16* __restrict__ qkh, const h16* __restrict__ qkl,
    const h16* __restrict__ sh,  const h16* __restrict__ sl,
    const h16* __restrict__ Wh,  const h16* __restrict__ Wl, const float* __restrict__ bias,
    h16* __restrict__ Qh, h16* __restrict__ Ql, h16* __restrict__ Kh, h16* __restrict__ Kl,
    h16* __restrict__ Vh, h16* __restrict__ Vl)
{
  __shared__ h16 lds[(2*128 + 2*64)*SLDA];
  const int n0 = blockIdx.x*64, m0 = blockIdx.y*128;
  const bool isV = (n0 >= 2048);
  f32x4 a1[4][2] = {}; f32x4 a2[4][2] = {};
  gemm128x64_core(isV ? sh : qkh, isV ? sl : qkl, Wh, Wl,
                  1024, 1024, 1024, m0, n0, a1, a2, lds);
  EPI_W;
  #pragma unroll
  for (int i = 0; i < 4; ++i)
    #pragma unroll
    for (int j = 0; j < 2; ++j)
      #pragma unroll
      for (int r = 0; r < 4; ++r) {
        int row = m0 + wr + i*16 + rb + r;
        int col = n0 + wc + j*16 + fr;
        float c = (a1[i][j][r] + a2[i][j][r]*(1.0f/4096.0f)) * (1.0f/1024.0f) + bias[col];
        int b = row >> 10, s = row & 1023;
        int cc = col & 1023, h = cc >> 6, d = cc & 63;
        long bh = (long)b*NH + h;
        float cs = c * 16.0f;
        if (col < 1024)      store_split(Qh, Ql, (bh*SEQ + s)*HD + d, cs);
        else if (col < 2048) store_split(Kh, Kl, (bh*SEQ + s)*HD + d, cs);
        else                 store_split(Vh, Vl, (bh*HD + d)*SEQ + s, cs);
      }
}

// ---------------------------------------------------------------------------
// Fused flash attention, SWAPPED QK^T + in-register softmax + reg->reg P.
// S^T = mfma(A=K, B=Q): lane (fr,hg) holds S[n = 16j + 4hg + r][q = fr].
// Softmax over n is lane-local (16 vals) + 2 shfl_xor (hg groups).
// P hi/lo packed with cvt_pkrtz (residual absorbed by lo); routed to PV's
// A-fragment via 2 shfl pulls per packed reg:
//   target (ks,g) <- reg (j=2ks+(hg>>1), rp=g&1) of lane fr+16*(2(hg&1)+(g>>1)).
// PV D-layout and epilogue identical to previous (verified) version.
// ---------------------------------------------------------------------------
__global__ __launch_bounds__(256) void k_attn(
    const h16* __restrict__ Qh, const h16* __restrict__ Ql,
    const h16* __restrict__ Kh, const h16* __restrict__ Kl,
    const h16* __restrict__ Vh, const h16* __restrict__ Vl,
    h16* __restrict__ Oh, h16* __restrict__ Ol)
{
  __shared__ h16 lds[4*64*FLD];   // 36,864 B (K h/l + V h/l)
  h16* sKh = lds;            h16* sKl = lds + 64*FLD;
  h16* sVh = lds + 2*64*FLD; h16* sVl = lds + 3*64*FLD;
  const int bid = blockIdx.x;                  // 0..2047
  const int swz = (bid & 7) * 256 + (bid >> 3);
  const int bh = swz >> 4;
  const int q0 = (swz & 15) * QB;
  const int tid = threadIdx.x, lane = tid & 63, w = tid >> 6;
  const int fr = lane & 15, hg = lane >> 4;   // 0..3
  const int kg = hg << 3;
  // Q fragments (B-operand layout: col=q=fr, k-chunk per hg), scale 16
  const long qbase = ((long)bh*SEQ + q0 + w*16 + fr) * HD;
  h16x8 qh[2], ql[2];
  qh[0] = *(const h16x8*)(Qh + qbase + kg);
  qh[1] = *(const h16x8*)(Qh + qbase + 32 + kg);
  ql[0] = *(const h16x8*)(Ql + qbase + kg);
  ql[1] = *(const h16x8*)(Ql + qbase + 32 + kg);
  f32x4 o1[4] = {}, o2[4] = {};      // O[q=4hg+r][d=16jd+fr]
  float mrow = -3.0e38f, lrow = 0.f; // for q-row = w*16 + fr
  // staging: 64 rows x 64 h16, 4 threads/row, 16 h16 each
  const int srow = tid >> 2, skc = (tid & 3) << 4;
  const long kbase = ((long)bh*SEQ + srow) * HD + skc;
  const long vbase = ((long)bh*HD + srow) * SEQ + skc;
  const int srcA = fr + ((hg & 1) << 5);   // lane of hg_s = 2*(hg&1)
  const int srcB = srcA + 16;              // hg_s = 2*(hg&1)+1
  for (int kt = 0; kt < NCHUNK; ++kt) {
    const int n0 = kt * QB;
    __syncthreads();    // all waves done with prev K/V tile (PV reads)
    {
      const long ka = kbase + (long)n0*HD;
      *(uint4*)(sKh + srow*FLD + skc)     = *(const uint4*)(Kh + ka);
      *(uint4*)(sKh + srow*FLD + skc + 8) = *(const uint4*)(Kh + ka + 8);
      *(uint4*)(sKl + srow*FLD + skc)     = *(const uint4*)(Kl + ka);
      *(uint4*)(sKl + srow*FLD + skc + 8) = *(const uint4*)(Kl + ka + 8);
      const long va = vbase + n0;
      *(uint4*)(sVh + srow*FLD + skc)     = *(const uint4*)(Vh + va);
      *(uint4*)(sVh + srow*FLD + skc + 8) = *(const uint4*)(Vh + va + 8);
      *(uint4*)(sVl + srow*FLD + skc)     = *(const uint4*)(Vl + va);
      *(uint4*)(sVl + srow*FLD + skc + 8) = *(const uint4*)(Vl + va + 8);
    }
    __syncthreads();
    // S^T = K.Q (split): s[j] rows n = 16j + 4hg + r, col q = fr
    f32x4 s1[4] = {}, s2[4] = {};
    #pragma unroll
    for (int ks = 0; ks < 2; ++ks)
      #pragma unroll
      for (int j = 0; j < 4; ++j) {
        h16x8 kh = *(const h16x8*)(sKh + (j*16 + fr)*FLD + ks*32 + kg);
        h16x8 kl = *(const h16x8*)(sKl + (j*16 + fr)*FLD + ks*32 + kg);
        s1[j] = MFMA16(kh, qh[ks], s1[j]);
        s2[j] = MFMA16(kh, ql[ks], s2[j]);
        s2[j] = MFMA16(kl, qh[ks], s2[j]);
      }
    // lane-local softmax for q = fr (16 vals: n = 16j + 4hg + r)
    float p[4][4];
    float tmax = -3.0e38f;
    #pragma unroll
    for (int j = 0; j < 4; ++j)
      #pragma unroll
      for (int r = 0; r < 4; ++r) {
        float sc = (s1[j][r] + s2[j][r]*(1.0f/4096.0f)) * (0.125f/256.0f);
        p[j][r] = sc;
        tmax = fmaxf(tmax, sc);
      }
    tmax = fmaxf(tmax, __shfl_xor(tmax, 16));
    tmax = fmaxf(tmax, __shfl_xor(tmax, 32));
    float mn = fmaxf(mrow, tmax);
    float sclf = __expf(mrow - mn);
    mrow = mn;
    float psum = 0.f;
    #pragma unroll
    for (int j = 0; j < 4; ++j)
      #pragma unroll
      for (int r = 0; r < 4; ++r) { float e = __expf(p[j][r] - mn); p[j][r] = e; psum += e; }
    psum += __shfl_xor(psum, 16);
    psum += __shfl_xor(psum, 32);
    lrow = lrow*sclf + psum;
    // rescale O: scale for q-local 4hg+r lives at lane fr = 4hg+r
    #pragma unroll
    for (int r = 0; r < 4; ++r) {
      float sq = __shfl(sclf, hg*4 + r);
      #pragma unroll
      for (int jd = 0; jd < 4; ++jd) { o1[jd][r] *= sq; o2[jd][r] *= sq; }
    }
    // pack P*512 as hi/lo pairs: reg (j,rp) = n {16j+4hg+2rp, +1}
    u32 hp[4][2], lp[4][2];
    #pragma unroll
    for (int j = 0; j < 4; ++j)
      #pragma unroll
      for (int rp = 0; rp < 2; ++rp) {
        float a = p[j][2*rp]   * 512.0f;
        float b = p[j][2*rp+1] * 512.0f;
        float fa, fb;
        hp[j][rp] = pk2(a, b, fa, fb);
        lp[j][rp] = pk2w((a - fa) * 4096.0f, (b - fb) * 4096.0f);
      }
    // PV per ks: pull the 4 hi + 4 lo pair-regs this ks needs, assemble, mfma
    #pragma unroll
    for (int ks = 0; ks < 2; ++ks) {
      const int j0 = 2*ks, j1 = 2*ks + 1;
      u32 hA0 = (u32)__shfl((int)hp[j0][0], srcA), hA1 = (u32)__shfl((int)hp[j0][1], srcA);
      u32 hB0 = (u32)__shfl((int)hp[j0][0], srcB), hB1 = (u32)__shfl((int)hp[j0][1], srcB);
      u32 hC0 = (u32)__shfl((int)hp[j1][0], srcA), hC1 = (u32)__shfl((int)hp[j1][1], srcA);
      u32 hD0 = (u32)__shfl((int)hp[j1][0], srcB), hD1 = (u32)__shfl((int)hp[j1][1], srcB);
      u32 lA0 = (u32)__shfl((int)lp[j0][0], srcA), lA1 = (u32)__shfl((int)lp[j0][1], srcA);
      u32 lB0 = (u32)__shfl((int)lp[j0][0], srcB), lB1 = (u32)__shfl((int)lp[j0][1], srcB);
      u32 lC0 = (u32)__shfl((int)lp[j1][0], srcA), lC1 = (u32)__shfl((int)lp[j1][1], srcA);
      u32 lD0 = (u32)__shfl((int)lp[j1][0], srcB), lD1 = (u32)__shfl((int)lp[j1][1], srcB);
      const bool hij = (hg & 2) != 0;   // jsel = 2ks + (hg>>1)
      union { u32 w[4]; h16x8 v; } pa, pb;
      pa.w[0] = hij ? hC0 : hA0;  pa.w[1] = hij ? hC1 : hA1;
      pa.w[2] = hij ? hD0 : hB0;  pa.w[3] = hij ? hD1 : hB1;
      pb.w[0] = hij ? lC0 : lA0;  pb.w[1] = hij ? lC1 : lA1;
      pb.w[2] = hij ? lD0 : lB0;  pb.w[3] = hij ? lD1 : lB1;
      #pragma unroll
      for (int jd = 0; jd < 4; ++jd) {
        h16x8 vh = *(const h16x8*)(sVh + (jd*16 + fr)*FLD + ks*32 + kg);
        h16x8 vl = *(const h16x8*)(sVl + (jd*16 + fr)*FLD + ks*32 + kg);
        o1[jd] = MFMA16(pa.v, vh, o1[jd]);
        o2[jd] = MFMA16(pa.v, vl, o2[jd]);
        o2[jd] = MFMA16(pb.v, vh, o2[jd]);
      }
    }
  }
  // epilogue: normalize and store O split (scale 16); l for q=4hg+r at lane 4hg+r
  float lq[4];
  #pragma unroll
  for (int r = 0; r < 4; ++r) lq[r] = __shfl(lrow, hg*4 + r);
  const int b = bh >> 4, h = bh & 15;
  #pragma unroll
  for (int jd = 0; jd < 4; ++jd)
    #pragma unroll
    for (int r = 0; r < 4; ++r) {
      int qrow = q0 + w*16 + hg*4 + r;
      int d = jd*16 + fr;
      float ov = (o1[jd][r] + o2[jd][r]*(1.0f/4096.0f)) / (512.0f*16.0f*lq[r]);
      store_split(Oh, Ol, ((long)b*SEQ + qrow)*DM + h*HD + d, ov*16.0f);
    }
}

// out_proj (128x64 split, gload_lds staging): attn = O.Wo^T + bo, fp32
__global__ __launch_bounds__(256) void k_out(
    const h16* __restrict__ Oh, const h16* __restrict__ Ol,
    const h16* __restrict__ Wh, const h16* __restrict__ Wl,
    const float* __restrict__ bias, float* __restrict__ attn)
{
  __shared__ h16 lds[(2*128 + 2*64)*SLDA];
  const int n0 = blockIdx.x*64, m0 = blockIdx.y*128;
  f32x4 a1[4][2] = {}; f32x4 a2[4][2] = {};
  gemm128x64_core(Oh, Ol, Wh, Wl, 1024, 1024, 1024, m0, n0, a1, a2, lds);
  EPI_W;
  #pragma unroll
  for (int i = 0; i < 4; ++i)
    #pragma unroll
    for (int j = 0; j < 2; ++j)
      #pragma unroll
      for (int r = 0; r < 4; ++r) {
        int row = m0 + wr + i*16 + rb + r;
        int col = n0 + wc + j*16 + fr;
        attn[(long)row*DM + col] =
            (a1[i][j][r] + a2[i][j][r]*(1.0f/4096.0f)) * (1.0f/1024.0f) + bias[col];
      }
}

// LayerNorm of (A + Badd): optional fp32 out, f16(x*16) out, direct out
__global__ __launch_bounds__(256) void k_ln(
    const float* __restrict__ A, const float* __restrict__ Badd,
    const float* __restrict__ g, const float* __restrict__ be,
    float* __restrict__ xout, h16* __restrict__ xh, float* __restrict__ dout)
{
  int wave = threadIdx.x >> 6, lane = threadIdx.x & 63;
  long row = (long)blockIdx.x*4 + wave;
  const float* ar = A + row*DM; const float* br = Badd + row*DM;
  float v[16]; float s = 0.0f;
  #pragma unroll
  for (int p = 0; p < 4; ++p) {
    int d = p*256 + lane*4;
    float4 a = *(const float4*)(ar + d);
    float4 b = *(const float4*)(br + d);
    float t0=a.x+b.x, t1=a.y+b.y, t2=a.z+b.z, t3=a.w+b.w;
    v[4*p+0]=t0; v[4*p+1]=t1; v[4*p+2]=t2; v[4*p+3]=t3;
    s += t0+t1+t2+t3;
  }
  s = wave_sum(s);
  float m = s * (1.0f/1024.0f);
  float q = 0.0f;
  #pragma unroll
  for (int i = 0; i < 16; ++i) { float dd = v[i]-m; q += dd*dd; }
  q = wave_sum(q);
  float rs = (float)(1.0 / sqrt((double)(q * (1.0f/1024.0f) + 1e-5f)));
  #pragma unroll
  for (int p = 0; p < 4; ++p) {
    int d = p*256 + lane*4;
    float4 gv = *(const float4*)(g + d);
    float4 bv = *(const float4*)(be + d);
    float y0 = (v[4*p+0]-m)*rs*gv.x + bv.x;
    float y1 = (v[4*p+1]-m)*rs*gv.y + bv.y;
    float y2 = (v[4*p+2]-m)*rs*gv.z + bv.z;
    float y3 = (v[4*p+3]-m)*rs*gv.w + bv.w;
    if (xout) { float4 o = {y0,y1,y2,y3}; *(float4*)(xout + row*DM + d) = o; }
    if (xh) {
      h16x4 hv; hv[0]=(h16)(y0*16.f); hv[1]=(h16)(y1*16.f);
      hv[2]=(h16)(y2*16.f); hv[3]=(h16)(y3*16.f);
      *(h16x4*)(xh + row*DM + d) = hv;
    }
    if (dout) { float4 o = {y0,y1,y2,y3}; *(float4*)(dout + row*DM + d) = o; }
  }
}

// ---------------------------------------------------------------------------
// threefry2x32 (key=[0,42]) -> gumbel -> argmax. VERIFIED round 5 — DO NOT TOUCH.
// partitionable bits = b1 ^ b2, counter = (0, i).
// ---------------------------------------------------------------------------
__device__ __forceinline__ void threefry(u32 x0, u32 x1, u32& y0, u32& y1) {
  const u32 ks0 = 0u, ks1 = 42u, ks2 = 0x1BD11BDAu ^ 42u;
  x0 += ks0; x1 += ks1;
  #define TF_R(r) { x0 += x1; x1 = (x1 << r) | (x1 >> (32 - r)); x1 ^= x0; }
  TF_R(13) TF_R(15) TF_R(26) TF_R(6)  x0 += ks1; x1 += ks2 + 1u;
  TF_R(17) TF_R(29) TF_R(16) TF_R(24) x0 += ks2; x1 += ks0 + 2u;
  TF_R(13) TF_R(15) TF_R(26) TF_R(6)  x0 += ks0; x1 += ks1 + 3u;
  TF_R(17) TF_R(29) TF_R(16) TF_R(24) x0 += ks1; x1 += ks2 + 4u;
  TF_R(13) TF_R(15) TF_R(26) TF_R(6)  x0 += ks2; x1 += ks0 + 5u;
  #undef TF_R
  y0 = x0; y1 = x1;
}

__device__ __forceinline__ float gumbel_from(u32 bits) {
  float f = __uint_as_float((bits >> 9) | 0x3F800000u) - 1.0f;
  float u = (f > 0.0f) ? f : 1.17549435e-38f;
  float nl = (float)(-log((double)u));
  return -(float)log((double)nl);
}

__global__ __launch_bounds__(256) void k_gate(
    const float* __restrict__ x, const float* __restrict__ gw,
    const float* __restrict__ gb, int* __restrict__ chosen, int* __restrict__ counts)
{
  int wave = threadIdx.x >> 6, lane = threadIdx.x & 63;
  long t = (long)blockIdx.x*4 + wave;
  const float* xr = x + t*DM;
  float p[4] = {0.f,0.f,0.f,0.f};
  #pragma unroll
  for (int pp = 0; pp < 4; ++pp) {
    int d = pp*256 + lane*4;
    float4 xv = *(const float4*)(xr + d);
    #pragma unroll
    for (int e = 0; e < 4; ++e) {
      float4 gv = *(const float4*)(gw + e*DM + d);
      p[e] += xv.x*gv.x + xv.y*gv.y + xv.z*gv.z + xv.w*gv.w;
    }
  }
  #pragma unroll
  for (int e = 0; e < 4; ++e) p[e] = wave_sum(p[e]);
  if (lane == 0) {
    float best = -3.0e38f; int arg = 0;
    #pragma unroll
    for (int e = 0; e < 4; ++e) {
      float logit = p[e] + gb[e];
      u32 j = (u32)(4*t + e);
      u32 y0, y1;
      threefry(0u, j, y0, y1);
      float v = gumbel_from(y0 ^ y1) + logit;
      if (v > best) { best = v; arg = e; }
    }
    chosen[(int)t] = arg;
    atomicAdd(&counts[arg], 1);
  }
}

__global__ void k_offsets(const int* __restrict__ counts, int* __restrict__ eoff) {
  if (threadIdx.x == 0 && blockIdx.x == 0) {
    int o = 0;
    for (int e = 0; e < 4; ++e) { eoff[e] = o; o += (counts[e] + 127) & ~127; }
  }
}

__global__ void k_fill(int* __restrict__ p, int n) {
  int i = blockIdx.x*256 + threadIdx.x;
  if (i < n) p[i] = -1;
}

__global__ void k_scatter(const int* __restrict__ chosen, const int* __restrict__ eoff,
                          int* __restrict__ cursor, int* __restrict__ plist) {
  int t = blockIdx.x*256 + threadIdx.x;
  if (t >= BS) return;
  int e = chosen[t];
  int slot = atomicAdd(&cursor[e], 1);
  plist[eoff[e] + slot] = t;
}

// MoE layer 1 (gathered rows, 128x64 core): h = relu(x.w1[e]^T + b1[e])
__global__ __launch_bounds__(256) void k_e1(
    const h16* __restrict__ Xh, const h16* __restrict__ W1, const float* __restrict__ b1,
    const int* __restrict__ plist, const int* __restrict__ eoff, h16* __restrict__ Hh)
{
  __shared__ h16 lds[(128 + 64)*LDK];
  const int n0 = blockIdx.x*64, m0 = blockIdx.y*128;
  const int e = (m0 >= eoff[1]) + (m0 >= eoff[2]) + (m0 >= eoff[3]);
  f32x4 acc[4][2] = {};
  hgemm128_core<true>(Xh, W1 + (long)e*DFE*DM, 1024, 1024, 1024, m0, n0, plist, acc, lds);
  EPI_W;
  #pragma unroll
  for (int i = 0; i < 4; ++i)
    #pragma unroll
    for (int j = 0; j < 2; ++j)
      #pragma unroll
      for (int r = 0; r < 4; ++r) {
        int row = m0 + wr + i*16 + rb + r;
        int col = n0 + wc + j*16 + fr;
        float c = acc[i][j][r] * (1.0f/1024.0f) + b1[e*DFE + col];
        c = fmaxf(c, 0.0f);
        Hh[(long)row*DFE + col] = (h16)(c * 16.0f);
      }
}

// MoE layer 2 (bucket rows, 128x64 core, scatter out): y[t] = h.w2[e]^T + b2[e]
__global__ __launch_bounds__(256) void k_e2(
    const h16* __restrict__ Hh, const h16* __restrict__ W2, const float* __restrict__ b2,
    const int* __restrict__ plist, const int* __restrict__ eoff, float* __restrict__ y)
{
  __shared__ h16 lds[(128 + 64)*LDK];
  const int n0 = blockIdx.x*64, m0 = blockIdx.y*128;
  const int e = (m0 >= eoff[1]) + (m0 >= eoff[2]) + (m0 >= eoff[3]);
  f32x4 acc[4][2] = {};
  hgemm128_core<false>(Hh, W2 + (long)e*DM*DFE, 1024, DFE, DFE, m0, n0, nullptr, acc, lds);
  EPI_W;
  #pragma unroll
  for (int i = 0; i < 4; ++i)
    #pragma unroll
    for (int j = 0; j < 2; ++j)
      #pragma unroll
      for (int r = 0; r < 4; ++r) {
        int row = m0 + wr + i*16 + rb + r;
        int col = n0 + wc + j*16 + fr;
        int t = plist[row];
        if (t >= 0)
          y[(long)t*DM + col] = acc[i][j][r] * (1.0f/1024.0f) + b2[e*DM + col];
      }
}

// ---------------------------------------------------------------------------
extern "C" void kernel_launch(void* const* d_in, const int* in_sizes, int n_in,
                              void* d_out, int out_size, void* d_ws, size_t ws_size,
                              hipStream_t stream) {
  const float* src = (const float*)d_in[0];
  const float* pos = (const float*)d_in[1];
  const float* w3  = (const float*)d_in[2];
  const float* b3  = (const float*)d_in[3];
  const float* wo  = (const float*)d_in[4];
  const float* bo  = (const float*)d_in[5];
  const float* gw  = (const float*)d_in[6];
  const float* gb  = (const float*)d_in[7];
  const float* w1  = (const float*)d_in[8];
  const float* b1  = (const float*)d_in[9];
  const float* w2  = (const float*)d_in[10];
  const float* b2  = (const float*)d_in[11];
  const float* g1  = (const float*)d_in[12];
  const float* be1 = (const float*)d_in[13];
  const float* g2  = (const float*)d_in[14];
  const float* be2 = (const float*)d_in[15];
  float* out = (float*)d_out;
  char* ws = (char*)d_ws;
  if (ws_size < WS_NEEDED) return;

  auto H = [&](size_t off) { return (h16*)(ws + off); };
  auto F = [&](size_t off) { return (float*)(ws + off); };
  auto I = [&](size_t off) { return (int*)(ws + off); };

  // zero atomic counters (counts[4] + cursor[4] contiguous)
  k_zero8<<<1, 64, 0, stream>>>(I(OFF_COUNTS));

  // input + weight splits
  k_split_in<<<BS*DM/4/256, 256, 0, stream>>>(src, pos,
      H(OFF_QKH), H(OFF_QKL), H(OFF_SRCH), H(OFF_SRCL));
  k_split2<<<3*DM*DM/4/256, 256, 0, stream>>>(w3, H(OFF_W3H), H(OFF_W3L), 64.0f, 3*DM*DM/4);
  k_split2<<<DM*DM/4/256, 256, 0, stream>>>(wo, H(OFF_WOH), H(OFF_WOL), 64.0f, DM*DM/4);

  // QKV projection
  k_qkv<<<dim3(48, 64), 256, 0, stream>>>(
      H(OFF_QKH), H(OFF_QKL), H(OFF_SRCH), H(OFF_SRCL), H(OFF_W3H), H(OFF_W3L), b3,
      H(OFF_QH), H(OFF_QL), H(OFF_KH), H(OFF_KL), H(OFF_VH), H(OFF_VL));

  // fused flash attention (one dispatch, XCD-swizzled)
  k_attn<<<dim3(NCHUNK*NBH), 256, 0, stream>>>(
      H(OFF_QH), H(OFF_QL), H(OFF_KH), H(OFF_KL), H(OFF_VH), H(OFF_VL),
      H(OFF_OH), H(OFF_OL));

  // out projection + LN1
  k_out<<<dim3(16, 64), 256, 0, stream>>>(
      H(OFF_OH), H(OFF_OL), H(OFF_WOH), H(OFF_WOL), bo, F(OFF_ATT));
  k_ln<<<BS/4, 256, 0, stream>>>(src, F(OFF_ATT), g1, be1, F(OFF_X), H(OFF_XH), nullptr);

  // gate + expert bucketing (buckets padded to 128 rows)
  k_gate<<<BS/4, 256, 0, stream>>>(F(OFF_X), gw, gb, I(OFF_CHOSEN), I(OFF_COUNTS));
  k_offsets<<<1, 64, 0, stream>>>(I(OFF_COUNTS), I(OFF_EOFF));
  k_fill<<<(NPOS+255)/256, 256, 0, stream>>>(I(OFF_PLIST), NPOS);
  k_scatter<<<BS/256, 256, 0, stream>>>(I(OFF_CHOSEN), I(OFF_EOFF), I(OFF_CURSOR), I(OFF_PLIST));

  // MoE weights to f16 and bucketed expert FFN (128x64 core)
  k_tof16<<<NE*DFE*DM/4/256, 256, 0, stream>>>(w1, H(OFF_W1H), 64.0f, NE*DFE*DM/4);
  k_tof16<<<NE*DM*DFE/4/256, 256, 0, stream>>>(w2, H(OFF_W2H), 64.0f, NE*DM*DFE/4);
  k_e1<<<dim3(16, NPOS/128), 256, 0, stream>>>(
      H(OFF_XH), H(OFF_W1H), b1, I(OFF_PLIST), I(OFF_EOFF), H(OFF_HH));
  k_e2<<<dim3(16, NPOS/128), 256, 0, stream>>>(
      H(OFF_HH), H(OFF_W2H), b2, I(OFF_PLIST), I(OFF_EOFF), F(OFF_Y));

  // final LN2 -> output
  k_ln<<<BS/4, 256, 0, stream>>>(F(OFF_X), F(OFF_Y), g2, be2, nullptr, nullptr, out);
}